// Round 1
// baseline (705.448 us; speedup 1.0000x reference)
//
#include <hip/hip_runtime.h>
#include <hip/hip_bf16.h>

namespace {

constexpr int B  = 2;
constexpr int C  = 64;
constexpr int CQ = 8;
constexpr int H  = 270;
constexpr int W  = 480;
constexpr int HW = H * W;
constexpr float INVH2 = 2.0f / (270.0f * 270.0f);  // dw_h = exp(-d^2 * INVH2)
constexpr float INVW2 = 2.0f / (480.0f * 480.0f);

typedef __attribute__((ext_vector_type(4))) float f32x4;
typedef __attribute__((ext_vector_type(8))) short short8;

__device__ __forceinline__ float bits2f(unsigned short u) {
  union { unsigned int i; float f; } cv;
  cv.i = ((unsigned int)u) << 16;
  return cv.f;
}

__device__ __forceinline__ unsigned short f2bf(float f) {
  union { __hip_bfloat16 b; unsigned short u; } cv;
  cv.b = __float2bfloat16(f);
  return cv.u;
}

__device__ __forceinline__ unsigned int pack2(float a, float b) {
  return ((unsigned int)f2bf(b) << 16) | (unsigned int)f2bf(a);
}

// V-row permutation inside each 32-row K-step so that the swapped-QK P layout
// (lane quad q holds g = 4q+rr from E0 and 16+4q+rr from E1) feeds the PV
// A-fragment (k-slot q*8+j) with NO cross-lane data movement:
//   u < 16: slot = 8*(u>>2) + (u&3);  u >= 16: slot = 8*((u-16)>>2) + 4 + (u&3)

// ---------------------------------------------------------------------------
// K1: q/k/v 1x1 projections. One thread per pixel. Writes bf16 packs:
// qwp/kwp [b][h][w][8], qhp/khp [b][w][h][8], v [b][c][h][w], vt [b][w][h][c].
// ---------------------------------------------------------------------------
__global__ __launch_bounds__(256)
void k_qkv(const float* __restrict__ x,
           const float* __restrict__ Wq, const float* __restrict__ bq,
           const float* __restrict__ Wk, const float* __restrict__ bk,
           const float* __restrict__ Wv, const float* __restrict__ bv,
           unsigned short* __restrict__ qwp, unsigned short* __restrict__ kwp,
           unsigned short* __restrict__ qhp, unsigned short* __restrict__ khp,
           unsigned short* __restrict__ v, unsigned short* __restrict__ vt) {
  __shared__ __align__(16) float wql[CQ * C];
  __shared__ __align__(16) float wkl[CQ * C];
  __shared__ __align__(16) float wvl[C * C];
  __shared__ float bql[CQ], bkl[CQ], bvl[C];
  const int tid = threadIdx.x;
  for (int i = tid; i < CQ * C; i += 256) { wql[i] = Wq[i]; wkl[i] = Wk[i]; }
  for (int i = tid; i < C * C; i += 256) wvl[i] = Wv[i];
  if (tid < CQ) { bql[tid] = bq[tid]; bkl[tid] = bk[tid]; }
  if (tid < C) bvl[tid] = bv[tid];
  __syncthreads();
  const int pix = blockIdx.x * 256 + tid;
  if (pix >= B * HW) return;
  const int b = pix / HW;
  const int r = pix - b * HW;
  const int h = r / W;
  const int w = r - h * W;

  float qa[CQ], ka[CQ], va[C];
#pragma unroll
  for (int o = 0; o < CQ; ++o) { qa[o] = bql[o]; ka[o] = bkl[o]; }
#pragma unroll
  for (int o = 0; o < C; ++o) va[o] = bvl[o];

  const float* xp = x + (size_t)b * C * HW + r;
  for (int c = 0; c < C; c += 4) {
    const float x0 = xp[(size_t)(c + 0) * HW];
    const float x1 = xp[(size_t)(c + 1) * HW];
    const float x2 = xp[(size_t)(c + 2) * HW];
    const float x3 = xp[(size_t)(c + 3) * HW];
#pragma unroll
    for (int o = 0; o < CQ; ++o) {
      const float4 a = *(const float4*)(wql + o * C + c);
      qa[o] = fmaf(a.w, x3, fmaf(a.z, x2, fmaf(a.y, x1, fmaf(a.x, x0, qa[o]))));
      const float4 bb = *(const float4*)(wkl + o * C + c);
      ka[o] = fmaf(bb.w, x3, fmaf(bb.z, x2, fmaf(bb.y, x1, fmaf(bb.x, x0, ka[o]))));
    }
#pragma unroll
    for (int o = 0; o < C; ++o) {
      const float4 cc = *(const float4*)(wvl + o * C + c);
      va[o] = fmaf(cc.w, x3, fmaf(cc.z, x2, fmaf(cc.y, x1, fmaf(cc.x, x0, va[o]))));
    }
  }

  uint4 qp4, kp4;
  qp4.x = pack2(qa[0], qa[1]); qp4.y = pack2(qa[2], qa[3]);
  qp4.z = pack2(qa[4], qa[5]); qp4.w = pack2(qa[6], qa[7]);
  kp4.x = pack2(ka[0], ka[1]); kp4.y = pack2(ka[2], ka[3]);
  kp4.z = pack2(ka[4], ka[5]); kp4.w = pack2(ka[6], ka[7]);
  *(uint4*)(qwp + (size_t)pix * 8) = qp4;
  *(uint4*)(kwp + (size_t)pix * 8) = kp4;
  const size_t tbase = ((size_t)b * W + w) * H + h;
  *(uint4*)(qhp + tbase * 8) = qp4;
  *(uint4*)(khp + tbase * 8) = kp4;

  unsigned short* vp = v + (size_t)b * C * HW + r;
#pragma unroll
  for (int o = 0; o < C; ++o) vp[(size_t)o * HW] = f2bf(va[o]);
  unsigned short* vtp = vt + tbase * C;
#pragma unroll
  for (int j = 0; j < 16; ++j) {
    ushort4 u;
    u.x = f2bf(va[4 * j + 0]);
    u.y = f2bf(va[4 * j + 1]);
    u.z = f2bf(va[4 * j + 2]);
    u.w = f2bf(va[4 * j + 3]);
    *(ushort4*)(vtp + 4 * j) = u;
  }
}

// ---------------------------------------------------------------------------
// K2: out_w unnormalized + S_w. ONE block per (b,h): 960 thr = 15 waves,
// each wave owns 32 m-rows (M=480). Swapped QK (mfma(K,Q)) puts P with
// m=lane&15, g in regs -> exp + pack2 in registers feeds PV A-frag directly
// (V rows stored k-slot-permuted in LDS). No P LDS round-trip, no dw table.
// LDS 62.5 KB -> 2 blocks/CU. Outputs ow [b][h][c][w] bf16, Sw [b][h][w].
// ---------------------------------------------------------------------------
constexpr int VSW = 488;

__global__ __launch_bounds__(960, 7)
void k_outw(const unsigned short* __restrict__ qwp,
            const unsigned short* __restrict__ kwp,
            const unsigned short* __restrict__ v,
            unsigned short* __restrict__ ow, float* __restrict__ Sw) {
  __shared__ __align__(16) unsigned short vbs[31232];  // 64*488 u16 = 62464 B
  const int h = blockIdx.x, b = blockIdx.y;
  const int tid = threadIdx.x;

  const unsigned short* vrow = v + (size_t)b * C * HW + (size_t)h * W;
  for (int idx = tid; idx < 64 * 120; idx += 960) {
    const int c = idx / 120, s4 = (idx - c * 120) * 4;
    const int u = s4 & 31;  // multiple of 4
    const int t = (u < 16) ? ((u >> 2) * 8) : (((u - 16) >> 2) * 8 + 4);
    *(ushort4*)(vbs + c * VSW + (s4 & ~31) + t) =
        *(const ushort4*)(vrow + (size_t)c * HW + s4);
  }

  const int lane = tid & 63, wv = tid >> 6;
  const int l15 = lane & 15, quad = lane >> 4;
  const int m0 = wv * 32;
  const size_t rowbase = ((size_t)b * H + h) * W;

  short8 qa0 = short8{0, 0, 0, 0, 0, 0, 0, 0};
  short8 qa1 = short8{0, 0, 0, 0, 0, 0, 0, 0};
  if (quad == 0) {
    qa0 = *(const short8*)(qwp + (rowbase + m0 + l15) * 8);
    qa1 = *(const short8*)(qwp + (rowbase + m0 + 16 + l15) * 8);
  }
  const unsigned short* kRow = kwp + rowbase * 8;

  f32x4 acc[2][4];
  float Sacc[2] = {0.0f, 0.0f};
#pragma unroll
  for (int mt = 0; mt < 2; ++mt)
#pragma unroll
    for (int ct = 0; ct < 4; ++ct)
#pragma unroll
      for (int rr = 0; rr < 4; ++rr) acc[mt][ct][rr] = 0.0f;

  __syncthreads();

  for (int ci = 0; ci < 15; ++ci) {
    const int sc = ci * 32;
    short8 kb0 = short8{0, 0, 0, 0, 0, 0, 0, 0};
    short8 kb1 = short8{0, 0, 0, 0, 0, 0, 0, 0};
    if (quad == 0) {
      kb0 = *(const short8*)(kRow + (size_t)(sc + l15) * 8);
      kb1 = *(const short8*)(kRow + (size_t)(sc + 16 + l15) * 8);
    }
    const f32x4 z4 = f32x4{0.f, 0.f, 0.f, 0.f};
    const f32x4 E00 = __builtin_amdgcn_mfma_f32_16x16x32_bf16(kb0, qa0, z4, 0, 0, 0);
    const f32x4 E01 = __builtin_amdgcn_mfma_f32_16x16x32_bf16(kb1, qa0, z4, 0, 0, 0);
    const f32x4 E10 = __builtin_amdgcn_mfma_f32_16x16x32_bf16(kb0, qa1, z4, 0, 0, 0);
    const f32x4 E11 = __builtin_amdgcn_mfma_f32_16x16x32_bf16(kb1, qa1, z4, 0, 0, 0);
    short8 vb[4];
#pragma unroll
    for (int ct = 0; ct < 4; ++ct)
      vb[ct] = *(const short8*)(vbs + (ct * 16 + l15) * VSW + sc + quad * 8);
#pragma unroll
    for (int mt = 0; mt < 2; ++mt) {
      const int m = m0 + mt * 16 + l15;
      const f32x4 Ea = mt ? E10 : E00;
      const f32x4 Eb = mt ? E11 : E01;
      float p0[4], p1[4];
#pragma unroll
      for (int rr = 0; rr < 4; ++rr) {
        const float d0 = (float)(m - (sc + quad * 4 + rr));
        const float d1 = d0 - 16.0f;
        p0[rr] = __expf(Ea[rr] * __expf(-(d0 * d0) * INVW2));
        p1[rr] = __expf(Eb[rr] * __expf(-(d1 * d1) * INVW2));
        Sacc[mt] += p0[rr] + p1[rr];
      }
      union { short8 s; unsigned int u[4]; } pu;
      pu.u[0] = pack2(p0[0], p0[1]);
      pu.u[1] = pack2(p0[2], p0[3]);
      pu.u[2] = pack2(p1[0], p1[1]);
      pu.u[3] = pack2(p1[2], p1[3]);
#pragma unroll
      for (int ct = 0; ct < 4; ++ct)
        acc[mt][ct] = __builtin_amdgcn_mfma_f32_16x16x32_bf16(pu.s, vb[ct], acc[mt][ct], 0, 0, 0);
    }
  }

#pragma unroll
  for (int mt = 0; mt < 2; ++mt) {
    float s = Sacc[mt];
    s += __shfl_xor(s, 16);
    s += __shfl_xor(s, 32);
    if (lane < 16) Sw[rowbase + m0 + mt * 16 + l15] = s;
  }

  __syncthreads();  // vbs reads done; reuse as [c][480] transpose buffer
  unsigned short* ob = vbs;
#pragma unroll
  for (int mt = 0; mt < 2; ++mt)
#pragma unroll
    for (int ct = 0; ct < 4; ++ct)
#pragma unroll
      for (int rr = 0; rr < 4; ++rr)
        ob[(ct * 16 + l15) * VSW + m0 + mt * 16 + quad * 4 + rr] = f2bf(acc[mt][ct][rr]);
  __syncthreads();
  unsigned short* og = ow + ((size_t)b * H + h) * C * W;
  for (int idx = tid; idx < 64 * 240; idx += 960) {
    const int c = idx / 240, wp = idx - c * 240;
    *(unsigned int*)(og + (size_t)c * W + 2 * wp) =
        *(const unsigned int*)(ob + c * VSW + 2 * wp);
  }
}

// ---------------------------------------------------------------------------
// K3: out_h unnormalized + S_h. ONE block per (b,w): 576 thr = 9 waves,
// each wave 32 m-rows (M=288, rows >= 270 pad: loads clamped, p masked).
// Same swapped-QK register-resident P path. LDS 37.9 KB -> 3 blocks/CU.
// Outputs oht [b][w][c][h], Sht [b][w][h] (transposed, contiguous per block).
// ---------------------------------------------------------------------------
constexpr int VSH = 296;

__global__ __launch_bounds__(576, 6)
void k_outh(const unsigned short* __restrict__ qhp,
            const unsigned short* __restrict__ khp,
            const unsigned short* __restrict__ vt,
            unsigned short* __restrict__ oht, float* __restrict__ Sht) {
  __shared__ __align__(16) unsigned short vbs[18944];  // 64*296 u16 = 37888 B
  const int w = blockIdx.x, b = blockIdx.y;
  const int tid = threadIdx.x;

  const unsigned short* vtb = vt + ((size_t)b * W + w) * H * C;
  for (int idx = tid; idx < 288 * 16; idx += 576) {
    const int g = idx >> 4, c4 = (idx & 15) * 4;
    ushort4 vv = make_ushort4(0, 0, 0, 0);
    if (g < H) vv = *(const ushort4*)(vtb + (size_t)g * C + c4);
    const int u = g & 31;
    const int t = (u < 16) ? ((u >> 2) * 8 + (u & 3))
                           : (((u - 16) >> 2) * 8 + 4 + (u & 3));
    const int slot = (g & ~31) + t;
    vbs[(c4 + 0) * VSH + slot] = vv.x;
    vbs[(c4 + 1) * VSH + slot] = vv.y;
    vbs[(c4 + 2) * VSH + slot] = vv.z;
    vbs[(c4 + 3) * VSH + slot] = vv.w;
  }

  const int lane = tid & 63, wv = tid >> 6;
  const int l15 = lane & 15, quad = lane >> 4;
  const int m0 = wv * 32;
  const size_t colbase = ((size_t)b * W + w) * H;

  short8 qa0 = short8{0, 0, 0, 0, 0, 0, 0, 0};
  short8 qa1 = short8{0, 0, 0, 0, 0, 0, 0, 0};
  if (quad == 0) {
    qa0 = *(const short8*)(qhp + (colbase + min(m0 + l15, H - 1)) * 8);
    qa1 = *(const short8*)(qhp + (colbase + min(m0 + 16 + l15, H - 1)) * 8);
  }
  const unsigned short* kCol = khp + colbase * 8;

  f32x4 acc[2][4];
  float Sacc[2] = {0.0f, 0.0f};
#pragma unroll
  for (int mt = 0; mt < 2; ++mt)
#pragma unroll
    for (int ct = 0; ct < 4; ++ct)
#pragma unroll
      for (int rr = 0; rr < 4; ++rr) acc[mt][ct][rr] = 0.0f;

  __syncthreads();

  for (int ci = 0; ci < 9; ++ci) {
    const int gc = ci * 32;
    short8 kb0 = short8{0, 0, 0, 0, 0, 0, 0, 0};
    short8 kb1 = short8{0, 0, 0, 0, 0, 0, 0, 0};
    if (quad == 0) {
      kb0 = *(const short8*)(kCol + (size_t)min(gc + l15, H - 1) * 8);
      kb1 = *(const short8*)(kCol + (size_t)min(gc + 16 + l15, H - 1) * 8);
    }
    const f32x4 z4 = f32x4{0.f, 0.f, 0.f, 0.f};
    const f32x4 E00 = __builtin_amdgcn_mfma_f32_16x16x32_bf16(kb0, qa0, z4, 0, 0, 0);
    const f32x4 E01 = __builtin_amdgcn_mfma_f32_16x16x32_bf16(kb1, qa0, z4, 0, 0, 0);
    const f32x4 E10 = __builtin_amdgcn_mfma_f32_16x16x32_bf16(kb0, qa1, z4, 0, 0, 0);
    const f32x4 E11 = __builtin_amdgcn_mfma_f32_16x16x32_bf16(kb1, qa1, z4, 0, 0, 0);
    short8 vb[4];
#pragma unroll
    for (int ct = 0; ct < 4; ++ct)
      vb[ct] = *(const short8*)(vbs + (ct * 16 + l15) * VSH + gc + quad * 8);
#pragma unroll
    for (int mt = 0; mt < 2; ++mt) {
      const int m = m0 + mt * 16 + l15;
      const f32x4 Ea = mt ? E10 : E00;
      const f32x4 Eb = mt ? E11 : E01;
      float p0[4], p1[4];
#pragma unroll
      for (int rr = 0; rr < 4; ++rr) {
        const int g0 = gc + quad * 4 + rr;
        const int g1 = g0 + 16;
        const float d0 = (float)(m - g0);
        const float d1 = d0 - 16.0f;
        p0[rr] = (g0 < H && g0 != m)
                     ? __expf(Ea[rr] * __expf(-(d0 * d0) * INVH2)) : 0.0f;
        p1[rr] = (g1 < H && g1 != m)
                     ? __expf(Eb[rr] * __expf(-(d1 * d1) * INVH2)) : 0.0f;
        Sacc[mt] += p0[rr] + p1[rr];
      }
      union { short8 s; unsigned int u[4]; } pu;
      pu.u[0] = pack2(p0[0], p0[1]);
      pu.u[1] = pack2(p0[2], p0[3]);
      pu.u[2] = pack2(p1[0], p1[1]);
      pu.u[3] = pack2(p1[2], p1[3]);
#pragma unroll
      for (int ct = 0; ct < 4; ++ct)
        acc[mt][ct] = __builtin_amdgcn_mfma_f32_16x16x32_bf16(pu.s, vb[ct], acc[mt][ct], 0, 0, 0);
    }
  }

#pragma unroll
  for (int mt = 0; mt < 2; ++mt) {
    float s = Sacc[mt];
    s += __shfl_xor(s, 16);
    s += __shfl_xor(s, 32);
    const int m = m0 + mt * 16 + l15;
    if (lane < 16 && m < H) Sht[colbase + m] = s;
  }

  __syncthreads();
  unsigned short* ob = vbs;  // [c][288] stride 296
#pragma unroll
  for (int mt = 0; mt < 2; ++mt)
#pragma unroll
    for (int ct = 0; ct < 4; ++ct)
#pragma unroll
      for (int rr = 0; rr < 4; ++rr)
        ob[(ct * 16 + l15) * VSH + m0 + mt * 16 + quad * 4 + rr] = f2bf(acc[mt][ct][rr]);
  __syncthreads();
  unsigned short* og = oht + ((size_t)b * W + w) * C * H;
  for (int idx = tid; idx < 64 * 135; idx += 576) {
    const int c = idx / 135, hp = idx - c * 135;
    *(unsigned int*)(og + (size_t)c * H + 2 * hp) =
        *(const unsigned int*)(ob + c * VSH + 2 * hp);
  }
}

// ---------------------------------------------------------------------------
// K4: out = gamma*(U_h + U_w)/(S_h+S_w) + x, LDS tile transpose for oht.
// Sht is [b][w][h] (1 MB, L2-resident, 64x c-reuse -> strided read is cheap).
// ---------------------------------------------------------------------------
__global__ __launch_bounds__(256)
void k_combine(const unsigned short* __restrict__ oht,
               const unsigned short* __restrict__ ow,
               const float* __restrict__ Sht, const float* __restrict__ Sw,
               const float* __restrict__ x,
               const float* __restrict__ gp,
               float* __restrict__ out) {
  __shared__ float tile[32][33];
  const int b = blockIdx.z >> 6, c = blockIdx.z & 63;
  const int w0 = blockIdx.x * 32, h0 = blockIdx.y * 32;
  const int tx = threadIdx.x, ty = threadIdx.y;  // (32, 8)
#pragma unroll
  for (int i = 0; i < 4; ++i) {
    const int wl = ty + i * 8;
    const int hh = h0 + tx;
    float val = 0.0f;
    if (hh < H) val = bits2f(oht[(((size_t)b * W + (w0 + wl)) * C + c) * H + hh]);
    tile[wl][tx] = val;
  }
  __syncthreads();
  const float gamma = *gp;
#pragma unroll
  for (int i = 0; i < 4; ++i) {
    const int hl = ty + i * 8;
    const int hh = h0 + hl;
    if (hh < H) {
      const int ww = w0 + tx;
      const float uh = tile[tx][hl];
      const float uw = bits2f(ow[(((size_t)b * H + hh) * C + c) * W + ww]);
      const size_t si = ((size_t)b * H + hh) * W + ww;
      const float Z = Sht[((size_t)b * W + ww) * H + hh] + Sw[si];
      const float invZ = __builtin_amdgcn_rcpf(Z);
      const size_t xi = ((size_t)b * C + c) * HW + (size_t)hh * W + ww;
      out[xi] = fmaf(gamma * invZ, uh + uw, x[xi]);
    }
  }
}

}  // namespace

extern "C" void kernel_launch(void* const* d_in, const int* in_sizes, int n_in,
                              void* d_out, int out_size, void* d_ws, size_t ws_size,
                              hipStream_t stream) {
  (void)in_sizes; (void)n_in; (void)out_size; (void)ws_size;
  const float* x  = (const float*)d_in[0];
  const float* Wq = (const float*)d_in[1];
  const float* bq = (const float*)d_in[2];
  const float* Wk = (const float*)d_in[3];
  const float* bk = (const float*)d_in[4];
  const float* Wv = (const float*)d_in[5];
  const float* bv = (const float*)d_in[6];
  const float* gp = (const float*)d_in[7];
  float* out = (float*)d_out;

  char* p = (char*)d_ws;
  auto take = [&](size_t bytes) -> void* {
    char* r = p;
    p += (bytes + 255) & ~(size_t)255;
    return (void*)r;
  };
  unsigned short* qwp = (unsigned short*)take(sizeof(unsigned short) * (size_t)B * HW * 8);
  unsigned short* kwp = (unsigned short*)take(sizeof(unsigned short) * (size_t)B * HW * 8);
  unsigned short* qhp = (unsigned short*)take(sizeof(unsigned short) * (size_t)B * HW * 8);
  unsigned short* khp = (unsigned short*)take(sizeof(unsigned short) * (size_t)B * HW * 8);
  unsigned short* v   = (unsigned short*)take(sizeof(unsigned short) * (size_t)B * C * HW);
  unsigned short* vt  = (unsigned short*)take(sizeof(unsigned short) * (size_t)B * C * HW);
  unsigned short* oht = (unsigned short*)take(sizeof(unsigned short) * (size_t)B * C * HW);
  unsigned short* owb = (unsigned short*)take(sizeof(unsigned short) * (size_t)B * C * HW);
  float* Sht = (float*)take(sizeof(float) * (size_t)B * HW);
  float* Sw  = (float*)take(sizeof(float) * (size_t)B * HW);

  hipLaunchKernelGGL(k_qkv, dim3((B * HW + 255) / 256), dim3(256), 0, stream,
                     x, Wq, bq, Wk, bk, Wv, bv, qwp, kwp, qhp, khp, v, vt);
  hipLaunchKernelGGL(k_outh, dim3(W, B), dim3(576), 0, stream,
                     qhp, khp, vt, oht, Sht);
  hipLaunchKernelGGL(k_outw, dim3(H, B), dim3(960), 0, stream,
                     qwp, kwp, v, owb, Sw);
  hipLaunchKernelGGL(k_combine, dim3(W / 32, (H + 31) / 32, B * C), dim3(32, 8), 0, stream,
                     oht, owb, Sht, Sw, x, gp, out);
}

// Round 2
// 493.882 us; speedup vs baseline: 1.4284x; 1.4284x over previous
//
#include <hip/hip_runtime.h>
#include <hip/hip_bf16.h>

namespace {

constexpr int B  = 2;
constexpr int C  = 64;
constexpr int CQ = 8;
constexpr int H  = 270;
constexpr int W  = 480;
constexpr int HW = H * W;
constexpr float INVH2 = 2.0f / (270.0f * 270.0f);  // dw_h = exp(-d^2 * INVH2)
constexpr float INVW2 = 2.0f / (480.0f * 480.0f);

typedef __attribute__((ext_vector_type(4))) float f32x4;
typedef __attribute__((ext_vector_type(8))) short short8;

__device__ __forceinline__ float bits2f(unsigned short u) {
  union { unsigned int i; float f; } cv;
  cv.i = ((unsigned int)u) << 16;
  return cv.f;
}

__device__ __forceinline__ unsigned short f2bf(float f) {
  union { __hip_bfloat16 b; unsigned short u; } cv;
  cv.b = __float2bfloat16(f);
  return cv.u;
}

__device__ __forceinline__ unsigned int pack2(float a, float b) {
  return ((unsigned int)f2bf(b) << 16) | (unsigned int)f2bf(a);
}

// V-row permutation inside each 32-row K-step so that the swapped-QK P layout
// (lane quad q holds g = 4q+rr from E0 and 16+4q+rr from E1) feeds the PV
// A-fragment (k-slot q*8+j) with NO cross-lane data movement:
//   u < 16: slot = 8*(u>>2) + (u&3);  u >= 16: slot = 8*((u-16)>>2) + 4 + (u&3)

// ---------------------------------------------------------------------------
// K1: q/k/v 1x1 projections. One thread per pixel. Writes bf16 packs:
// qwp/kwp [b][h][w][8], qhp/khp [b][w][h][8], v [b][c][h][w], vt [b][w][h][c].
// ---------------------------------------------------------------------------
__global__ __launch_bounds__(256)
void k_qkv(const float* __restrict__ x,
           const float* __restrict__ Wq, const float* __restrict__ bq,
           const float* __restrict__ Wk, const float* __restrict__ bk,
           const float* __restrict__ Wv, const float* __restrict__ bv,
           unsigned short* __restrict__ qwp, unsigned short* __restrict__ kwp,
           unsigned short* __restrict__ qhp, unsigned short* __restrict__ khp,
           unsigned short* __restrict__ v, unsigned short* __restrict__ vt) {
  __shared__ __align__(16) float wql[CQ * C];
  __shared__ __align__(16) float wkl[CQ * C];
  __shared__ __align__(16) float wvl[C * C];
  __shared__ float bql[CQ], bkl[CQ], bvl[C];
  const int tid = threadIdx.x;
  for (int i = tid; i < CQ * C; i += 256) { wql[i] = Wq[i]; wkl[i] = Wk[i]; }
  for (int i = tid; i < C * C; i += 256) wvl[i] = Wv[i];
  if (tid < CQ) { bql[tid] = bq[tid]; bkl[tid] = bk[tid]; }
  if (tid < C) bvl[tid] = bv[tid];
  __syncthreads();
  const int pix = blockIdx.x * 256 + tid;
  if (pix >= B * HW) return;
  const int b = pix / HW;
  const int r = pix - b * HW;
  const int h = r / W;
  const int w = r - h * W;

  float qa[CQ], ka[CQ], va[C];
#pragma unroll
  for (int o = 0; o < CQ; ++o) { qa[o] = bql[o]; ka[o] = bkl[o]; }
#pragma unroll
  for (int o = 0; o < C; ++o) va[o] = bvl[o];

  const float* xp = x + (size_t)b * C * HW + r;
  for (int c = 0; c < C; c += 4) {
    const float x0 = xp[(size_t)(c + 0) * HW];
    const float x1 = xp[(size_t)(c + 1) * HW];
    const float x2 = xp[(size_t)(c + 2) * HW];
    const float x3 = xp[(size_t)(c + 3) * HW];
#pragma unroll
    for (int o = 0; o < CQ; ++o) {
      const float4 a = *(const float4*)(wql + o * C + c);
      qa[o] = fmaf(a.w, x3, fmaf(a.z, x2, fmaf(a.y, x1, fmaf(a.x, x0, qa[o]))));
      const float4 bb = *(const float4*)(wkl + o * C + c);
      ka[o] = fmaf(bb.w, x3, fmaf(bb.z, x2, fmaf(bb.y, x1, fmaf(bb.x, x0, ka[o]))));
    }
#pragma unroll
    for (int o = 0; o < C; ++o) {
      const float4 cc = *(const float4*)(wvl + o * C + c);
      va[o] = fmaf(cc.w, x3, fmaf(cc.z, x2, fmaf(cc.y, x1, fmaf(cc.x, x0, va[o]))));
    }
  }

  uint4 qp4, kp4;
  qp4.x = pack2(qa[0], qa[1]); qp4.y = pack2(qa[2], qa[3]);
  qp4.z = pack2(qa[4], qa[5]); qp4.w = pack2(qa[6], qa[7]);
  kp4.x = pack2(ka[0], ka[1]); kp4.y = pack2(ka[2], ka[3]);
  kp4.z = pack2(ka[4], ka[5]); kp4.w = pack2(ka[6], ka[7]);
  *(uint4*)(qwp + (size_t)pix * 8) = qp4;
  *(uint4*)(kwp + (size_t)pix * 8) = kp4;
  const size_t tbase = ((size_t)b * W + w) * H + h;
  *(uint4*)(qhp + tbase * 8) = qp4;
  *(uint4*)(khp + tbase * 8) = kp4;

  unsigned short* vp = v + (size_t)b * C * HW + r;
#pragma unroll
  for (int o = 0; o < C; ++o) vp[(size_t)o * HW] = f2bf(va[o]);
  unsigned short* vtp = vt + tbase * C;
#pragma unroll
  for (int j = 0; j < 16; ++j) {
    ushort4 u;
    u.x = f2bf(va[4 * j + 0]);
    u.y = f2bf(va[4 * j + 1]);
    u.z = f2bf(va[4 * j + 2]);
    u.w = f2bf(va[4 * j + 3]);
    *(ushort4*)(vtp + 4 * j) = u;
  }
}

// ---------------------------------------------------------------------------
// K2: out_w unnormalized + S_w. ONE block per (b,h): 960 thr = 15 waves,
// each wave owns 32 m-rows (M=480). Swapped QK (mfma(K,Q)) puts P with
// m=lane&15, g in regs -> exp + pack2 in registers feeds PV A-frag directly
// (V rows stored k-slot-permuted in LDS). No P LDS round-trip, no dw table.
// __launch_bounds__(960,4): 15-wave blocks NEED >=4 waves on a SIMD, so the
// VGPR cap is 128 regardless; asking for more (round 1 used 7) forces scratch
// spill (VGPR=36, WRITE_SIZE 321 MB vs 34 MB real). Live state ~110 regs.
// ---------------------------------------------------------------------------
constexpr int VSW = 488;

__global__ __launch_bounds__(960, 4)
void k_outw(const unsigned short* __restrict__ qwp,
            const unsigned short* __restrict__ kwp,
            const unsigned short* __restrict__ v,
            unsigned short* __restrict__ ow, float* __restrict__ Sw) {
  __shared__ __align__(16) unsigned short vbs[31232];  // 64*488 u16 = 62464 B
  const int h = blockIdx.x, b = blockIdx.y;
  const int tid = threadIdx.x;

  const unsigned short* vrow = v + (size_t)b * C * HW + (size_t)h * W;
  for (int idx = tid; idx < 64 * 120; idx += 960) {
    const int c = idx / 120, s4 = (idx - c * 120) * 4;
    const int u = s4 & 31;  // multiple of 4
    const int t = (u < 16) ? ((u >> 2) * 8) : (((u - 16) >> 2) * 8 + 4);
    *(ushort4*)(vbs + c * VSW + (s4 & ~31) + t) =
        *(const ushort4*)(vrow + (size_t)c * HW + s4);
  }

  const int lane = tid & 63, wv = tid >> 6;
  const int l15 = lane & 15, quad = lane >> 4;
  const int m0 = wv * 32;
  const size_t rowbase = ((size_t)b * H + h) * W;

  short8 qa0 = short8{0, 0, 0, 0, 0, 0, 0, 0};
  short8 qa1 = short8{0, 0, 0, 0, 0, 0, 0, 0};
  if (quad == 0) {
    qa0 = *(const short8*)(qwp + (rowbase + m0 + l15) * 8);
    qa1 = *(const short8*)(qwp + (rowbase + m0 + 16 + l15) * 8);
  }
  const unsigned short* kRow = kwp + rowbase * 8;

  f32x4 acc[2][4];
  float Sacc[2] = {0.0f, 0.0f};
#pragma unroll
  for (int mt = 0; mt < 2; ++mt)
#pragma unroll
    for (int ct = 0; ct < 4; ++ct)
#pragma unroll
      for (int rr = 0; rr < 4; ++rr) acc[mt][ct][rr] = 0.0f;

  __syncthreads();

  for (int ci = 0; ci < 15; ++ci) {
    const int sc = ci * 32;
    short8 kb0 = short8{0, 0, 0, 0, 0, 0, 0, 0};
    short8 kb1 = short8{0, 0, 0, 0, 0, 0, 0, 0};
    if (quad == 0) {
      kb0 = *(const short8*)(kRow + (size_t)(sc + l15) * 8);
      kb1 = *(const short8*)(kRow + (size_t)(sc + 16 + l15) * 8);
    }
    const f32x4 z4 = f32x4{0.f, 0.f, 0.f, 0.f};
    const f32x4 E00 = __builtin_amdgcn_mfma_f32_16x16x32_bf16(kb0, qa0, z4, 0, 0, 0);
    const f32x4 E01 = __builtin_amdgcn_mfma_f32_16x16x32_bf16(kb1, qa0, z4, 0, 0, 0);
    const f32x4 E10 = __builtin_amdgcn_mfma_f32_16x16x32_bf16(kb0, qa1, z4, 0, 0, 0);
    const f32x4 E11 = __builtin_amdgcn_mfma_f32_16x16x32_bf16(kb1, qa1, z4, 0, 0, 0);
    short8 vb[4];
#pragma unroll
    for (int ct = 0; ct < 4; ++ct)
      vb[ct] = *(const short8*)(vbs + (ct * 16 + l15) * VSW + sc + quad * 8);
#pragma unroll
    for (int mt = 0; mt < 2; ++mt) {
      const int m = m0 + mt * 16 + l15;
      const f32x4 Ea = mt ? E10 : E00;
      const f32x4 Eb = mt ? E11 : E01;
      float p0[4], p1[4];
#pragma unroll
      for (int rr = 0; rr < 4; ++rr) {
        const float d0 = (float)(m - (sc + quad * 4 + rr));
        const float d1 = d0 - 16.0f;
        p0[rr] = __expf(Ea[rr] * __expf(-(d0 * d0) * INVW2));
        p1[rr] = __expf(Eb[rr] * __expf(-(d1 * d1) * INVW2));
        Sacc[mt] += p0[rr] + p1[rr];
      }
      union { short8 s; unsigned int u[4]; } pu;
      pu.u[0] = pack2(p0[0], p0[1]);
      pu.u[1] = pack2(p0[2], p0[3]);
      pu.u[2] = pack2(p1[0], p1[1]);
      pu.u[3] = pack2(p1[2], p1[3]);
#pragma unroll
      for (int ct = 0; ct < 4; ++ct)
        acc[mt][ct] = __builtin_amdgcn_mfma_f32_16x16x32_bf16(pu.s, vb[ct], acc[mt][ct], 0, 0, 0);
    }
  }

#pragma unroll
  for (int mt = 0; mt < 2; ++mt) {
    float s = Sacc[mt];
    s += __shfl_xor(s, 16);
    s += __shfl_xor(s, 32);
    if (lane < 16) Sw[rowbase + m0 + mt * 16 + l15] = s;
  }

  __syncthreads();  // vbs reads done; reuse as [c][480] transpose buffer
  unsigned short* ob = vbs;
#pragma unroll
  for (int mt = 0; mt < 2; ++mt)
#pragma unroll
    for (int ct = 0; ct < 4; ++ct)
#pragma unroll
      for (int rr = 0; rr < 4; ++rr)
        ob[(ct * 16 + l15) * VSW + m0 + mt * 16 + quad * 4 + rr] = f2bf(acc[mt][ct][rr]);
  __syncthreads();
  unsigned short* og = ow + ((size_t)b * H + h) * C * W;
  for (int idx = tid; idx < 64 * 240; idx += 960) {
    const int c = idx / 240, wp = idx - c * 240;
    *(unsigned int*)(og + (size_t)c * W + 2 * wp) =
        *(const unsigned int*)(ob + c * VSW + 2 * wp);
  }
}

// ---------------------------------------------------------------------------
// K3: out_h unnormalized + S_h. ONE block per (b,w): 576 thr = 9 waves,
// each wave 32 m-rows (M=288, rows >= 270 pad: loads clamped, p masked).
// Same swapped-QK register-resident P path. __launch_bounds__(576,4): cap 128
// regs (live state ~110). Round 0/1 used min-waves 5/6 -> cap 102/85 ->
// scratch spill (VGPR=48, WRITE_SIZE 300 MB). Outputs oht [b][w][c][h],
// Sht [b][w][h].
// ---------------------------------------------------------------------------
constexpr int VSH = 296;

__global__ __launch_bounds__(576, 4)
void k_outh(const unsigned short* __restrict__ qhp,
            const unsigned short* __restrict__ khp,
            const unsigned short* __restrict__ vt,
            unsigned short* __restrict__ oht, float* __restrict__ Sht) {
  __shared__ __align__(16) unsigned short vbs[18944];  // 64*296 u16 = 37888 B
  const int w = blockIdx.x, b = blockIdx.y;
  const int tid = threadIdx.x;

  const unsigned short* vtb = vt + ((size_t)b * W + w) * H * C;
  for (int idx = tid; idx < 288 * 16; idx += 576) {
    const int g = idx >> 4, c4 = (idx & 15) * 4;
    ushort4 vv = make_ushort4(0, 0, 0, 0);
    if (g < H) vv = *(const ushort4*)(vtb + (size_t)g * C + c4);
    const int u = g & 31;
    const int t = (u < 16) ? ((u >> 2) * 8 + (u & 3))
                           : (((u - 16) >> 2) * 8 + 4 + (u & 3));
    const int slot = (g & ~31) + t;
    vbs[(c4 + 0) * VSH + slot] = vv.x;
    vbs[(c4 + 1) * VSH + slot] = vv.y;
    vbs[(c4 + 2) * VSH + slot] = vv.z;
    vbs[(c4 + 3) * VSH + slot] = vv.w;
  }

  const int lane = tid & 63, wv = tid >> 6;
  const int l15 = lane & 15, quad = lane >> 4;
  const int m0 = wv * 32;
  const size_t colbase = ((size_t)b * W + w) * H;

  short8 qa0 = short8{0, 0, 0, 0, 0, 0, 0, 0};
  short8 qa1 = short8{0, 0, 0, 0, 0, 0, 0, 0};
  if (quad == 0) {
    qa0 = *(const short8*)(qhp + (colbase + min(m0 + l15, H - 1)) * 8);
    qa1 = *(const short8*)(qhp + (colbase + min(m0 + 16 + l15, H - 1)) * 8);
  }
  const unsigned short* kCol = khp + colbase * 8;

  f32x4 acc[2][4];
  float Sacc[2] = {0.0f, 0.0f};
#pragma unroll
  for (int mt = 0; mt < 2; ++mt)
#pragma unroll
    for (int ct = 0; ct < 4; ++ct)
#pragma unroll
      for (int rr = 0; rr < 4; ++rr) acc[mt][ct][rr] = 0.0f;

  __syncthreads();

  for (int ci = 0; ci < 9; ++ci) {
    const int gc = ci * 32;
    short8 kb0 = short8{0, 0, 0, 0, 0, 0, 0, 0};
    short8 kb1 = short8{0, 0, 0, 0, 0, 0, 0, 0};
    if (quad == 0) {
      kb0 = *(const short8*)(kCol + (size_t)min(gc + l15, H - 1) * 8);
      kb1 = *(const short8*)(kCol + (size_t)min(gc + 16 + l15, H - 1) * 8);
    }
    const f32x4 z4 = f32x4{0.f, 0.f, 0.f, 0.f};
    const f32x4 E00 = __builtin_amdgcn_mfma_f32_16x16x32_bf16(kb0, qa0, z4, 0, 0, 0);
    const f32x4 E01 = __builtin_amdgcn_mfma_f32_16x16x32_bf16(kb1, qa0, z4, 0, 0, 0);
    const f32x4 E10 = __builtin_amdgcn_mfma_f32_16x16x32_bf16(kb0, qa1, z4, 0, 0, 0);
    const f32x4 E11 = __builtin_amdgcn_mfma_f32_16x16x32_bf16(kb1, qa1, z4, 0, 0, 0);
    short8 vb[4];
#pragma unroll
    for (int ct = 0; ct < 4; ++ct)
      vb[ct] = *(const short8*)(vbs + (ct * 16 + l15) * VSH + gc + quad * 8);
#pragma unroll
    for (int mt = 0; mt < 2; ++mt) {
      const int m = m0 + mt * 16 + l15;
      const f32x4 Ea = mt ? E10 : E00;
      const f32x4 Eb = mt ? E11 : E01;
      float p0[4], p1[4];
#pragma unroll
      for (int rr = 0; rr < 4; ++rr) {
        const int g0 = gc + quad * 4 + rr;
        const int g1 = g0 + 16;
        const float d0 = (float)(m - g0);
        const float d1 = d0 - 16.0f;
        p0[rr] = (g0 < H && g0 != m)
                     ? __expf(Ea[rr] * __expf(-(d0 * d0) * INVH2)) : 0.0f;
        p1[rr] = (g1 < H && g1 != m)
                     ? __expf(Eb[rr] * __expf(-(d1 * d1) * INVH2)) : 0.0f;
        Sacc[mt] += p0[rr] + p1[rr];
      }
      union { short8 s; unsigned int u[4]; } pu;
      pu.u[0] = pack2(p0[0], p0[1]);
      pu.u[1] = pack2(p0[2], p0[3]);
      pu.u[2] = pack2(p1[0], p1[1]);
      pu.u[3] = pack2(p1[2], p1[3]);
#pragma unroll
      for (int ct = 0; ct < 4; ++ct)
        acc[mt][ct] = __builtin_amdgcn_mfma_f32_16x16x32_bf16(pu.s, vb[ct], acc[mt][ct], 0, 0, 0);
    }
  }

#pragma unroll
  for (int mt = 0; mt < 2; ++mt) {
    float s = Sacc[mt];
    s += __shfl_xor(s, 16);
    s += __shfl_xor(s, 32);
    const int m = m0 + mt * 16 + l15;
    if (lane < 16 && m < H) Sht[colbase + m] = s;
  }

  __syncthreads();
  unsigned short* ob = vbs;  // [c][288] stride 296
#pragma unroll
  for (int mt = 0; mt < 2; ++mt)
#pragma unroll
    for (int ct = 0; ct < 4; ++ct)
#pragma unroll
      for (int rr = 0; rr < 4; ++rr)
        ob[(ct * 16 + l15) * VSH + m0 + mt * 16 + quad * 4 + rr] = f2bf(acc[mt][ct][rr]);
  __syncthreads();
  unsigned short* og = oht + ((size_t)b * W + w) * C * H;
  for (int idx = tid; idx < 64 * 135; idx += 576) {
    const int c = idx / 135, hp = idx - c * 135;
    *(unsigned int*)(og + (size_t)c * H + 2 * hp) =
        *(const unsigned int*)(ob + c * VSH + 2 * hp);
  }
}

// ---------------------------------------------------------------------------
// K4: out = gamma*(U_h + U_w)/(S_h+S_w) + x, LDS tile transpose for oht.
// Sht is [b][w][h] (1 MB, L2-resident, 64x c-reuse -> strided read is cheap).
// ---------------------------------------------------------------------------
__global__ __launch_bounds__(256)
void k_combine(const unsigned short* __restrict__ oht,
               const unsigned short* __restrict__ ow,
               const float* __restrict__ Sht, const float* __restrict__ Sw,
               const float* __restrict__ x,
               const float* __restrict__ gp,
               float* __restrict__ out) {
  __shared__ float tile[32][33];
  const int b = blockIdx.z >> 6, c = blockIdx.z & 63;
  const int w0 = blockIdx.x * 32, h0 = blockIdx.y * 32;
  const int tx = threadIdx.x, ty = threadIdx.y;  // (32, 8)
#pragma unroll
  for (int i = 0; i < 4; ++i) {
    const int wl = ty + i * 8;
    const int hh = h0 + tx;
    float val = 0.0f;
    if (hh < H) val = bits2f(oht[(((size_t)b * W + (w0 + wl)) * C + c) * H + hh]);
    tile[wl][tx] = val;
  }
  __syncthreads();
  const float gamma = *gp;
#pragma unroll
  for (int i = 0; i < 4; ++i) {
    const int hl = ty + i * 8;
    const int hh = h0 + hl;
    if (hh < H) {
      const int ww = w0 + tx;
      const float uh = tile[tx][hl];
      const float uw = bits2f(ow[(((size_t)b * H + hh) * C + c) * W + ww]);
      const size_t si = ((size_t)b * H + hh) * W + ww;
      const float Z = Sht[((size_t)b * W + ww) * H + hh] + Sw[si];
      const float invZ = __builtin_amdgcn_rcpf(Z);
      const size_t xi = ((size_t)b * C + c) * HW + (size_t)hh * W + ww;
      out[xi] = fmaf(gamma * invZ, uh + uw, x[xi]);
    }
  }
}

}  // namespace

extern "C" void kernel_launch(void* const* d_in, const int* in_sizes, int n_in,
                              void* d_out, int out_size, void* d_ws, size_t ws_size,
                              hipStream_t stream) {
  (void)in_sizes; (void)n_in; (void)out_size; (void)ws_size;
  const float* x  = (const float*)d_in[0];
  const float* Wq = (const float*)d_in[1];
  const float* bq = (const float*)d_in[2];
  const float* Wk = (const float*)d_in[3];
  const float* bk = (const float*)d_in[4];
  const float* Wv = (const float*)d_in[5];
  const float* bv = (const float*)d_in[6];
  const float* gp = (const float*)d_in[7];
  float* out = (float*)d_out;

  char* p = (char*)d_ws;
  auto take = [&](size_t bytes) -> void* {
    char* r = p;
    p += (bytes + 255) & ~(size_t)255;
    return (void*)r;
  };
  unsigned short* qwp = (unsigned short*)take(sizeof(unsigned short) * (size_t)B * HW * 8);
  unsigned short* kwp = (unsigned short*)take(sizeof(unsigned short) * (size_t)B * HW * 8);
  unsigned short* qhp = (unsigned short*)take(sizeof(unsigned short) * (size_t)B * HW * 8);
  unsigned short* khp = (unsigned short*)take(sizeof(unsigned short) * (size_t)B * HW * 8);
  unsigned short* v   = (unsigned short*)take(sizeof(unsigned short) * (size_t)B * C * HW);
  unsigned short* vt  = (unsigned short*)take(sizeof(unsigned short) * (size_t)B * C * HW);
  unsigned short* oht = (unsigned short*)take(sizeof(unsigned short) * (size_t)B * C * HW);
  unsigned short* owb = (unsigned short*)take(sizeof(unsigned short) * (size_t)B * C * HW);
  float* Sht = (float*)take(sizeof(float) * (size_t)B * HW);
  float* Sw  = (float*)take(sizeof(float) * (size_t)B * HW);

  hipLaunchKernelGGL(k_qkv, dim3((B * HW + 255) / 256), dim3(256), 0, stream,
                     x, Wq, bq, Wk, bk, Wv, bv, qwp, kwp, qhp, khp, v, vt);
  hipLaunchKernelGGL(k_outh, dim3(W, B), dim3(576), 0, stream,
                     qhp, khp, vt, oht, Sht);
  hipLaunchKernelGGL(k_outw, dim3(H, B), dim3(960), 0, stream,
                     qwp, kwp, v, owb, Sw);
  hipLaunchKernelGGL(k_combine, dim3(W / 32, (H + 31) / 32, B * C), dim3(32, 8), 0, stream,
                     oht, owb, Sht, Sw, x, gp, out);
}

// Round 3
// 456.135 us; speedup vs baseline: 1.5466x; 1.0828x over previous
//
#include <hip/hip_runtime.h>
#include <hip/hip_bf16.h>

namespace {

constexpr int B  = 2;
constexpr int C  = 64;
constexpr int CQ = 8;
constexpr int H  = 270;
constexpr int W  = 480;
constexpr int HW = H * W;
constexpr float INVH2 = 2.0f / (270.0f * 270.0f);  // dw_h = exp(-d^2 * INVH2)
constexpr float INVW2 = 2.0f / (480.0f * 480.0f);

typedef __attribute__((ext_vector_type(4))) float f32x4;
typedef __attribute__((ext_vector_type(8))) short short8;

__device__ __forceinline__ float bits2f(unsigned short u) {
  union { unsigned int i; float f; } cv;
  cv.i = ((unsigned int)u) << 16;
  return cv.f;
}

__device__ __forceinline__ unsigned short f2bf(float f) {
  union { __hip_bfloat16 b; unsigned short u; } cv;
  cv.b = __float2bfloat16(f);
  return cv.u;
}

__device__ __forceinline__ unsigned int pack2(float a, float b) {
  return ((unsigned int)f2bf(b) << 16) | (unsigned int)f2bf(a);
}

// V-row permutation inside each 32-row K-step so that the swapped-QK P layout
// (lane quad q holds g = 4q+rr from E0 and 16+4q+rr from E1) feeds the PV
// A-fragment (k-slot q*8+j) with NO cross-lane data movement:
//   u < 16: slot = 8*(u>>2) + (u&3);  u >= 16: slot = 8*((u-16)>>2) + 4 + (u&3)

// ---------------------------------------------------------------------------
// K1: q/k/v 1x1 projections. One thread per pixel. Writes bf16 packs:
// qwp/kwp [b][h][w][8], qhp/khp [b][w][h][8], v [b][c][h][w], vt [b][w][h][c].
// ---------------------------------------------------------------------------
__global__ __launch_bounds__(256)
void k_qkv(const float* __restrict__ x,
           const float* __restrict__ Wq, const float* __restrict__ bq,
           const float* __restrict__ Wk, const float* __restrict__ bk,
           const float* __restrict__ Wv, const float* __restrict__ bv,
           unsigned short* __restrict__ qwp, unsigned short* __restrict__ kwp,
           unsigned short* __restrict__ qhp, unsigned short* __restrict__ khp,
           unsigned short* __restrict__ v, unsigned short* __restrict__ vt) {
  __shared__ __align__(16) float wql[CQ * C];
  __shared__ __align__(16) float wkl[CQ * C];
  __shared__ __align__(16) float wvl[C * C];
  __shared__ float bql[CQ], bkl[CQ], bvl[C];
  const int tid = threadIdx.x;
  for (int i = tid; i < CQ * C; i += 256) { wql[i] = Wq[i]; wkl[i] = Wk[i]; }
  for (int i = tid; i < C * C; i += 256) wvl[i] = Wv[i];
  if (tid < CQ) { bql[tid] = bq[tid]; bkl[tid] = bk[tid]; }
  if (tid < C) bvl[tid] = bv[tid];
  __syncthreads();
  const int pix = blockIdx.x * 256 + tid;
  if (pix >= B * HW) return;
  const int b = pix / HW;
  const int r = pix - b * HW;
  const int h = r / W;
  const int w = r - h * W;

  float qa[CQ], ka[CQ], va[C];
#pragma unroll
  for (int o = 0; o < CQ; ++o) { qa[o] = bql[o]; ka[o] = bkl[o]; }
#pragma unroll
  for (int o = 0; o < C; ++o) va[o] = bvl[o];

  const float* xp = x + (size_t)b * C * HW + r;
  for (int c = 0; c < C; c += 4) {
    const float x0 = xp[(size_t)(c + 0) * HW];
    const float x1 = xp[(size_t)(c + 1) * HW];
    const float x2 = xp[(size_t)(c + 2) * HW];
    const float x3 = xp[(size_t)(c + 3) * HW];
#pragma unroll
    for (int o = 0; o < CQ; ++o) {
      const float4 a = *(const float4*)(wql + o * C + c);
      qa[o] = fmaf(a.w, x3, fmaf(a.z, x2, fmaf(a.y, x1, fmaf(a.x, x0, qa[o]))));
      const float4 bb = *(const float4*)(wkl + o * C + c);
      ka[o] = fmaf(bb.w, x3, fmaf(bb.z, x2, fmaf(bb.y, x1, fmaf(bb.x, x0, ka[o]))));
    }
#pragma unroll
    for (int o = 0; o < C; ++o) {
      const float4 cc = *(const float4*)(wvl + o * C + c);
      va[o] = fmaf(cc.w, x3, fmaf(cc.z, x2, fmaf(cc.y, x1, fmaf(cc.x, x0, va[o]))));
    }
  }

  uint4 qp4, kp4;
  qp4.x = pack2(qa[0], qa[1]); qp4.y = pack2(qa[2], qa[3]);
  qp4.z = pack2(qa[4], qa[5]); qp4.w = pack2(qa[6], qa[7]);
  kp4.x = pack2(ka[0], ka[1]); kp4.y = pack2(ka[2], ka[3]);
  kp4.z = pack2(ka[4], ka[5]); kp4.w = pack2(ka[6], ka[7]);
  *(uint4*)(qwp + (size_t)pix * 8) = qp4;
  *(uint4*)(kwp + (size_t)pix * 8) = kp4;
  const size_t tbase = ((size_t)b * W + w) * H + h;
  *(uint4*)(qhp + tbase * 8) = qp4;
  *(uint4*)(khp + tbase * 8) = kp4;

  unsigned short* vp = v + (size_t)b * C * HW + r;
#pragma unroll
  for (int o = 0; o < C; ++o) vp[(size_t)o * HW] = f2bf(va[o]);
  unsigned short* vtp = vt + tbase * C;
#pragma unroll
  for (int j = 0; j < 16; ++j) {
    ushort4 u;
    u.x = f2bf(va[4 * j + 0]);
    u.y = f2bf(va[4 * j + 1]);
    u.z = f2bf(va[4 * j + 2]);
    u.w = f2bf(va[4 * j + 3]);
    *(ushort4*)(vtp + 4 * j) = u;
  }
}

// ---------------------------------------------------------------------------
// K2: out_w unnormalized + S_w. ONE block per (b,h): 960 thr = 15 waves,
// each wave owns 32 m-rows (M=480). Swapped QK (mfma(K,Q)) puts P with
// m=lane&15, g in regs -> exp + pack2 in registers feeds PV A-frag directly
// (V rows stored k-slot-permuted in LDS). No P LDS round-trip, no dw table.
// __launch_bounds__(960,1): min-waves is a MINIMUM occupancy demand -> it
// SHRINKS the reg cap. (960,4) forced 2 blocks/CU = 8 waves/SIMD = cap 64
// -> severe spill (round 2). With min=1 the only constraint is 1-block
// residency: ceil(15/4)=4 waves/SIMD -> cap 128 >= ~110 live -> no spill.
// ---------------------------------------------------------------------------
constexpr int VSW = 488;

__global__ __launch_bounds__(960, 1)
void k_outw(const unsigned short* __restrict__ qwp,
            const unsigned short* __restrict__ kwp,
            const unsigned short* __restrict__ v,
            unsigned short* __restrict__ ow, float* __restrict__ Sw) {
  __shared__ __align__(16) unsigned short vbs[31232];  // 64*488 u16 = 62464 B
  const int h = blockIdx.x, b = blockIdx.y;
  const int tid = threadIdx.x;

  const unsigned short* vrow = v + (size_t)b * C * HW + (size_t)h * W;
  for (int idx = tid; idx < 64 * 120; idx += 960) {
    const int c = idx / 120, s4 = (idx - c * 120) * 4;
    const int u = s4 & 31;  // multiple of 4
    const int t = (u < 16) ? ((u >> 2) * 8) : (((u - 16) >> 2) * 8 + 4);
    *(ushort4*)(vbs + c * VSW + (s4 & ~31) + t) =
        *(const ushort4*)(vrow + (size_t)c * HW + s4);
  }

  const int lane = tid & 63, wv = tid >> 6;
  const int l15 = lane & 15, quad = lane >> 4;
  const int m0 = wv * 32;
  const size_t rowbase = ((size_t)b * H + h) * W;

  short8 qa0 = short8{0, 0, 0, 0, 0, 0, 0, 0};
  short8 qa1 = short8{0, 0, 0, 0, 0, 0, 0, 0};
  if (quad == 0) {
    qa0 = *(const short8*)(qwp + (rowbase + m0 + l15) * 8);
    qa1 = *(const short8*)(qwp + (rowbase + m0 + 16 + l15) * 8);
  }
  const unsigned short* kRow = kwp + rowbase * 8;

  f32x4 acc[2][4];
  float Sacc[2] = {0.0f, 0.0f};
#pragma unroll
  for (int mt = 0; mt < 2; ++mt)
#pragma unroll
    for (int ct = 0; ct < 4; ++ct)
#pragma unroll
      for (int rr = 0; rr < 4; ++rr) acc[mt][ct][rr] = 0.0f;

  __syncthreads();

  for (int ci = 0; ci < 15; ++ci) {
    const int sc = ci * 32;
    short8 kb0 = short8{0, 0, 0, 0, 0, 0, 0, 0};
    short8 kb1 = short8{0, 0, 0, 0, 0, 0, 0, 0};
    if (quad == 0) {
      kb0 = *(const short8*)(kRow + (size_t)(sc + l15) * 8);
      kb1 = *(const short8*)(kRow + (size_t)(sc + 16 + l15) * 8);
    }
    const f32x4 z4 = f32x4{0.f, 0.f, 0.f, 0.f};
    const f32x4 E00 = __builtin_amdgcn_mfma_f32_16x16x32_bf16(kb0, qa0, z4, 0, 0, 0);
    const f32x4 E01 = __builtin_amdgcn_mfma_f32_16x16x32_bf16(kb1, qa0, z4, 0, 0, 0);
    const f32x4 E10 = __builtin_amdgcn_mfma_f32_16x16x32_bf16(kb0, qa1, z4, 0, 0, 0);
    const f32x4 E11 = __builtin_amdgcn_mfma_f32_16x16x32_bf16(kb1, qa1, z4, 0, 0, 0);
    short8 vb[4];
#pragma unroll
    for (int ct = 0; ct < 4; ++ct)
      vb[ct] = *(const short8*)(vbs + (ct * 16 + l15) * VSW + sc + quad * 8);
#pragma unroll
    for (int mt = 0; mt < 2; ++mt) {
      const int m = m0 + mt * 16 + l15;
      const f32x4 Ea = mt ? E10 : E00;
      const f32x4 Eb = mt ? E11 : E01;
      float p0[4], p1[4];
#pragma unroll
      for (int rr = 0; rr < 4; ++rr) {
        const float d0 = (float)(m - (sc + quad * 4 + rr));
        const float d1 = d0 - 16.0f;
        p0[rr] = __expf(Ea[rr] * __expf(-(d0 * d0) * INVW2));
        p1[rr] = __expf(Eb[rr] * __expf(-(d1 * d1) * INVW2));
        Sacc[mt] += p0[rr] + p1[rr];
      }
      union { short8 s; unsigned int u[4]; } pu;
      pu.u[0] = pack2(p0[0], p0[1]);
      pu.u[1] = pack2(p0[2], p0[3]);
      pu.u[2] = pack2(p1[0], p1[1]);
      pu.u[3] = pack2(p1[2], p1[3]);
#pragma unroll
      for (int ct = 0; ct < 4; ++ct)
        acc[mt][ct] = __builtin_amdgcn_mfma_f32_16x16x32_bf16(pu.s, vb[ct], acc[mt][ct], 0, 0, 0);
    }
  }

#pragma unroll
  for (int mt = 0; mt < 2; ++mt) {
    float s = Sacc[mt];
    s += __shfl_xor(s, 16);
    s += __shfl_xor(s, 32);
    if (lane < 16) Sw[rowbase + m0 + mt * 16 + l15] = s;
  }

  __syncthreads();  // vbs reads done; reuse as [c][480] transpose buffer
  unsigned short* ob = vbs;
#pragma unroll
  for (int mt = 0; mt < 2; ++mt)
#pragma unroll
    for (int ct = 0; ct < 4; ++ct)
#pragma unroll
      for (int rr = 0; rr < 4; ++rr)
        ob[(ct * 16 + l15) * VSW + m0 + mt * 16 + quad * 4 + rr] = f2bf(acc[mt][ct][rr]);
  __syncthreads();
  unsigned short* og = ow + ((size_t)b * H + h) * C * W;
  for (int idx = tid; idx < 64 * 240; idx += 960) {
    const int c = idx / 240, wp = idx - c * 240;
    *(unsigned int*)(og + (size_t)c * W + 2 * wp) =
        *(const unsigned int*)(ob + c * VSW + 2 * wp);
  }
}

// ---------------------------------------------------------------------------
// K3: out_h unnormalized + S_h. ONE block per (b,w): 576 thr = 9 waves,
// each wave 32 m-rows (M=288, rows >= 270 pad: loads clamped, p masked).
// Same swapped-QK register-resident P path. __launch_bounds__(576,1):
// (576,4) forced 2-block residency -> cap 96 (64V+32A) -> spill (round 2:
// VGPR=64, WRITE 226 MB vs 34 real). min=1 -> cap = 512/ceil(9/4) = 170,
// compiler allocates the ~110 it needs, zero scratch.
// Outputs oht [b][w][c][h], Sht [b][w][h].
// ---------------------------------------------------------------------------
constexpr int VSH = 296;

__global__ __launch_bounds__(576, 1)
void k_outh(const unsigned short* __restrict__ qhp,
            const unsigned short* __restrict__ khp,
            const unsigned short* __restrict__ vt,
            unsigned short* __restrict__ oht, float* __restrict__ Sht) {
  __shared__ __align__(16) unsigned short vbs[18944];  // 64*296 u16 = 37888 B
  const int w = blockIdx.x, b = blockIdx.y;
  const int tid = threadIdx.x;

  const unsigned short* vtb = vt + ((size_t)b * W + w) * H * C;
  for (int idx = tid; idx < 288 * 16; idx += 576) {
    const int g = idx >> 4, c4 = (idx & 15) * 4;
    ushort4 vv = make_ushort4(0, 0, 0, 0);
    if (g < H) vv = *(const ushort4*)(vtb + (size_t)g * C + c4);
    const int u = g & 31;
    const int t = (u < 16) ? ((u >> 2) * 8 + (u & 3))
                           : (((u - 16) >> 2) * 8 + 4 + (u & 3));
    const int slot = (g & ~31) + t;
    vbs[(c4 + 0) * VSH + slot] = vv.x;
    vbs[(c4 + 1) * VSH + slot] = vv.y;
    vbs[(c4 + 2) * VSH + slot] = vv.z;
    vbs[(c4 + 3) * VSH + slot] = vv.w;
  }

  const int lane = tid & 63, wv = tid >> 6;
  const int l15 = lane & 15, quad = lane >> 4;
  const int m0 = wv * 32;
  const size_t colbase = ((size_t)b * W + w) * H;

  short8 qa0 = short8{0, 0, 0, 0, 0, 0, 0, 0};
  short8 qa1 = short8{0, 0, 0, 0, 0, 0, 0, 0};
  if (quad == 0) {
    qa0 = *(const short8*)(qhp + (colbase + min(m0 + l15, H - 1)) * 8);
    qa1 = *(const short8*)(qhp + (colbase + min(m0 + 16 + l15, H - 1)) * 8);
  }
  const unsigned short* kCol = khp + colbase * 8;

  f32x4 acc[2][4];
  float Sacc[2] = {0.0f, 0.0f};
#pragma unroll
  for (int mt = 0; mt < 2; ++mt)
#pragma unroll
    for (int ct = 0; ct < 4; ++ct)
#pragma unroll
      for (int rr = 0; rr < 4; ++rr) acc[mt][ct][rr] = 0.0f;

  __syncthreads();

  for (int ci = 0; ci < 9; ++ci) {
    const int gc = ci * 32;
    short8 kb0 = short8{0, 0, 0, 0, 0, 0, 0, 0};
    short8 kb1 = short8{0, 0, 0, 0, 0, 0, 0, 0};
    if (quad == 0) {
      kb0 = *(const short8*)(kCol + (size_t)min(gc + l15, H - 1) * 8);
      kb1 = *(const short8*)(kCol + (size_t)min(gc + 16 + l15, H - 1) * 8);
    }
    const f32x4 z4 = f32x4{0.f, 0.f, 0.f, 0.f};
    const f32x4 E00 = __builtin_amdgcn_mfma_f32_16x16x32_bf16(kb0, qa0, z4, 0, 0, 0);
    const f32x4 E01 = __builtin_amdgcn_mfma_f32_16x16x32_bf16(kb1, qa0, z4, 0, 0, 0);
    const f32x4 E10 = __builtin_amdgcn_mfma_f32_16x16x32_bf16(kb0, qa1, z4, 0, 0, 0);
    const f32x4 E11 = __builtin_amdgcn_mfma_f32_16x16x32_bf16(kb1, qa1, z4, 0, 0, 0);
    short8 vb[4];
#pragma unroll
    for (int ct = 0; ct < 4; ++ct)
      vb[ct] = *(const short8*)(vbs + (ct * 16 + l15) * VSH + gc + quad * 8);
#pragma unroll
    for (int mt = 0; mt < 2; ++mt) {
      const int m = m0 + mt * 16 + l15;
      const f32x4 Ea = mt ? E10 : E00;
      const f32x4 Eb = mt ? E11 : E01;
      float p0[4], p1[4];
#pragma unroll
      for (int rr = 0; rr < 4; ++rr) {
        const int g0 = gc + quad * 4 + rr;
        const int g1 = g0 + 16;
        const float d0 = (float)(m - g0);
        const float d1 = d0 - 16.0f;
        p0[rr] = (g0 < H && g0 != m)
                     ? __expf(Ea[rr] * __expf(-(d0 * d0) * INVH2)) : 0.0f;
        p1[rr] = (g1 < H && g1 != m)
                     ? __expf(Eb[rr] * __expf(-(d1 * d1) * INVH2)) : 0.0f;
        Sacc[mt] += p0[rr] + p1[rr];
      }
      union { short8 s; unsigned int u[4]; } pu;
      pu.u[0] = pack2(p0[0], p0[1]);
      pu.u[1] = pack2(p0[2], p0[3]);
      pu.u[2] = pack2(p1[0], p1[1]);
      pu.u[3] = pack2(p1[2], p1[3]);
#pragma unroll
      for (int ct = 0; ct < 4; ++ct)
        acc[mt][ct] = __builtin_amdgcn_mfma_f32_16x16x32_bf16(pu.s, vb[ct], acc[mt][ct], 0, 0, 0);
    }
  }

#pragma unroll
  for (int mt = 0; mt < 2; ++mt) {
    float s = Sacc[mt];
    s += __shfl_xor(s, 16);
    s += __shfl_xor(s, 32);
    const int m = m0 + mt * 16 + l15;
    if (lane < 16 && m < H) Sht[colbase + m] = s;
  }

  __syncthreads();
  unsigned short* ob = vbs;  // [c][288] stride 296
#pragma unroll
  for (int mt = 0; mt < 2; ++mt)
#pragma unroll
    for (int ct = 0; ct < 4; ++ct)
#pragma unroll
      for (int rr = 0; rr < 4; ++rr)
        ob[(ct * 16 + l15) * VSH + m0 + mt * 16 + quad * 4 + rr] = f2bf(acc[mt][ct][rr]);
  __syncthreads();
  unsigned short* og = oht + ((size_t)b * W + w) * C * H;
  for (int idx = tid; idx < 64 * 135; idx += 576) {
    const int c = idx / 135, hp = idx - c * 135;
    *(unsigned int*)(og + (size_t)c * H + 2 * hp) =
        *(const unsigned int*)(ob + c * VSH + 2 * hp);
  }
}

// ---------------------------------------------------------------------------
// K4: out = gamma*(U_h + U_w)/(S_h+S_w) + x, LDS tile transpose for oht.
// Sht is [b][w][h] (1 MB, L2-resident, 64x c-reuse -> strided read is cheap).
// ---------------------------------------------------------------------------
__global__ __launch_bounds__(256)
void k_combine(const unsigned short* __restrict__ oht,
               const unsigned short* __restrict__ ow,
               const float* __restrict__ Sht, const float* __restrict__ Sw,
               const float* __restrict__ x,
               const float* __restrict__ gp,
               float* __restrict__ out) {
  __shared__ float tile[32][33];
  const int b = blockIdx.z >> 6, c = blockIdx.z & 63;
  const int w0 = blockIdx.x * 32, h0 = blockIdx.y * 32;
  const int tx = threadIdx.x, ty = threadIdx.y;  // (32, 8)
#pragma unroll
  for (int i = 0; i < 4; ++i) {
    const int wl = ty + i * 8;
    const int hh = h0 + tx;
    float val = 0.0f;
    if (hh < H) val = bits2f(oht[(((size_t)b * W + (w0 + wl)) * C + c) * H + hh]);
    tile[wl][tx] = val;
  }
  __syncthreads();
  const float gamma = *gp;
#pragma unroll
  for (int i = 0; i < 4; ++i) {
    const int hl = ty + i * 8;
    const int hh = h0 + hl;
    if (hh < H) {
      const int ww = w0 + tx;
      const float uh = tile[tx][hl];
      const float uw = bits2f(ow[(((size_t)b * H + hh) * C + c) * W + ww]);
      const size_t si = ((size_t)b * H + hh) * W + ww;
      const float Z = Sht[((size_t)b * W + ww) * H + hh] + Sw[si];
      const float invZ = __builtin_amdgcn_rcpf(Z);
      const size_t xi = ((size_t)b * C + c) * HW + (size_t)hh * W + ww;
      out[xi] = fmaf(gamma * invZ, uh + uw, x[xi]);
    }
  }
}

}  // namespace

extern "C" void kernel_launch(void* const* d_in, const int* in_sizes, int n_in,
                              void* d_out, int out_size, void* d_ws, size_t ws_size,
                              hipStream_t stream) {
  (void)in_sizes; (void)n_in; (void)out_size; (void)ws_size;
  const float* x  = (const float*)d_in[0];
  const float* Wq = (const float*)d_in[1];
  const float* bq = (const float*)d_in[2];
  const float* Wk = (const float*)d_in[3];
  const float* bk = (const float*)d_in[4];
  const float* Wv = (const float*)d_in[5];
  const float* bv = (const float*)d_in[6];
  const float* gp = (const float*)d_in[7];
  float* out = (float*)d_out;

  char* p = (char*)d_ws;
  auto take = [&](size_t bytes) -> void* {
    char* r = p;
    p += (bytes + 255) & ~(size_t)255;
    return (void*)r;
  };
  unsigned short* qwp = (unsigned short*)take(sizeof(unsigned short) * (size_t)B * HW * 8);
  unsigned short* kwp = (unsigned short*)take(sizeof(unsigned short) * (size_t)B * HW * 8);
  unsigned short* qhp = (unsigned short*)take(sizeof(unsigned short) * (size_t)B * HW * 8);
  unsigned short* khp = (unsigned short*)take(sizeof(unsigned short) * (size_t)B * HW * 8);
  unsigned short* v   = (unsigned short*)take(sizeof(unsigned short) * (size_t)B * C * HW);
  unsigned short* vt  = (unsigned short*)take(sizeof(unsigned short) * (size_t)B * C * HW);
  unsigned short* oht = (unsigned short*)take(sizeof(unsigned short) * (size_t)B * C * HW);
  unsigned short* owb = (unsigned short*)take(sizeof(unsigned short) * (size_t)B * C * HW);
  float* Sht = (float*)take(sizeof(float) * (size_t)B * HW);
  float* Sw  = (float*)take(sizeof(float) * (size_t)B * HW);

  hipLaunchKernelGGL(k_qkv, dim3((B * HW + 255) / 256), dim3(256), 0, stream,
                     x, Wq, bq, Wk, bk, Wv, bv, qwp, kwp, qhp, khp, v, vt);
  hipLaunchKernelGGL(k_outh, dim3(W, B), dim3(576), 0, stream,
                     qhp, khp, vt, oht, Sht);
  hipLaunchKernelGGL(k_outw, dim3(H, B), dim3(960), 0, stream,
                     qwp, kwp, v, owb, Sw);
  hipLaunchKernelGGL(k_combine, dim3(W / 32, (H + 31) / 32, B * C), dim3(32, 8), 0, stream,
                     oht, owb, Sht, Sw, x, gp, out);
}

// Round 4
// 454.067 us; speedup vs baseline: 1.5536x; 1.0046x over previous
//
#include <hip/hip_runtime.h>
#include <hip/hip_bf16.h>

namespace {

constexpr int B  = 2;
constexpr int C  = 64;
constexpr int CQ = 8;
constexpr int H  = 270;
constexpr int W  = 480;
constexpr int HW = H * W;
constexpr float INVH2 = 2.0f / (270.0f * 270.0f);  // dw_h = exp(-d^2 * INVH2)
constexpr float INVW2 = 2.0f / (480.0f * 480.0f);

typedef __attribute__((ext_vector_type(4))) float f32x4;
typedef __attribute__((ext_vector_type(8))) short short8;
typedef __attribute__((ext_vector_type(4))) unsigned int uint4v;

__device__ __forceinline__ float bits2f(unsigned short u) {
  union { unsigned int i; float f; } cv;
  cv.i = ((unsigned int)u) << 16;
  return cv.f;
}

__device__ __forceinline__ unsigned short f2bf(float f) {
  union { __hip_bfloat16 b; unsigned short u; } cv;
  cv.b = __float2bfloat16(f);
  return cv.u;
}

__device__ __forceinline__ unsigned int pack2(float a, float b) {
  return ((unsigned int)f2bf(b) << 16) | (unsigned int)f2bf(a);
}

// Build the PV A-fragment (short8) from 8 P floats ENTIRELY in registers.
// The previous union{short8;u32[4]} pattern defeated SROA and was lowered to
// scratch: 16 B written+read per mt per K-iter = ~159 MB/dispatch of scratch
// traffic (matches the 99 MB WRITE excess seen in rounds 0-3).
__device__ __forceinline__ short8 pack_p(const float p0[4], const float p1[4]) {
  uint4v pw;
  pw[0] = pack2(p0[0], p0[1]);
  pw[1] = pack2(p0[2], p0[3]);
  pw[2] = pack2(p1[0], p1[1]);
  pw[3] = pack2(p1[2], p1[3]);
  return __builtin_bit_cast(short8, pw);
}

// V-row permutation inside each 32-row K-step so that the swapped-QK P layout
// (lane quad q holds g = 4q+rr from E0 and 16+4q+rr from E1) feeds the PV
// A-fragment (k-slot q*8+j) with NO cross-lane data movement:
//   u < 16: slot = 8*(u>>2) + (u&3);  u >= 16: slot = 8*((u-16)>>2) + 4 + (u&3)

// ---------------------------------------------------------------------------
// K1: q/k/v 1x1 projections. One thread per pixel. Writes bf16 packs:
// qwp/kwp [b][h][w][8], qhp/khp [b][w][h][8], v [b][c][h][w], vt [b][w][h][c].
// ---------------------------------------------------------------------------
__global__ __launch_bounds__(256)
void k_qkv(const float* __restrict__ x,
           const float* __restrict__ Wq, const float* __restrict__ bq,
           const float* __restrict__ Wk, const float* __restrict__ bk,
           const float* __restrict__ Wv, const float* __restrict__ bv,
           unsigned short* __restrict__ qwp, unsigned short* __restrict__ kwp,
           unsigned short* __restrict__ qhp, unsigned short* __restrict__ khp,
           unsigned short* __restrict__ v, unsigned short* __restrict__ vt) {
  __shared__ __align__(16) float wql[CQ * C];
  __shared__ __align__(16) float wkl[CQ * C];
  __shared__ __align__(16) float wvl[C * C];
  __shared__ float bql[CQ], bkl[CQ], bvl[C];
  const int tid = threadIdx.x;
  for (int i = tid; i < CQ * C; i += 256) { wql[i] = Wq[i]; wkl[i] = Wk[i]; }
  for (int i = tid; i < C * C; i += 256) wvl[i] = Wv[i];
  if (tid < CQ) { bql[tid] = bq[tid]; bkl[tid] = bk[tid]; }
  if (tid < C) bvl[tid] = bv[tid];
  __syncthreads();
  const int pix = blockIdx.x * 256 + tid;
  if (pix >= B * HW) return;
  const int b = pix / HW;
  const int r = pix - b * HW;
  const int h = r / W;
  const int w = r - h * W;

  float qa[CQ], ka[CQ], va[C];
#pragma unroll
  for (int o = 0; o < CQ; ++o) { qa[o] = bql[o]; ka[o] = bkl[o]; }
#pragma unroll
  for (int o = 0; o < C; ++o) va[o] = bvl[o];

  const float* xp = x + (size_t)b * C * HW + r;
  for (int c = 0; c < C; c += 4) {
    const float x0 = xp[(size_t)(c + 0) * HW];
    const float x1 = xp[(size_t)(c + 1) * HW];
    const float x2 = xp[(size_t)(c + 2) * HW];
    const float x3 = xp[(size_t)(c + 3) * HW];
#pragma unroll
    for (int o = 0; o < CQ; ++o) {
      const float4 a = *(const float4*)(wql + o * C + c);
      qa[o] = fmaf(a.w, x3, fmaf(a.z, x2, fmaf(a.y, x1, fmaf(a.x, x0, qa[o]))));
      const float4 bb = *(const float4*)(wkl + o * C + c);
      ka[o] = fmaf(bb.w, x3, fmaf(bb.z, x2, fmaf(bb.y, x1, fmaf(bb.x, x0, ka[o]))));
    }
#pragma unroll
    for (int o = 0; o < C; ++o) {
      const float4 cc = *(const float4*)(wvl + o * C + c);
      va[o] = fmaf(cc.w, x3, fmaf(cc.z, x2, fmaf(cc.y, x1, fmaf(cc.x, x0, va[o]))));
    }
  }

  uint4 qp4, kp4;
  qp4.x = pack2(qa[0], qa[1]); qp4.y = pack2(qa[2], qa[3]);
  qp4.z = pack2(qa[4], qa[5]); qp4.w = pack2(qa[6], qa[7]);
  kp4.x = pack2(ka[0], ka[1]); kp4.y = pack2(ka[2], ka[3]);
  kp4.z = pack2(ka[4], ka[5]); kp4.w = pack2(ka[6], ka[7]);
  *(uint4*)(qwp + (size_t)pix * 8) = qp4;
  *(uint4*)(kwp + (size_t)pix * 8) = kp4;
  const size_t tbase = ((size_t)b * W + w) * H + h;
  *(uint4*)(qhp + tbase * 8) = qp4;
  *(uint4*)(khp + tbase * 8) = kp4;

  unsigned short* vp = v + (size_t)b * C * HW + r;
#pragma unroll
  for (int o = 0; o < C; ++o) vp[(size_t)o * HW] = f2bf(va[o]);
  unsigned short* vtp = vt + tbase * C;
#pragma unroll
  for (int j = 0; j < 16; ++j) {
    ushort4 u;
    u.x = f2bf(va[4 * j + 0]);
    u.y = f2bf(va[4 * j + 1]);
    u.z = f2bf(va[4 * j + 2]);
    u.w = f2bf(va[4 * j + 3]);
    *(ushort4*)(vtp + 4 * j) = u;
  }
}

// ---------------------------------------------------------------------------
// K2: out_w unnormalized + S_w. ONE block per (b,h): 960 thr = 15 waves,
// each wave owns 32 m-rows (M=480). Swapped QK (mfma(K,Q)) puts P with
// m=lane&15, g in regs -> exp + register pack feeds PV A-frag directly
// (V rows stored k-slot-permuted in LDS). K column ALSO staged in LDS once:
// the K-loop touches no global memory at all (ds_read ~120cy vs global
// ~300-900cy; 15 waves all re-read the same column).
// __launch_bounds__(960,1): min-waves is a MINIMUM occupancy demand (shrinks
// the reg cap); min=1 leaves the cap at 1-block residency = 128/wave.
// ---------------------------------------------------------------------------
constexpr int VSW = 488;

__global__ __launch_bounds__(960, 1)
void k_outw(const unsigned short* __restrict__ qwp,
            const unsigned short* __restrict__ kwp,
            const unsigned short* __restrict__ v,
            unsigned short* __restrict__ ow, float* __restrict__ Sw) {
  __shared__ __align__(16) unsigned short vbs[31232];  // 64*488 u16 = 62464 B
  __shared__ __align__(16) unsigned short kls[480 * 8];  // 7680 B
  const int h = blockIdx.x, b = blockIdx.y;
  const int tid = threadIdx.x;
  const size_t rowbase = ((size_t)b * H + h) * W;

  const unsigned short* vrow = v + (size_t)b * C * HW + (size_t)h * W;
  for (int idx = tid; idx < 64 * 120; idx += 960) {
    const int c = idx / 120, s4 = (idx - c * 120) * 4;
    const int u = s4 & 31;  // multiple of 4
    const int t = (u < 16) ? ((u >> 2) * 8) : (((u - 16) >> 2) * 8 + 4);
    *(ushort4*)(vbs + c * VSW + (s4 & ~31) + t) =
        *(const ushort4*)(vrow + (size_t)c * HW + s4);
  }
  for (int g = tid; g < 480; g += 960)
    *(uint4*)(kls + g * 8) = *(const uint4*)(kwp + (rowbase + g) * 8);

  const int lane = tid & 63, wv = tid >> 6;
  const int l15 = lane & 15, quad = lane >> 4;
  const int m0 = wv * 32;

  short8 qa0 = short8{0, 0, 0, 0, 0, 0, 0, 0};
  short8 qa1 = short8{0, 0, 0, 0, 0, 0, 0, 0};
  if (quad == 0) {
    qa0 = *(const short8*)(qwp + (rowbase + m0 + l15) * 8);
    qa1 = *(const short8*)(qwp + (rowbase + m0 + 16 + l15) * 8);
  }

  f32x4 acc[2][4];
  float Sacc[2] = {0.0f, 0.0f};
#pragma unroll
  for (int mt = 0; mt < 2; ++mt)
#pragma unroll
    for (int ct = 0; ct < 4; ++ct)
#pragma unroll
      for (int rr = 0; rr < 4; ++rr) acc[mt][ct][rr] = 0.0f;

  __syncthreads();

  for (int ci = 0; ci < 15; ++ci) {
    const int sc = ci * 32;
    short8 kb0 = short8{0, 0, 0, 0, 0, 0, 0, 0};
    short8 kb1 = short8{0, 0, 0, 0, 0, 0, 0, 0};
    if (quad == 0) {
      kb0 = *(const short8*)(kls + (sc + l15) * 8);
      kb1 = *(const short8*)(kls + (sc + 16 + l15) * 8);
    }
    const f32x4 z4 = f32x4{0.f, 0.f, 0.f, 0.f};
    const f32x4 E00 = __builtin_amdgcn_mfma_f32_16x16x32_bf16(kb0, qa0, z4, 0, 0, 0);
    const f32x4 E01 = __builtin_amdgcn_mfma_f32_16x16x32_bf16(kb1, qa0, z4, 0, 0, 0);
    const f32x4 E10 = __builtin_amdgcn_mfma_f32_16x16x32_bf16(kb0, qa1, z4, 0, 0, 0);
    const f32x4 E11 = __builtin_amdgcn_mfma_f32_16x16x32_bf16(kb1, qa1, z4, 0, 0, 0);
    short8 vb[4];
#pragma unroll
    for (int ct = 0; ct < 4; ++ct)
      vb[ct] = *(const short8*)(vbs + (ct * 16 + l15) * VSW + sc + quad * 8);
#pragma unroll
    for (int mt = 0; mt < 2; ++mt) {
      const int m = m0 + mt * 16 + l15;
      const f32x4 Ea = mt ? E10 : E00;
      const f32x4 Eb = mt ? E11 : E01;
      float p0[4], p1[4];
#pragma unroll
      for (int rr = 0; rr < 4; ++rr) {
        const float d0 = (float)(m - (sc + quad * 4 + rr));
        const float d1 = d0 - 16.0f;
        p0[rr] = __expf(Ea[rr] * __expf(-(d0 * d0) * INVW2));
        p1[rr] = __expf(Eb[rr] * __expf(-(d1 * d1) * INVW2));
        Sacc[mt] += p0[rr] + p1[rr];
      }
      const short8 pa = pack_p(p0, p1);
#pragma unroll
      for (int ct = 0; ct < 4; ++ct)
        acc[mt][ct] = __builtin_amdgcn_mfma_f32_16x16x32_bf16(pa, vb[ct], acc[mt][ct], 0, 0, 0);
    }
  }

#pragma unroll
  for (int mt = 0; mt < 2; ++mt) {
    float s = Sacc[mt];
    s += __shfl_xor(s, 16);
    s += __shfl_xor(s, 32);
    if (lane < 16) Sw[rowbase + m0 + mt * 16 + l15] = s;
  }

  __syncthreads();  // vbs reads done; reuse as [c][480] transpose buffer
  unsigned short* ob = vbs;
#pragma unroll
  for (int mt = 0; mt < 2; ++mt)
#pragma unroll
    for (int ct = 0; ct < 4; ++ct)
#pragma unroll
      for (int rr = 0; rr < 4; ++rr)
        ob[(ct * 16 + l15) * VSW + m0 + mt * 16 + quad * 4 + rr] = f2bf(acc[mt][ct][rr]);
  __syncthreads();
  unsigned short* og = ow + ((size_t)b * H + h) * C * W;
  for (int idx = tid; idx < 64 * 240; idx += 960) {
    const int c = idx / 240, wp = idx - c * 240;
    *(unsigned int*)(og + (size_t)c * W + 2 * wp) =
        *(const unsigned int*)(ob + c * VSW + 2 * wp);
  }
}

// ---------------------------------------------------------------------------
// K3: out_h unnormalized + S_h. ONE block per (b,w): 576 thr = 9 waves,
// each wave 32 m-rows (M=288, rows >= 270 pad: loads clamped, p masked).
// Same swapped-QK register-resident P path + K column staged in LDS.
// Outputs oht [b][w][c][h], Sht [b][w][h].
// ---------------------------------------------------------------------------
constexpr int VSH = 296;

__global__ __launch_bounds__(576, 1)
void k_outh(const unsigned short* __restrict__ qhp,
            const unsigned short* __restrict__ khp,
            const unsigned short* __restrict__ vt,
            unsigned short* __restrict__ oht, float* __restrict__ Sht) {
  __shared__ __align__(16) unsigned short vbs[18944];  // 64*296 u16 = 37888 B
  __shared__ __align__(16) unsigned short kls[288 * 8];  // 4608 B
  const int w = blockIdx.x, b = blockIdx.y;
  const int tid = threadIdx.x;
  const size_t colbase = ((size_t)b * W + w) * H;

  const unsigned short* vtb = vt + ((size_t)b * W + w) * H * C;
  for (int idx = tid; idx < 288 * 16; idx += 576) {
    const int g = idx >> 4, c4 = (idx & 15) * 4;
    ushort4 vv = make_ushort4(0, 0, 0, 0);
    if (g < H) vv = *(const ushort4*)(vtb + (size_t)g * C + c4);
    const int u = g & 31;
    const int t = (u < 16) ? ((u >> 2) * 8 + (u & 3))
                           : (((u - 16) >> 2) * 8 + 4 + (u & 3));
    const int slot = (g & ~31) + t;
    vbs[(c4 + 0) * VSH + slot] = vv.x;
    vbs[(c4 + 1) * VSH + slot] = vv.y;
    vbs[(c4 + 2) * VSH + slot] = vv.z;
    vbs[(c4 + 3) * VSH + slot] = vv.w;
  }
  for (int g = tid; g < 288; g += 576)
    *(uint4*)(kls + g * 8) =
        *(const uint4*)(khp + (colbase + min(g, H - 1)) * 8);

  const int lane = tid & 63, wv = tid >> 6;
  const int l15 = lane & 15, quad = lane >> 4;
  const int m0 = wv * 32;

  short8 qa0 = short8{0, 0, 0, 0, 0, 0, 0, 0};
  short8 qa1 = short8{0, 0, 0, 0, 0, 0, 0, 0};
  if (quad == 0) {
    qa0 = *(const short8*)(qhp + (colbase + min(m0 + l15, H - 1)) * 8);
    qa1 = *(const short8*)(qhp + (colbase + min(m0 + 16 + l15, H - 1)) * 8);
  }

  f32x4 acc[2][4];
  float Sacc[2] = {0.0f, 0.0f};
#pragma unroll
  for (int mt = 0; mt < 2; ++mt)
#pragma unroll
    for (int ct = 0; ct < 4; ++ct)
#pragma unroll
      for (int rr = 0; rr < 4; ++rr) acc[mt][ct][rr] = 0.0f;

  __syncthreads();

  for (int ci = 0; ci < 9; ++ci) {
    const int gc = ci * 32;
    short8 kb0 = short8{0, 0, 0, 0, 0, 0, 0, 0};
    short8 kb1 = short8{0, 0, 0, 0, 0, 0, 0, 0};
    if (quad == 0) {
      kb0 = *(const short8*)(kls + (gc + l15) * 8);
      kb1 = *(const short8*)(kls + (gc + 16 + l15) * 8);
    }
    const f32x4 z4 = f32x4{0.f, 0.f, 0.f, 0.f};
    const f32x4 E00 = __builtin_amdgcn_mfma_f32_16x16x32_bf16(kb0, qa0, z4, 0, 0, 0);
    const f32x4 E01 = __builtin_amdgcn_mfma_f32_16x16x32_bf16(kb1, qa0, z4, 0, 0, 0);
    const f32x4 E10 = __builtin_amdgcn_mfma_f32_16x16x32_bf16(kb0, qa1, z4, 0, 0, 0);
    const f32x4 E11 = __builtin_amdgcn_mfma_f32_16x16x32_bf16(kb1, qa1, z4, 0, 0, 0);
    short8 vb[4];
#pragma unroll
    for (int ct = 0; ct < 4; ++ct)
      vb[ct] = *(const short8*)(vbs + (ct * 16 + l15) * VSH + gc + quad * 8);
#pragma unroll
    for (int mt = 0; mt < 2; ++mt) {
      const int m = m0 + mt * 16 + l15;
      const f32x4 Ea = mt ? E10 : E00;
      const f32x4 Eb = mt ? E11 : E01;
      float p0[4], p1[4];
#pragma unroll
      for (int rr = 0; rr < 4; ++rr) {
        const int g0 = gc + quad * 4 + rr;
        const int g1 = g0 + 16;
        const float d0 = (float)(m - g0);
        const float d1 = d0 - 16.0f;
        p0[rr] = (g0 < H && g0 != m)
                     ? __expf(Ea[rr] * __expf(-(d0 * d0) * INVH2)) : 0.0f;
        p1[rr] = (g1 < H && g1 != m)
                     ? __expf(Eb[rr] * __expf(-(d1 * d1) * INVH2)) : 0.0f;
        Sacc[mt] += p0[rr] + p1[rr];
      }
      const short8 pa = pack_p(p0, p1);
#pragma unroll
      for (int ct = 0; ct < 4; ++ct)
        acc[mt][ct] = __builtin_amdgcn_mfma_f32_16x16x32_bf16(pa, vb[ct], acc[mt][ct], 0, 0, 0);
    }
  }

#pragma unroll
  for (int mt = 0; mt < 2; ++mt) {
    float s = Sacc[mt];
    s += __shfl_xor(s, 16);
    s += __shfl_xor(s, 32);
    const int m = m0 + mt * 16 + l15;
    if (lane < 16 && m < H) Sht[colbase + m] = s;
  }

  __syncthreads();
  unsigned short* ob = vbs;  // [c][288] stride 296
#pragma unroll
  for (int mt = 0; mt < 2; ++mt)
#pragma unroll
    for (int ct = 0; ct < 4; ++ct)
#pragma unroll
      for (int rr = 0; rr < 4; ++rr)
        ob[(ct * 16 + l15) * VSH + m0 + mt * 16 + quad * 4 + rr] = f2bf(acc[mt][ct][rr]);
  __syncthreads();
  unsigned short* og = oht + ((size_t)b * W + w) * C * H;
  for (int idx = tid; idx < 64 * 135; idx += 576) {
    const int c = idx / 135, hp = idx - c * 135;
    *(unsigned int*)(og + (size_t)c * H + 2 * hp) =
        *(const unsigned int*)(ob + c * VSH + 2 * hp);
  }
}

// ---------------------------------------------------------------------------
// K4: out = gamma*(U_h + U_w)/(S_h+S_w) + x, LDS tile transpose for oht.
// Sht is [b][w][h] (1 MB, L2-resident, 64x c-reuse -> strided read is cheap).
// ---------------------------------------------------------------------------
__global__ __launch_bounds__(256)
void k_combine(const unsigned short* __restrict__ oht,
               const unsigned short* __restrict__ ow,
               const float* __restrict__ Sht, const float* __restrict__ Sw,
               const float* __restrict__ x,
               const float* __restrict__ gp,
               float* __restrict__ out) {
  __shared__ float tile[32][33];
  const int b = blockIdx.z >> 6, c = blockIdx.z & 63;
  const int w0 = blockIdx.x * 32, h0 = blockIdx.y * 32;
  const int tx = threadIdx.x, ty = threadIdx.y;  // (32, 8)
#pragma unroll
  for (int i = 0; i < 4; ++i) {
    const int wl = ty + i * 8;
    const int hh = h0 + tx;
    float val = 0.0f;
    if (hh < H) val = bits2f(oht[(((size_t)b * W + (w0 + wl)) * C + c) * H + hh]);
    tile[wl][tx] = val;
  }
  __syncthreads();
  const float gamma = *gp;
#pragma unroll
  for (int i = 0; i < 4; ++i) {
    const int hl = ty + i * 8;
    const int hh = h0 + hl;
    if (hh < H) {
      const int ww = w0 + tx;
      const float uh = tile[tx][hl];
      const float uw = bits2f(ow[(((size_t)b * H + hh) * C + c) * W + ww]);
      const size_t si = ((size_t)b * H + hh) * W + ww;
      const float Z = Sht[((size_t)b * W + ww) * H + hh] + Sw[si];
      const float invZ = __builtin_amdgcn_rcpf(Z);
      const size_t xi = ((size_t)b * C + c) * HW + (size_t)hh * W + ww;
      out[xi] = fmaf(gamma * invZ, uh + uw, x[xi]);
    }
  }
}

}  // namespace

extern "C" void kernel_launch(void* const* d_in, const int* in_sizes, int n_in,
                              void* d_out, int out_size, void* d_ws, size_t ws_size,
                              hipStream_t stream) {
  (void)in_sizes; (void)n_in; (void)out_size; (void)ws_size;
  const float* x  = (const float*)d_in[0];
  const float* Wq = (const float*)d_in[1];
  const float* bq = (const float*)d_in[2];
  const float* Wk = (const float*)d_in[3];
  const float* bk = (const float*)d_in[4];
  const float* Wv = (const float*)d_in[5];
  const float* bv = (const float*)d_in[6];
  const float* gp = (const float*)d_in[7];
  float* out = (float*)d_out;

  char* p = (char*)d_ws;
  auto take = [&](size_t bytes) -> void* {
    char* r = p;
    p += (bytes + 255) & ~(size_t)255;
    return (void*)r;
  };
  unsigned short* qwp = (unsigned short*)take(sizeof(unsigned short) * (size_t)B * HW * 8);
  unsigned short* kwp = (unsigned short*)take(sizeof(unsigned short) * (size_t)B * HW * 8);
  unsigned short* qhp = (unsigned short*)take(sizeof(unsigned short) * (size_t)B * HW * 8);
  unsigned short* khp = (unsigned short*)take(sizeof(unsigned short) * (size_t)B * HW * 8);
  unsigned short* v   = (unsigned short*)take(sizeof(unsigned short) * (size_t)B * C * HW);
  unsigned short* vt  = (unsigned short*)take(sizeof(unsigned short) * (size_t)B * C * HW);
  unsigned short* oht = (unsigned short*)take(sizeof(unsigned short) * (size_t)B * C * HW);
  unsigned short* owb = (unsigned short*)take(sizeof(unsigned short) * (size_t)B * C * HW);
  float* Sht = (float*)take(sizeof(float) * (size_t)B * HW);
  float* Sw  = (float*)take(sizeof(float) * (size_t)B * HW);

  hipLaunchKernelGGL(k_qkv, dim3((B * HW + 255) / 256), dim3(256), 0, stream,
                     x, Wq, bq, Wk, bk, Wv, bv, qwp, kwp, qhp, khp, v, vt);
  hipLaunchKernelGGL(k_outh, dim3(W, B), dim3(576), 0, stream,
                     qhp, khp, vt, oht, Sht);
  hipLaunchKernelGGL(k_outw, dim3(H, B), dim3(960), 0, stream,
                     qwp, kwp, v, owb, Sw);
  hipLaunchKernelGGL(k_combine, dim3(W / 32, (H + 31) / 32, B * C), dim3(32, 8), 0, stream,
                     oht, owb, Sht, Sw, x, gp, out);
}

// Round 6
// 445.791 us; speedup vs baseline: 1.5825x; 1.0186x over previous
//
#include <hip/hip_runtime.h>
#include <hip/hip_bf16.h>

namespace {

constexpr int B  = 2;
constexpr int C  = 64;
constexpr int CQ = 8;
constexpr int H  = 270;
constexpr int W  = 480;
constexpr int HW = H * W;
constexpr float INVH2 = 2.0f / (270.0f * 270.0f);  // dw_h = exp(-d^2 * INVH2)
constexpr float INVW2 = 2.0f / (480.0f * 480.0f);

typedef __attribute__((ext_vector_type(4))) float f32x4;
typedef __attribute__((ext_vector_type(8))) short short8;
typedef __attribute__((ext_vector_type(4))) unsigned int uint4v;

__device__ __forceinline__ float bits2f(unsigned short u) {
  union { unsigned int i; float f; } cv;
  cv.i = ((unsigned int)u) << 16;
  return cv.f;
}

__device__ __forceinline__ unsigned short f2bf(float f) {
  union { __hip_bfloat16 b; unsigned short u; } cv;
  cv.b = __float2bfloat16(f);
  return cv.u;
}

__device__ __forceinline__ unsigned int pack2(float a, float b) {
  return ((unsigned int)f2bf(b) << 16) | (unsigned int)f2bf(a);
}

__device__ __forceinline__ short8 pack_p(const float p0[4], const float p1[4]) {
  uint4v pw;
  pw[0] = pack2(p0[0], p0[1]);
  pw[1] = pack2(p0[2], p0[3]);
  pw[2] = pack2(p1[0], p1[1]);
  pw[3] = pack2(p1[2], p1[3]);
  return __builtin_bit_cast(short8, pw);
}

// V-row permutation inside each 32-row K-step so that the swapped-QK P layout
// (lane quad q holds g = 4q+rr from E0 and 16+4q+rr from E1) feeds the PV
// A-fragment (k-slot q*8+j) with NO cross-lane data movement:
//   u < 16: slot = 8*(u>>2) + (u&3);  u >= 16: slot = 8*((u-16)>>2) + 4 + (u&3)

// ---------------------------------------------------------------------------
// K1: q/k/v 1x1 projections. One thread per pixel. Writes bf16 packs:
// qwp/kwp [b][h][w][8], qhp/khp [b][w][h][8], v [b][c][h][w], vt [b][w][h][c].
// ---------------------------------------------------------------------------
__global__ __launch_bounds__(256)
void k_qkv(const float* __restrict__ x,
           const float* __restrict__ Wq, const float* __restrict__ bq,
           const float* __restrict__ Wk, const float* __restrict__ bk,
           const float* __restrict__ Wv, const float* __restrict__ bv,
           unsigned short* __restrict__ qwp, unsigned short* __restrict__ kwp,
           unsigned short* __restrict__ qhp, unsigned short* __restrict__ khp,
           unsigned short* __restrict__ v, unsigned short* __restrict__ vt) {
  __shared__ __align__(16) float wql[CQ * C];
  __shared__ __align__(16) float wkl[CQ * C];
  __shared__ __align__(16) float wvl[C * C];
  __shared__ float bql[CQ], bkl[CQ], bvl[C];
  const int tid = threadIdx.x;
  for (int i = tid; i < CQ * C; i += 256) { wql[i] = Wq[i]; wkl[i] = Wk[i]; }
  for (int i = tid; i < C * C; i += 256) wvl[i] = Wv[i];
  if (tid < CQ) { bql[tid] = bq[tid]; bkl[tid] = bk[tid]; }
  if (tid < C) bvl[tid] = bv[tid];
  __syncthreads();
  const int pix = blockIdx.x * 256 + tid;
  if (pix >= B * HW) return;
  const int b = pix / HW;
  const int r = pix - b * HW;
  const int h = r / W;
  const int w = r - h * W;

  float qa[CQ], ka[CQ], va[C];
#pragma unroll
  for (int o = 0; o < CQ; ++o) { qa[o] = bql[o]; ka[o] = bkl[o]; }
#pragma unroll
  for (int o = 0; o < C; ++o) va[o] = bvl[o];

  const float* xp = x + (size_t)b * C * HW + r;
  for (int c = 0; c < C; c += 4) {
    const float x0 = xp[(size_t)(c + 0) * HW];
    const float x1 = xp[(size_t)(c + 1) * HW];
    const float x2 = xp[(size_t)(c + 2) * HW];
    const float x3 = xp[(size_t)(c + 3) * HW];
#pragma unroll
    for (int o = 0; o < CQ; ++o) {
      const float4 a = *(const float4*)(wql + o * C + c);
      qa[o] = fmaf(a.w, x3, fmaf(a.z, x2, fmaf(a.y, x1, fmaf(a.x, x0, qa[o]))));
      const float4 bb = *(const float4*)(wkl + o * C + c);
      ka[o] = fmaf(bb.w, x3, fmaf(bb.z, x2, fmaf(bb.y, x1, fmaf(bb.x, x0, ka[o]))));
    }
#pragma unroll
    for (int o = 0; o < C; ++o) {
      const float4 cc = *(const float4*)(wvl + o * C + c);
      va[o] = fmaf(cc.w, x3, fmaf(cc.z, x2, fmaf(cc.y, x1, fmaf(cc.x, x0, va[o]))));
    }
  }

  uint4 qp4, kp4;
  qp4.x = pack2(qa[0], qa[1]); qp4.y = pack2(qa[2], qa[3]);
  qp4.z = pack2(qa[4], qa[5]); qp4.w = pack2(qa[6], qa[7]);
  kp4.x = pack2(ka[0], ka[1]); kp4.y = pack2(ka[2], ka[3]);
  kp4.z = pack2(ka[4], ka[5]); kp4.w = pack2(ka[6], ka[7]);
  *(uint4*)(qwp + (size_t)pix * 8) = qp4;
  *(uint4*)(kwp + (size_t)pix * 8) = kp4;
  const size_t tbase = ((size_t)b * W + w) * H + h;
  *(uint4*)(qhp + tbase * 8) = qp4;
  *(uint4*)(khp + tbase * 8) = kp4;

  unsigned short* vp = v + (size_t)b * C * HW + r;
#pragma unroll
  for (int o = 0; o < C; ++o) vp[(size_t)o * HW] = f2bf(va[o]);
  unsigned short* vtp = vt + tbase * C;
#pragma unroll
  for (int j = 0; j < 16; ++j) {
    ushort4 u;
    u.x = f2bf(va[4 * j + 0]);
    u.y = f2bf(va[4 * j + 1]);
    u.z = f2bf(va[4 * j + 2]);
    u.w = f2bf(va[4 * j + 3]);
    *(ushort4*)(vtp + 4 * j) = u;
  }
}

// ---------------------------------------------------------------------------
// K2: out_w unnormalized + S_w. TWO blocks per (b,h) (z = blockIdx.x&1):
// 512 thr = 8 waves, chunks z*8+wv of 32 m-rows (M=480 = 15 chunks; z=1 wv7
// idle). At 116 regs/wave, 2 blocks (16 waves, 4/SIMD, 464<=512) + LDS
// 69.3 KB x2 = 139 KB fit -> 2 blocks/CU vs the old 15-wave single block's 1.
// Swapped QK (mfma(K,Q)): P lands m=lane, g=regs -> exp+pack in registers
// feeds PV A-frag (V k-slot-permuted in LDS). K row in LDS: no global in loop.
// VSW=494 (odd 4B-stride) spreads LDS banks.
// ---------------------------------------------------------------------------
constexpr int VSW = 494;

__global__ __launch_bounds__(512, 1)
void k_outw(const unsigned short* __restrict__ qwp,
            const unsigned short* __restrict__ kwp,
            const unsigned short* __restrict__ v,
            unsigned short* __restrict__ ow, float* __restrict__ Sw) {
  __shared__ __align__(16) unsigned short vbs[64 * VSW];   // 63232 B
  __shared__ __align__(16) unsigned short kls[480 * 8];    // 7680 B
  const int h = blockIdx.x >> 1, z = blockIdx.x & 1;
  const int b = blockIdx.y;
  const int tid = threadIdx.x;
  const size_t rowbase = ((size_t)b * H + h) * W;

  const unsigned short* vrow = v + (size_t)b * C * HW + (size_t)h * W;
  for (int idx = tid; idx < 64 * 120; idx += 512) {
    const int c = idx / 120, s4 = (idx - c * 120) * 4;
    const int u = s4 & 31;  // multiple of 4
    const int t = (u < 16) ? ((u >> 2) * 8) : (((u - 16) >> 2) * 8 + 4);
    *(ushort4*)(vbs + c * VSW + (s4 & ~31) + t) =
        *(const ushort4*)(vrow + (size_t)c * HW + s4);
  }
  for (int g = tid; g < 480; g += 512)
    *(uint4*)(kls + g * 8) = *(const uint4*)(kwp + (rowbase + g) * 8);

  const int lane = tid & 63, wv = tid >> 6;
  const int l15 = lane & 15, quad = lane >> 4;
  const int chunk = z * 8 + wv;
  const bool active = chunk < 15;
  const int m0 = chunk * 32;

  short8 qa0 = short8{0, 0, 0, 0, 0, 0, 0, 0};
  short8 qa1 = short8{0, 0, 0, 0, 0, 0, 0, 0};
  if (quad == 0 && active) {
    qa0 = *(const short8*)(qwp + (rowbase + m0 + l15) * 8);
    qa1 = *(const short8*)(qwp + (rowbase + m0 + 16 + l15) * 8);
  }

  f32x4 acc[2][4];
  float Sacc[2] = {0.0f, 0.0f};
#pragma unroll
  for (int mt = 0; mt < 2; ++mt)
#pragma unroll
    for (int ct = 0; ct < 4; ++ct)
#pragma unroll
      for (int rr = 0; rr < 4; ++rr) acc[mt][ct][rr] = 0.0f;

  __syncthreads();

  if (active) {
    for (int ci = 0; ci < 15; ++ci) {
      const int sc = ci * 32;
      short8 kb0 = short8{0, 0, 0, 0, 0, 0, 0, 0};
      short8 kb1 = short8{0, 0, 0, 0, 0, 0, 0, 0};
      if (quad == 0) {
        kb0 = *(const short8*)(kls + (sc + l15) * 8);
        kb1 = *(const short8*)(kls + (sc + 16 + l15) * 8);
      }
      const f32x4 z4 = f32x4{0.f, 0.f, 0.f, 0.f};
      const f32x4 E00 = __builtin_amdgcn_mfma_f32_16x16x32_bf16(kb0, qa0, z4, 0, 0, 0);
      const f32x4 E01 = __builtin_amdgcn_mfma_f32_16x16x32_bf16(kb1, qa0, z4, 0, 0, 0);
      const f32x4 E10 = __builtin_amdgcn_mfma_f32_16x16x32_bf16(kb0, qa1, z4, 0, 0, 0);
      const f32x4 E11 = __builtin_amdgcn_mfma_f32_16x16x32_bf16(kb1, qa1, z4, 0, 0, 0);
      short8 vb[4];
#pragma unroll
      for (int ct = 0; ct < 4; ++ct)
        vb[ct] = *(const short8*)(vbs + (ct * 16 + l15) * VSW + sc + quad * 8);
#pragma unroll
      for (int mt = 0; mt < 2; ++mt) {
        const int m = m0 + mt * 16 + l15;
        const f32x4 Ea = mt ? E10 : E00;
        const f32x4 Eb = mt ? E11 : E01;
        float p0[4], p1[4];
#pragma unroll
        for (int rr = 0; rr < 4; ++rr) {
          const float d0 = (float)(m - (sc + quad * 4 + rr));
          const float d1 = d0 - 16.0f;
          p0[rr] = __expf(Ea[rr] * __expf(-(d0 * d0) * INVW2));
          p1[rr] = __expf(Eb[rr] * __expf(-(d1 * d1) * INVW2));
          Sacc[mt] += p0[rr] + p1[rr];
        }
        const short8 pa = pack_p(p0, p1);
#pragma unroll
        for (int ct = 0; ct < 4; ++ct)
          acc[mt][ct] = __builtin_amdgcn_mfma_f32_16x16x32_bf16(pa, vb[ct], acc[mt][ct], 0, 0, 0);
      }
    }

#pragma unroll
    for (int mt = 0; mt < 2; ++mt) {
      float s = Sacc[mt];
      s += __shfl_xor(s, 16);
      s += __shfl_xor(s, 32);
      if (lane < 16) Sw[rowbase + m0 + mt * 16 + l15] = s;
    }
  }

  __syncthreads();  // vbs reads done; reuse as [c][480] transpose buffer
  unsigned short* ob = vbs;
  if (active) {
#pragma unroll
    for (int mt = 0; mt < 2; ++mt)
#pragma unroll
      for (int ct = 0; ct < 4; ++ct)
#pragma unroll
        for (int rr = 0; rr < 4; ++rr)
          ob[(ct * 16 + l15) * VSW + m0 + mt * 16 + quad * 4 + rr] = f2bf(acc[mt][ct][rr]);
  }
  __syncthreads();
  unsigned short* og = ow + ((size_t)b * H + h) * C * W;
  const int mlo = z ? 256 : 0;
  const int nu = z ? 112 : 128;  // u32 per c-row in this block's m-range
  for (int idx = tid; idx < 64 * nu; idx += 512) {
    const int c = idx / nu, i = idx - c * nu;
    *(unsigned int*)(og + (size_t)c * W + mlo + 2 * i) =
        *(const unsigned int*)(ob + c * VSW + mlo + 2 * i);
  }
}

// ---------------------------------------------------------------------------
// K3: out_h unnormalized + S_h. TWO blocks per (b,w) (z = blockIdx.x&1):
// 320 thr = 5 waves, chunks z*5+wv (M=288 = 9 chunks; z=1 wv4 idle; rows
// >= 270 pad). 116 regs -> 4 waves/SIMD legal; LDS 42.3 KB -> 3 blocks/CU
// = 15 waves/CU vs the old 9-wave single block. VSH=302 (odd 4B-stride):
// staging-transpose writes drop from 8-way bank conflict to ~2-way.
// Outputs oht [b][w][c][h], Sht [b][w][h].
// ---------------------------------------------------------------------------
constexpr int VSH = 302;

__global__ __launch_bounds__(320, 1)
void k_outh(const unsigned short* __restrict__ qhp,
            const unsigned short* __restrict__ khp,
            const unsigned short* __restrict__ vt,
            unsigned short* __restrict__ oht, float* __restrict__ Sht) {
  __shared__ __align__(16) unsigned short vbs[64 * VSH];   // 38656 B
  __shared__ __align__(16) unsigned short kls[288 * 8];    // 4608 B
  const int w = blockIdx.x >> 1, z = blockIdx.x & 1;
  const int b = blockIdx.y;
  const int tid = threadIdx.x;
  const size_t colbase = ((size_t)b * W + w) * H;

  const unsigned short* vtb = vt + colbase * C;
  for (int idx = tid; idx < 288 * 16; idx += 320) {
    const int g = idx >> 4, c4 = (idx & 15) * 4;
    ushort4 vv = make_ushort4(0, 0, 0, 0);
    if (g < H) vv = *(const ushort4*)(vtb + (size_t)g * C + c4);
    const int u = g & 31;
    const int t = (u < 16) ? ((u >> 2) * 8 + (u & 3))
                           : (((u - 16) >> 2) * 8 + 4 + (u & 3));
    const int slot = (g & ~31) + t;
    vbs[(c4 + 0) * VSH + slot] = vv.x;
    vbs[(c4 + 1) * VSH + slot] = vv.y;
    vbs[(c4 + 2) * VSH + slot] = vv.z;
    vbs[(c4 + 3) * VSH + slot] = vv.w;
  }
  for (int g = tid; g < 288; g += 320)
    *(uint4*)(kls + g * 8) =
        *(const uint4*)(khp + (colbase + min(g, H - 1)) * 8);

  const int lane = tid & 63, wv = tid >> 6;
  const int l15 = lane & 15, quad = lane >> 4;
  const int chunk = z * 5 + wv;
  const bool active = chunk < 9;
  const int m0 = chunk * 32;

  short8 qa0 = short8{0, 0, 0, 0, 0, 0, 0, 0};
  short8 qa1 = short8{0, 0, 0, 0, 0, 0, 0, 0};
  if (quad == 0 && active) {
    qa0 = *(const short8*)(qhp + (colbase + min(m0 + l15, H - 1)) * 8);
    qa1 = *(const short8*)(qhp + (colbase + min(m0 + 16 + l15, H - 1)) * 8);
  }

  f32x4 acc[2][4];
  float Sacc[2] = {0.0f, 0.0f};
#pragma unroll
  for (int mt = 0; mt < 2; ++mt)
#pragma unroll
    for (int ct = 0; ct < 4; ++ct)
#pragma unroll
      for (int rr = 0; rr < 4; ++rr) acc[mt][ct][rr] = 0.0f;

  __syncthreads();

  if (active) {
    for (int ci = 0; ci < 9; ++ci) {
      const int gc = ci * 32;
      short8 kb0 = short8{0, 0, 0, 0, 0, 0, 0, 0};
      short8 kb1 = short8{0, 0, 0, 0, 0, 0, 0, 0};
      if (quad == 0) {
        kb0 = *(const short8*)(kls + (gc + l15) * 8);
        kb1 = *(const short8*)(kls + (gc + 16 + l15) * 8);
      }
      const f32x4 z4 = f32x4{0.f, 0.f, 0.f, 0.f};
      const f32x4 E00 = __builtin_amdgcn_mfma_f32_16x16x32_bf16(kb0, qa0, z4, 0, 0, 0);
      const f32x4 E01 = __builtin_amdgcn_mfma_f32_16x16x32_bf16(kb1, qa0, z4, 0, 0, 0);
      const f32x4 E10 = __builtin_amdgcn_mfma_f32_16x16x32_bf16(kb0, qa1, z4, 0, 0, 0);
      const f32x4 E11 = __builtin_amdgcn_mfma_f32_16x16x32_bf16(kb1, qa1, z4, 0, 0, 0);
      short8 vb[4];
#pragma unroll
      for (int ct = 0; ct < 4; ++ct)
        vb[ct] = *(const short8*)(vbs + (ct * 16 + l15) * VSH + gc + quad * 8);
#pragma unroll
      for (int mt = 0; mt < 2; ++mt) {
        const int m = m0 + mt * 16 + l15;
        const f32x4 Ea = mt ? E10 : E00;
        const f32x4 Eb = mt ? E11 : E01;
        float p0[4], p1[4];
#pragma unroll
        for (int rr = 0; rr < 4; ++rr) {
          const int g0 = gc + quad * 4 + rr;
          const int g1 = g0 + 16;
          const float d0 = (float)(m - g0);
          const float d1 = d0 - 16.0f;
          p0[rr] = (g0 < H && g0 != m)
                       ? __expf(Ea[rr] * __expf(-(d0 * d0) * INVH2)) : 0.0f;
          p1[rr] = (g1 < H && g1 != m)
                       ? __expf(Eb[rr] * __expf(-(d1 * d1) * INVH2)) : 0.0f;
          Sacc[mt] += p0[rr] + p1[rr];
        }
        const short8 pa = pack_p(p0, p1);
#pragma unroll
        for (int ct = 0; ct < 4; ++ct)
          acc[mt][ct] = __builtin_amdgcn_mfma_f32_16x16x32_bf16(pa, vb[ct], acc[mt][ct], 0, 0, 0);
      }
    }

#pragma unroll
    for (int mt = 0; mt < 2; ++mt) {
      float s = Sacc[mt];
      s += __shfl_xor(s, 16);
      s += __shfl_xor(s, 32);
      const int m = m0 + mt * 16 + l15;
      if (lane < 16 && m < H) Sht[colbase + m] = s;
    }
  }

  __syncthreads();
  unsigned short* ob = vbs;  // [c][288] stride VSH
  if (active) {
#pragma unroll
    for (int mt = 0; mt < 2; ++mt)
#pragma unroll
      for (int ct = 0; ct < 4; ++ct)
#pragma unroll
        for (int rr = 0; rr < 4; ++rr)
          ob[(ct * 16 + l15) * VSH + m0 + mt * 16 + quad * 4 + rr] = f2bf(acc[mt][ct][rr]);
  }
  __syncthreads();
  unsigned short* og = oht + ((size_t)b * W + w) * C * H;
  const int mlo = z ? 160 : 0;
  const int nu = z ? 55 : 80;  // u32 per c-row: z=0 rows 0-159, z=1 rows 160-269
  for (int idx = tid; idx < 64 * nu; idx += 320) {
    const int c = idx / nu, i = idx - c * nu;
    *(unsigned int*)(og + (size_t)c * H + mlo + 2 * i) =
        *(const unsigned int*)(ob + c * VSH + mlo + 2 * i);
  }
}

// ---------------------------------------------------------------------------
// K4: out = gamma*(U_h + U_w)/(S_h+S_w) + x, LDS tile transpose for oht.
// Sht is [b][w][h] (1 MB, L2-resident, 64x c-reuse -> strided read is cheap).
// ---------------------------------------------------------------------------
__global__ __launch_bounds__(256)
void k_combine(const unsigned short* __restrict__ oht,
               const unsigned short* __restrict__ ow,
               const float* __restrict__ Sht, const float* __restrict__ Sw,
               const float* __restrict__ x,
               const float* __restrict__ gp,
               float* __restrict__ out) {
  __shared__ float tile[32][33];
  const int b = blockIdx.z >> 6, c = blockIdx.z & 63;
  const int w0 = blockIdx.x * 32, h0 = blockIdx.y * 32;
  const int tx = threadIdx.x, ty = threadIdx.y;  // (32, 8)
#pragma unroll
  for (int i = 0; i < 4; ++i) {
    const int wl = ty + i * 8;
    const int hh = h0 + tx;
    float val = 0.0f;
    if (hh < H) val = bits2f(oht[(((size_t)b * W + (w0 + wl)) * C + c) * H + hh]);
    tile[wl][tx] = val;
  }
  __syncthreads();
  const float gamma = *gp;
#pragma unroll
  for (int i = 0; i < 4; ++i) {
    const int hl = ty + i * 8;
    const int hh = h0 + hl;
    if (hh < H) {
      const int ww = w0 + tx;
      const float uh = tile[tx][hl];
      const float uw = bits2f(ow[(((size_t)b * H + hh) * C + c) * W + ww]);
      const size_t si = ((size_t)b * H + hh) * W + ww;
      const float Z = Sht[((size_t)b * W + ww) * H + hh] + Sw[si];
      const float invZ = __builtin_amdgcn_rcpf(Z);
      const size_t xi = ((size_t)b * C + c) * HW + (size_t)hh * W + ww;
      out[xi] = fmaf(gamma * invZ, uh + uw, x[xi]);
    }
  }
}

}  // namespace

extern "C" void kernel_launch(void* const* d_in, const int* in_sizes, int n_in,
                              void* d_out, int out_size, void* d_ws, size_t ws_size,
                              hipStream_t stream) {
  (void)in_sizes; (void)n_in; (void)out_size; (void)ws_size;
  const float* x  = (const float*)d_in[0];
  const float* Wq = (const float*)d_in[1];
  const float* bq = (const float*)d_in[2];
  const float* Wk = (const float*)d_in[3];
  const float* bk = (const float*)d_in[4];
  const float* Wv = (const float*)d_in[5];
  const float* bv = (const float*)d_in[6];
  const float* gp = (const float*)d_in[7];
  float* out = (float*)d_out;

  char* p = (char*)d_ws;
  auto take = [&](size_t bytes) -> void* {
    char* r = p;
    p += (bytes + 255) & ~(size_t)255;
    return (void*)r;
  };
  unsigned short* qwp = (unsigned short*)take(sizeof(unsigned short) * (size_t)B * HW * 8);
  unsigned short* kwp = (unsigned short*)take(sizeof(unsigned short) * (size_t)B * HW * 8);
  unsigned short* qhp = (unsigned short*)take(sizeof(unsigned short) * (size_t)B * HW * 8);
  unsigned short* khp = (unsigned short*)take(sizeof(unsigned short) * (size_t)B * HW * 8);
  unsigned short* v   = (unsigned short*)take(sizeof(unsigned short) * (size_t)B * C * HW);
  unsigned short* vt  = (unsigned short*)take(sizeof(unsigned short) * (size_t)B * C * HW);
  unsigned short* oht = (unsigned short*)take(sizeof(unsigned short) * (size_t)B * C * HW);
  unsigned short* owb = (unsigned short*)take(sizeof(unsigned short) * (size_t)B * C * HW);
  float* Sht = (float*)take(sizeof(float) * (size_t)B * HW);
  float* Sw  = (float*)take(sizeof(float) * (size_t)B * HW);

  hipLaunchKernelGGL(k_qkv, dim3((B * HW + 255) / 256), dim3(256), 0, stream,
                     x, Wq, bq, Wk, bk, Wv, bv, qwp, kwp, qhp, khp, v, vt);
  hipLaunchKernelGGL(k_outh, dim3(2 * W, B), dim3(320), 0, stream,
                     qhp, khp, vt, oht, Sht);
  hipLaunchKernelGGL(k_outw, dim3(2 * H, B), dim3(512), 0, stream,
                     qwp, kwp, v, owb, Sw);
  hipLaunchKernelGGL(k_combine, dim3(W / 32, (H + 31) / 32, B * C), dim3(32, 8), 0, stream,
                     oht, owb, Sht, Sw, x, gp, out);
}

// Round 7
// 444.365 us; speedup vs baseline: 1.5875x; 1.0032x over previous
//
#include <hip/hip_runtime.h>
#include <hip/hip_bf16.h>

namespace {

constexpr int B  = 2;
constexpr int C  = 64;
constexpr int CQ = 8;
constexpr int H  = 270;
constexpr int W  = 480;
constexpr int HW = H * W;
constexpr float INVH2 = 2.0f / (270.0f * 270.0f);  // dw_h = exp(-d^2 * INVH2)
constexpr float INVW2 = 2.0f / (480.0f * 480.0f);

typedef __attribute__((ext_vector_type(4))) float f32x4;
typedef __attribute__((ext_vector_type(8))) short short8;
typedef __attribute__((ext_vector_type(4))) unsigned int uint4v;

__device__ __forceinline__ float bits2f(unsigned short u) {
  union { unsigned int i; float f; } cv;
  cv.i = ((unsigned int)u) << 16;
  return cv.f;
}

__device__ __forceinline__ unsigned short f2bf(float f) {
  union { __hip_bfloat16 b; unsigned short u; } cv;
  cv.b = __float2bfloat16(f);
  return cv.u;
}

__device__ __forceinline__ unsigned int pack2(float a, float b) {
  return ((unsigned int)f2bf(b) << 16) | (unsigned int)f2bf(a);
}

__device__ __forceinline__ short8 pack_p(const float p0[4], const float p1[4]) {
  uint4v pw;
  pw[0] = pack2(p0[0], p0[1]);
  pw[1] = pack2(p0[2], p0[3]);
  pw[2] = pack2(p1[0], p1[1]);
  pw[3] = pack2(p1[2], p1[3]);
  return __builtin_bit_cast(short8, pw);
}

// V-row permutation inside each 32-row K-step so that the swapped-QK P layout
// (lane quad q holds g = 4q+rr from E0 and 16+4q+rr from E1) feeds the PV
// A-fragment (k-slot q*8+j) with NO cross-lane data movement:
//   u < 16: slot = 8*(u>>2) + (u&3);  u >= 16: slot = 8*((u-16)>>2) + 4 + (u&3)

// ---------------------------------------------------------------------------
// K1: q/k/v 1x1 projections. One thread per pixel. Writes bf16 packs:
// qwp/kwp [b][h][w][8], qhp/khp [b][w][h][8], v [b][c][h][w], vt [b][w][h][c].
// ---------------------------------------------------------------------------
__global__ __launch_bounds__(256)
void k_qkv(const float* __restrict__ x,
           const float* __restrict__ Wq, const float* __restrict__ bq,
           const float* __restrict__ Wk, const float* __restrict__ bk,
           const float* __restrict__ Wv, const float* __restrict__ bv,
           unsigned short* __restrict__ qwp, unsigned short* __restrict__ kwp,
           unsigned short* __restrict__ qhp, unsigned short* __restrict__ khp,
           unsigned short* __restrict__ v, unsigned short* __restrict__ vt) {
  __shared__ __align__(16) float wql[CQ * C];
  __shared__ __align__(16) float wkl[CQ * C];
  __shared__ __align__(16) float wvl[C * C];
  __shared__ float bql[CQ], bkl[CQ], bvl[C];
  const int tid = threadIdx.x;
  for (int i = tid; i < CQ * C; i += 256) { wql[i] = Wq[i]; wkl[i] = Wk[i]; }
  for (int i = tid; i < C * C; i += 256) wvl[i] = Wv[i];
  if (tid < CQ) { bql[tid] = bq[tid]; bkl[tid] = bk[tid]; }
  if (tid < C) bvl[tid] = bv[tid];
  __syncthreads();
  const int pix = blockIdx.x * 256 + tid;
  if (pix >= B * HW) return;
  const int b = pix / HW;
  const int r = pix - b * HW;
  const int h = r / W;
  const int w = r - h * W;

  float qa[CQ], ka[CQ], va[C];
#pragma unroll
  for (int o = 0; o < CQ; ++o) { qa[o] = bql[o]; ka[o] = bkl[o]; }
#pragma unroll
  for (int o = 0; o < C; ++o) va[o] = bvl[o];

  const float* xp = x + (size_t)b * C * HW + r;
  for (int c = 0; c < C; c += 4) {
    const float x0 = xp[(size_t)(c + 0) * HW];
    const float x1 = xp[(size_t)(c + 1) * HW];
    const float x2 = xp[(size_t)(c + 2) * HW];
    const float x3 = xp[(size_t)(c + 3) * HW];
#pragma unroll
    for (int o = 0; o < CQ; ++o) {
      const float4 a = *(const float4*)(wql + o * C + c);
      qa[o] = fmaf(a.w, x3, fmaf(a.z, x2, fmaf(a.y, x1, fmaf(a.x, x0, qa[o]))));
      const float4 bb = *(const float4*)(wkl + o * C + c);
      ka[o] = fmaf(bb.w, x3, fmaf(bb.z, x2, fmaf(bb.y, x1, fmaf(bb.x, x0, ka[o]))));
    }
#pragma unroll
    for (int o = 0; o < C; ++o) {
      const float4 cc = *(const float4*)(wvl + o * C + c);
      va[o] = fmaf(cc.w, x3, fmaf(cc.z, x2, fmaf(cc.y, x1, fmaf(cc.x, x0, va[o]))));
    }
  }

  uint4 qp4, kp4;
  qp4.x = pack2(qa[0], qa[1]); qp4.y = pack2(qa[2], qa[3]);
  qp4.z = pack2(qa[4], qa[5]); qp4.w = pack2(qa[6], qa[7]);
  kp4.x = pack2(ka[0], ka[1]); kp4.y = pack2(ka[2], ka[3]);
  kp4.z = pack2(ka[4], ka[5]); kp4.w = pack2(ka[6], ka[7]);
  *(uint4*)(qwp + (size_t)pix * 8) = qp4;
  *(uint4*)(kwp + (size_t)pix * 8) = kp4;
  const size_t tbase = ((size_t)b * W + w) * H + h;
  *(uint4*)(qhp + tbase * 8) = qp4;
  *(uint4*)(khp + tbase * 8) = kp4;

  unsigned short* vp = v + (size_t)b * C * HW + r;
#pragma unroll
  for (int o = 0; o < C; ++o) vp[(size_t)o * HW] = f2bf(va[o]);
  unsigned short* vtp = vt + tbase * C;
#pragma unroll
  for (int j = 0; j < 16; ++j) {
    ushort4 u;
    u.x = f2bf(va[4 * j + 0]);
    u.y = f2bf(va[4 * j + 1]);
    u.z = f2bf(va[4 * j + 2]);
    u.w = f2bf(va[4 * j + 3]);
    *(ushort4*)(vtp + 4 * j) = u;
  }
}

// ---------------------------------------------------------------------------
// K2: out_w unnormalized + S_w. TWO blocks per (b,h) (z = blockIdx.x&1):
// 512 thr = 8 waves, chunks z*8+wv of 32 m-rows (M=480 = 15 chunks; z=1 wv7
// idle). Round-6 measured: this split is a WIN for outw (cheap staging, 2-blk
// residency). Swapped QK (mfma(K,Q)): P lands m=lane, g=regs -> exp+pack in
// registers feeds PV A-frag (V k-slot-permuted in LDS). K row in LDS.
// Sequential-mt E computation shaves ~8 live regs.
// ---------------------------------------------------------------------------
constexpr int VSW = 494;

__global__ __launch_bounds__(512, 1)
void k_outw(const unsigned short* __restrict__ qwp,
            const unsigned short* __restrict__ kwp,
            const unsigned short* __restrict__ v,
            unsigned short* __restrict__ ow, float* __restrict__ Sw) {
  __shared__ __align__(16) unsigned short vbs[64 * VSW];   // 63232 B
  __shared__ __align__(16) unsigned short kls[480 * 8];    // 7680 B
  const int h = blockIdx.x >> 1, z = blockIdx.x & 1;
  const int b = blockIdx.y;
  const int tid = threadIdx.x;
  const size_t rowbase = ((size_t)b * H + h) * W;

  const unsigned short* vrow = v + (size_t)b * C * HW + (size_t)h * W;
  for (int idx = tid; idx < 64 * 120; idx += 512) {
    const int c = idx / 120, s4 = (idx - c * 120) * 4;
    const int u = s4 & 31;  // multiple of 4
    const int t = (u < 16) ? ((u >> 2) * 8) : (((u - 16) >> 2) * 8 + 4);
    *(ushort4*)(vbs + c * VSW + (s4 & ~31) + t) =
        *(const ushort4*)(vrow + (size_t)c * HW + s4);
  }
  for (int g = tid; g < 480; g += 512)
    *(uint4*)(kls + g * 8) = *(const uint4*)(kwp + (rowbase + g) * 8);

  const int lane = tid & 63, wv = tid >> 6;
  const int l15 = lane & 15, quad = lane >> 4;
  const int chunk = z * 8 + wv;
  const bool active = chunk < 15;
  const int m0 = chunk * 32;

  short8 qa0 = short8{0, 0, 0, 0, 0, 0, 0, 0};
  short8 qa1 = short8{0, 0, 0, 0, 0, 0, 0, 0};
  if (quad == 0 && active) {
    qa0 = *(const short8*)(qwp + (rowbase + m0 + l15) * 8);
    qa1 = *(const short8*)(qwp + (rowbase + m0 + 16 + l15) * 8);
  }

  f32x4 acc[2][4];
  float Sacc[2] = {0.0f, 0.0f};
#pragma unroll
  for (int mt = 0; mt < 2; ++mt)
#pragma unroll
    for (int ct = 0; ct < 4; ++ct)
#pragma unroll
      for (int rr = 0; rr < 4; ++rr) acc[mt][ct][rr] = 0.0f;

  __syncthreads();

  if (active) {
    for (int ci = 0; ci < 15; ++ci) {
      const int sc = ci * 32;
      short8 kb0 = short8{0, 0, 0, 0, 0, 0, 0, 0};
      short8 kb1 = short8{0, 0, 0, 0, 0, 0, 0, 0};
      if (quad == 0) {
        kb0 = *(const short8*)(kls + (sc + l15) * 8);
        kb1 = *(const short8*)(kls + (sc + 16 + l15) * 8);
      }
      short8 vb[4];
#pragma unroll
      for (int ct = 0; ct < 4; ++ct)
        vb[ct] = *(const short8*)(vbs + (ct * 16 + l15) * VSW + sc + quad * 8);
      const f32x4 z4 = f32x4{0.f, 0.f, 0.f, 0.f};
#pragma unroll
      for (int mt = 0; mt < 2; ++mt) {
        const short8 qa = mt ? qa1 : qa0;
        const f32x4 Ea = __builtin_amdgcn_mfma_f32_16x16x32_bf16(kb0, qa, z4, 0, 0, 0);
        const f32x4 Eb = __builtin_amdgcn_mfma_f32_16x16x32_bf16(kb1, qa, z4, 0, 0, 0);
        const int m = m0 + mt * 16 + l15;
        float p0[4], p1[4];
#pragma unroll
        for (int rr = 0; rr < 4; ++rr) {
          const float d0 = (float)(m - (sc + quad * 4 + rr));
          const float d1 = d0 - 16.0f;
          p0[rr] = __expf(Ea[rr] * __expf(-(d0 * d0) * INVW2));
          p1[rr] = __expf(Eb[rr] * __expf(-(d1 * d1) * INVW2));
          Sacc[mt] += p0[rr] + p1[rr];
        }
        const short8 pa = pack_p(p0, p1);
#pragma unroll
        for (int ct = 0; ct < 4; ++ct)
          acc[mt][ct] = __builtin_amdgcn_mfma_f32_16x16x32_bf16(pa, vb[ct], acc[mt][ct], 0, 0, 0);
      }
    }

#pragma unroll
    for (int mt = 0; mt < 2; ++mt) {
      float s = Sacc[mt];
      s += __shfl_xor(s, 16);
      s += __shfl_xor(s, 32);
      if (lane < 16) Sw[rowbase + m0 + mt * 16 + l15] = s;
    }
  }

  __syncthreads();  // vbs reads done; reuse as [c][480] transpose buffer
  unsigned short* ob = vbs;
  if (active) {
#pragma unroll
    for (int mt = 0; mt < 2; ++mt)
#pragma unroll
      for (int ct = 0; ct < 4; ++ct)
#pragma unroll
        for (int rr = 0; rr < 4; ++rr)
          ob[(ct * 16 + l15) * VSW + m0 + mt * 16 + quad * 4 + rr] = f2bf(acc[mt][ct][rr]);
  }
  __syncthreads();
  unsigned short* og = ow + ((size_t)b * H + h) * C * W;
  const int mlo = z ? 256 : 0;
  const int nu = z ? 112 : 128;  // u32 per c-row in this block's m-range
  for (int idx = tid; idx < 64 * nu; idx += 512) {
    const int c = idx / nu, i = idx - c * nu;
    *(unsigned int*)(og + (size_t)c * W + mlo + 2 * i) =
        *(const unsigned int*)(ob + c * VSW + mlo + 2 * i);
  }
}

// ---------------------------------------------------------------------------
// K3: out_h unnormalized + S_h. UNSPLIT (round-6 m-split doubled the V
// transpose staging and regressed 111->131; reverted): ONE block per (b,w),
// 576 thr = 9 waves, wave wv owns chunk wv of 32 m-rows (M=288; rows >= 270
// pad). VSH=302 kept (round 6: ~2.8x fewer staging conflicts than 296).
// Sequential-mt E computation: ~8 fewer live regs, targeting <=102 total so
// TWO 9-wave blocks can co-reside (busiest SIMD 5 waves x 102 <= 512).
// Outputs oht [b][w][c][h], Sht [b][w][h].
// ---------------------------------------------------------------------------
constexpr int VSH = 302;

__global__ __launch_bounds__(576, 1)
void k_outh(const unsigned short* __restrict__ qhp,
            const unsigned short* __restrict__ khp,
            const unsigned short* __restrict__ vt,
            unsigned short* __restrict__ oht, float* __restrict__ Sht) {
  __shared__ __align__(16) unsigned short vbs[64 * VSH];   // 38656 B
  __shared__ __align__(16) unsigned short kls[288 * 8];    // 4608 B
  const int w = blockIdx.x;
  const int b = blockIdx.y;
  const int tid = threadIdx.x;
  const size_t colbase = ((size_t)b * W + w) * H;

  const unsigned short* vtb = vt + colbase * C;
  for (int idx = tid; idx < 288 * 16; idx += 576) {
    const int g = idx >> 4, c4 = (idx & 15) * 4;
    ushort4 vv = make_ushort4(0, 0, 0, 0);
    if (g < H) vv = *(const ushort4*)(vtb + (size_t)g * C + c4);
    const int u = g & 31;
    const int t = (u < 16) ? ((u >> 2) * 8 + (u & 3))
                           : (((u - 16) >> 2) * 8 + 4 + (u & 3));
    const int slot = (g & ~31) + t;
    vbs[(c4 + 0) * VSH + slot] = vv.x;
    vbs[(c4 + 1) * VSH + slot] = vv.y;
    vbs[(c4 + 2) * VSH + slot] = vv.z;
    vbs[(c4 + 3) * VSH + slot] = vv.w;
  }
  for (int g = tid; g < 288; g += 576)
    *(uint4*)(kls + g * 8) =
        *(const uint4*)(khp + (colbase + min(g, H - 1)) * 8);

  const int lane = tid & 63, wv = tid >> 6;
  const int l15 = lane & 15, quad = lane >> 4;
  const int m0 = wv * 32;

  short8 qa0 = short8{0, 0, 0, 0, 0, 0, 0, 0};
  short8 qa1 = short8{0, 0, 0, 0, 0, 0, 0, 0};
  if (quad == 0) {
    qa0 = *(const short8*)(qhp + (colbase + min(m0 + l15, H - 1)) * 8);
    qa1 = *(const short8*)(qhp + (colbase + min(m0 + 16 + l15, H - 1)) * 8);
  }

  f32x4 acc[2][4];
  float Sacc[2] = {0.0f, 0.0f};
#pragma unroll
  for (int mt = 0; mt < 2; ++mt)
#pragma unroll
    for (int ct = 0; ct < 4; ++ct)
#pragma unroll
      for (int rr = 0; rr < 4; ++rr) acc[mt][ct][rr] = 0.0f;

  __syncthreads();

  for (int ci = 0; ci < 9; ++ci) {
    const int gc = ci * 32;
    short8 kb0 = short8{0, 0, 0, 0, 0, 0, 0, 0};
    short8 kb1 = short8{0, 0, 0, 0, 0, 0, 0, 0};
    if (quad == 0) {
      kb0 = *(const short8*)(kls + (gc + l15) * 8);
      kb1 = *(const short8*)(kls + (gc + 16 + l15) * 8);
    }
    short8 vb[4];
#pragma unroll
    for (int ct = 0; ct < 4; ++ct)
      vb[ct] = *(const short8*)(vbs + (ct * 16 + l15) * VSH + gc + quad * 8);
    const f32x4 z4 = f32x4{0.f, 0.f, 0.f, 0.f};
#pragma unroll
    for (int mt = 0; mt < 2; ++mt) {
      const short8 qa = mt ? qa1 : qa0;
      const f32x4 Ea = __builtin_amdgcn_mfma_f32_16x16x32_bf16(kb0, qa, z4, 0, 0, 0);
      const f32x4 Eb = __builtin_amdgcn_mfma_f32_16x16x32_bf16(kb1, qa, z4, 0, 0, 0);
      const int m = m0 + mt * 16 + l15;
      float p0[4], p1[4];
#pragma unroll
      for (int rr = 0; rr < 4; ++rr) {
        const int g0 = gc + quad * 4 + rr;
        const int g1 = g0 + 16;
        const float d0 = (float)(m - g0);
        const float d1 = d0 - 16.0f;
        p0[rr] = (g0 < H && g0 != m)
                     ? __expf(Ea[rr] * __expf(-(d0 * d0) * INVH2)) : 0.0f;
        p1[rr] = (g1 < H && g1 != m)
                     ? __expf(Eb[rr] * __expf(-(d1 * d1) * INVH2)) : 0.0f;
        Sacc[mt] += p0[rr] + p1[rr];
      }
      const short8 pa = pack_p(p0, p1);
#pragma unroll
      for (int ct = 0; ct < 4; ++ct)
        acc[mt][ct] = __builtin_amdgcn_mfma_f32_16x16x32_bf16(pa, vb[ct], acc[mt][ct], 0, 0, 0);
    }
  }

#pragma unroll
  for (int mt = 0; mt < 2; ++mt) {
    float s = Sacc[mt];
    s += __shfl_xor(s, 16);
    s += __shfl_xor(s, 32);
    const int m = m0 + mt * 16 + l15;
    if (lane < 16 && m < H) Sht[colbase + m] = s;
  }

  __syncthreads();
  unsigned short* ob = vbs;  // [c][288] stride VSH
#pragma unroll
  for (int mt = 0; mt < 2; ++mt)
#pragma unroll
    for (int ct = 0; ct < 4; ++ct)
#pragma unroll
      for (int rr = 0; rr < 4; ++rr)
        ob[(ct * 16 + l15) * VSH + m0 + mt * 16 + quad * 4 + rr] = f2bf(acc[mt][ct][rr]);
  __syncthreads();
  unsigned short* og = oht + ((size_t)b * W + w) * C * H;
  for (int idx = tid; idx < 64 * 135; idx += 576) {
    const int c = idx / 135, hp = idx - c * 135;
    *(unsigned int*)(og + (size_t)c * H + 2 * hp) =
        *(const unsigned int*)(ob + c * VSH + 2 * hp);
  }
}

// ---------------------------------------------------------------------------
// K4: out = gamma*(U_h + U_w)/(S_h+S_w) + x, LDS tile transpose for oht.
// Sht is [b][w][h] (1 MB, L2-resident, 64x c-reuse -> strided read is cheap).
// ---------------------------------------------------------------------------
__global__ __launch_bounds__(256)
void k_combine(const unsigned short* __restrict__ oht,
               const unsigned short* __restrict__ ow,
               const float* __restrict__ Sht, const float* __restrict__ Sw,
               const float* __restrict__ x,
               const float* __restrict__ gp,
               float* __restrict__ out) {
  __shared__ float tile[32][33];
  const int b = blockIdx.z >> 6, c = blockIdx.z & 63;
  const int w0 = blockIdx.x * 32, h0 = blockIdx.y * 32;
  const int tx = threadIdx.x, ty = threadIdx.y;  // (32, 8)
#pragma unroll
  for (int i = 0; i < 4; ++i) {
    const int wl = ty + i * 8;
    const int hh = h0 + tx;
    float val = 0.0f;
    if (hh < H) val = bits2f(oht[(((size_t)b * W + (w0 + wl)) * C + c) * H + hh]);
    tile[wl][tx] = val;
  }
  __syncthreads();
  const float gamma = *gp;
#pragma unroll
  for (int i = 0; i < 4; ++i) {
    const int hl = ty + i * 8;
    const int hh = h0 + hl;
    if (hh < H) {
      const int ww = w0 + tx;
      const float uh = tile[tx][hl];
      const float uw = bits2f(ow[(((size_t)b * H + hh) * C + c) * W + ww]);
      const size_t si = ((size_t)b * H + hh) * W + ww;
      const float Z = Sht[((size_t)b * W + ww) * H + hh] + Sw[si];
      const float invZ = __builtin_amdgcn_rcpf(Z);
      const size_t xi = ((size_t)b * C + c) * HW + (size_t)hh * W + ww;
      out[xi] = fmaf(gamma * invZ, uh + uw, x[xi]);
    }
  }
}

}  // namespace

extern "C" void kernel_launch(void* const* d_in, const int* in_sizes, int n_in,
                              void* d_out, int out_size, void* d_ws, size_t ws_size,
                              hipStream_t stream) {
  (void)in_sizes; (void)n_in; (void)out_size; (void)ws_size;
  const float* x  = (const float*)d_in[0];
  const float* Wq = (const float*)d_in[1];
  const float* bq = (const float*)d_in[2];
  const float* Wk = (const float*)d_in[3];
  const float* bk = (const float*)d_in[4];
  const float* Wv = (const float*)d_in[5];
  const float* bv = (const float*)d_in[6];
  const float* gp = (const float*)d_in[7];
  float* out = (float*)d_out;

  char* p = (char*)d_ws;
  auto take = [&](size_t bytes) -> void* {
    char* r = p;
    p += (bytes + 255) & ~(size_t)255;
    return (void*)r;
  };
  unsigned short* qwp = (unsigned short*)take(sizeof(unsigned short) * (size_t)B * HW * 8);
  unsigned short* kwp = (unsigned short*)take(sizeof(unsigned short) * (size_t)B * HW * 8);
  unsigned short* qhp = (unsigned short*)take(sizeof(unsigned short) * (size_t)B * HW * 8);
  unsigned short* khp = (unsigned short*)take(sizeof(unsigned short) * (size_t)B * HW * 8);
  unsigned short* v   = (unsigned short*)take(sizeof(unsigned short) * (size_t)B * C * HW);
  unsigned short* vt  = (unsigned short*)take(sizeof(unsigned short) * (size_t)B * C * HW);
  unsigned short* oht = (unsigned short*)take(sizeof(unsigned short) * (size_t)B * C * HW);
  unsigned short* owb = (unsigned short*)take(sizeof(unsigned short) * (size_t)B * C * HW);
  float* Sht = (float*)take(sizeof(float) * (size_t)B * HW);
  float* Sw  = (float*)take(sizeof(float) * (size_t)B * HW);

  hipLaunchKernelGGL(k_qkv, dim3((B * HW + 255) / 256), dim3(256), 0, stream,
                     x, Wq, bq, Wk, bk, Wv, bv, qwp, kwp, qhp, khp, v, vt);
  hipLaunchKernelGGL(k_outh, dim3(W, B), dim3(576), 0, stream,
                     qhp, khp, vt, oht, Sht);
  hipLaunchKernelGGL(k_outw, dim3(2 * H, B), dim3(512), 0, stream,
                     qwp, kwp, v, owb, Sw);
  hipLaunchKernelGGL(k_combine, dim3(W / 32, (H + 31) / 32, B * C), dim3(32, 8), 0, stream,
                     oht, owb, Sht, Sw, x, gp, out);
}

// Round 8
// 433.936 us; speedup vs baseline: 1.6257x; 1.0240x over previous
//
#include <hip/hip_runtime.h>
#include <hip/hip_bf16.h>

namespace {

constexpr int B  = 2;
constexpr int C  = 64;
constexpr int CQ = 8;
constexpr int H  = 270;
constexpr int W  = 480;
constexpr int HW = H * W;
constexpr float INVH2 = 2.0f / (270.0f * 270.0f);  // dw_h = exp(-d^2 * INVH2)
constexpr float INVW2 = 2.0f / (480.0f * 480.0f);

typedef __attribute__((ext_vector_type(4))) float f32x4;
typedef __attribute__((ext_vector_type(8))) short short8;
typedef __attribute__((ext_vector_type(4))) unsigned int uint4v;

__device__ __forceinline__ float bits2f(unsigned short u) {
  union { unsigned int i; float f; } cv;
  cv.i = ((unsigned int)u) << 16;
  return cv.f;
}

__device__ __forceinline__ unsigned short f2bf(float f) {
  union { __hip_bfloat16 b; unsigned short u; } cv;
  cv.b = __float2bfloat16(f);
  return cv.u;
}

__device__ __forceinline__ unsigned int pack2(float a, float b) {
  return ((unsigned int)f2bf(b) << 16) | (unsigned int)f2bf(a);
}

__device__ __forceinline__ short8 pack_p(const float p0[4], const float p1[4]) {
  uint4v pw;
  pw[0] = pack2(p0[0], p0[1]);
  pw[1] = pack2(p0[2], p0[3]);
  pw[2] = pack2(p1[0], p1[1]);
  pw[3] = pack2(p1[2], p1[3]);
  return __builtin_bit_cast(short8, pw);
}

// V-row permutation inside each 32-row K-step so that the swapped-QK P layout
// (lane quad q holds g = 4q+rr from E0 and 16+4q+rr from E1) feeds the PV
// A-fragment (k-slot q*8+j) with NO cross-lane data movement:
//   u < 16: slot = 8*(u>>2) + (u&3);  u >= 16: slot = 8*((u-16)>>2) + 4 + (u&3)

// ---------------------------------------------------------------------------
// K1: q/k/v 1x1 projections. One thread per pixel. Writes bf16 packs:
// qwp/kwp [b][h][w][8], qhp/khp [b][w][h][8], v [b][c][h][w], vt [b][w][h][c].
// ---------------------------------------------------------------------------
__global__ __launch_bounds__(256)
void k_qkv(const float* __restrict__ x,
           const float* __restrict__ Wq, const float* __restrict__ bq,
           const float* __restrict__ Wk, const float* __restrict__ bk,
           const float* __restrict__ Wv, const float* __restrict__ bv,
           unsigned short* __restrict__ qwp, unsigned short* __restrict__ kwp,
           unsigned short* __restrict__ qhp, unsigned short* __restrict__ khp,
           unsigned short* __restrict__ v, unsigned short* __restrict__ vt) {
  __shared__ __align__(16) float wql[CQ * C];
  __shared__ __align__(16) float wkl[CQ * C];
  __shared__ __align__(16) float wvl[C * C];
  __shared__ float bql[CQ], bkl[CQ], bvl[C];
  const int tid = threadIdx.x;
  for (int i = tid; i < CQ * C; i += 256) { wql[i] = Wq[i]; wkl[i] = Wk[i]; }
  for (int i = tid; i < C * C; i += 256) wvl[i] = Wv[i];
  if (tid < CQ) { bql[tid] = bq[tid]; bkl[tid] = bk[tid]; }
  if (tid < C) bvl[tid] = bv[tid];
  __syncthreads();
  const int pix = blockIdx.x * 256 + tid;
  if (pix >= B * HW) return;
  const int b = pix / HW;
  const int r = pix - b * HW;
  const int h = r / W;
  const int w = r - h * W;

  float qa[CQ], ka[CQ], va[C];
#pragma unroll
  for (int o = 0; o < CQ; ++o) { qa[o] = bql[o]; ka[o] = bkl[o]; }
#pragma unroll
  for (int o = 0; o < C; ++o) va[o] = bvl[o];

  const float* xp = x + (size_t)b * C * HW + r;
  for (int c = 0; c < C; c += 4) {
    const float x0 = xp[(size_t)(c + 0) * HW];
    const float x1 = xp[(size_t)(c + 1) * HW];
    const float x2 = xp[(size_t)(c + 2) * HW];
    const float x3 = xp[(size_t)(c + 3) * HW];
#pragma unroll
    for (int o = 0; o < CQ; ++o) {
      const float4 a = *(const float4*)(wql + o * C + c);
      qa[o] = fmaf(a.w, x3, fmaf(a.z, x2, fmaf(a.y, x1, fmaf(a.x, x0, qa[o]))));
      const float4 bb = *(const float4*)(wkl + o * C + c);
      ka[o] = fmaf(bb.w, x3, fmaf(bb.z, x2, fmaf(bb.y, x1, fmaf(bb.x, x0, ka[o]))));
    }
#pragma unroll
    for (int o = 0; o < C; ++o) {
      const float4 cc = *(const float4*)(wvl + o * C + c);
      va[o] = fmaf(cc.w, x3, fmaf(cc.z, x2, fmaf(cc.y, x1, fmaf(cc.x, x0, va[o]))));
    }
  }

  uint4 qp4, kp4;
  qp4.x = pack2(qa[0], qa[1]); qp4.y = pack2(qa[2], qa[3]);
  qp4.z = pack2(qa[4], qa[5]); qp4.w = pack2(qa[6], qa[7]);
  kp4.x = pack2(ka[0], ka[1]); kp4.y = pack2(ka[2], ka[3]);
  kp4.z = pack2(ka[4], ka[5]); kp4.w = pack2(ka[6], ka[7]);
  *(uint4*)(qwp + (size_t)pix * 8) = qp4;
  *(uint4*)(kwp + (size_t)pix * 8) = kp4;
  const size_t tbase = ((size_t)b * W + w) * H + h;
  *(uint4*)(qhp + tbase * 8) = qp4;
  *(uint4*)(khp + tbase * 8) = kp4;

  unsigned short* vp = v + (size_t)b * C * HW + r;
#pragma unroll
  for (int o = 0; o < C; ++o) vp[(size_t)o * HW] = f2bf(va[o]);
  unsigned short* vtp = vt + tbase * C;
#pragma unroll
  for (int j = 0; j < 16; ++j) {
    ushort4 u;
    u.x = f2bf(va[4 * j + 0]);
    u.y = f2bf(va[4 * j + 1]);
    u.z = f2bf(va[4 * j + 2]);
    u.w = f2bf(va[4 * j + 3]);
    *(ushort4*)(vtp + 4 * j) = u;
  }
}

// ---------------------------------------------------------------------------
// K2: out_w unnormalized + S_w. TWO blocks per (b,h) (z = blockIdx.x&1):
// 512 thr = 8 waves, chunks z*8+wv (M=480 = 15 chunks; z=1 wv7 idle).
// Parallel-E (R6's measured-best form; R7's sequential-mt lost ILP and ~16us).
// Async staging (T14): all global loads -> regs first, then LDS writes (one
// latency exposure instead of 15). kb prefetch hides the per-ci ds_read chain.
// ---------------------------------------------------------------------------
constexpr int VSW = 494;

__global__ __launch_bounds__(512, 1)
void k_outw(const unsigned short* __restrict__ qwp,
            const unsigned short* __restrict__ kwp,
            const unsigned short* __restrict__ v,
            unsigned short* __restrict__ ow, float* __restrict__ Sw) {
  __shared__ __align__(16) unsigned short vbs[64 * VSW];   // 63232 B
  __shared__ __align__(16) unsigned short kls[480 * 8];    // 7680 B
  const int h = blockIdx.x >> 1, z = blockIdx.x & 1;
  const int b = blockIdx.y;
  const int tid = threadIdx.x;
  const size_t rowbase = ((size_t)b * H + h) * W;

  const unsigned short* vrow = v + (size_t)b * C * HW + (size_t)h * W;
  // ---- async staging: load batch 1 (8), write, load batch 2 (7), write ----
  ushort4 vr0[8];
#pragma unroll
  for (int it = 0; it < 8; ++it) {
    const int idx = tid + it * 512;
    const int c = idx / 120, s4 = (idx - c * 120) * 4;
    vr0[it] = *(const ushort4*)(vrow + (size_t)c * HW + s4);
  }
  uint4 kreg;
  if (tid < 480) kreg = *(const uint4*)(kwp + (rowbase + tid) * 8);
#pragma unroll
  for (int it = 0; it < 8; ++it) {
    const int idx = tid + it * 512;
    const int c = idx / 120, s4 = (idx - c * 120) * 4;
    const int u = s4 & 31;
    const int t = (u < 16) ? ((u >> 2) * 8) : (((u - 16) >> 2) * 8 + 4);
    *(ushort4*)(vbs + c * VSW + (s4 & ~31) + t) = vr0[it];
  }
  ushort4 vr1[7];
#pragma unroll
  for (int it = 0; it < 7; ++it) {
    const int idx = tid + (8 + it) * 512;
    const int c = idx / 120, s4 = (idx - c * 120) * 4;
    vr1[it] = *(const ushort4*)(vrow + (size_t)c * HW + s4);
  }
#pragma unroll
  for (int it = 0; it < 7; ++it) {
    const int idx = tid + (8 + it) * 512;
    const int c = idx / 120, s4 = (idx - c * 120) * 4;
    const int u = s4 & 31;
    const int t = (u < 16) ? ((u >> 2) * 8) : (((u - 16) >> 2) * 8 + 4);
    *(ushort4*)(vbs + c * VSW + (s4 & ~31) + t) = vr1[it];
  }
  if (tid < 480) *(uint4*)(kls + tid * 8) = kreg;

  const int lane = tid & 63, wv = tid >> 6;
  const int l15 = lane & 15, quad = lane >> 4;
  const int chunk = z * 8 + wv;
  const bool active = chunk < 15;
  const int m0 = chunk * 32;

  short8 qa0 = short8{0, 0, 0, 0, 0, 0, 0, 0};
  short8 qa1 = short8{0, 0, 0, 0, 0, 0, 0, 0};
  if (quad == 0 && active) {
    qa0 = *(const short8*)(qwp + (rowbase + m0 + l15) * 8);
    qa1 = *(const short8*)(qwp + (rowbase + m0 + 16 + l15) * 8);
  }

  f32x4 acc[2][4];
  float Sacc[2] = {0.0f, 0.0f};
#pragma unroll
  for (int mt = 0; mt < 2; ++mt)
#pragma unroll
    for (int ct = 0; ct < 4; ++ct)
#pragma unroll
      for (int rr = 0; rr < 4; ++rr) acc[mt][ct][rr] = 0.0f;

  __syncthreads();

  if (active) {
    short8 kb0 = short8{0, 0, 0, 0, 0, 0, 0, 0};
    short8 kb1 = short8{0, 0, 0, 0, 0, 0, 0, 0};
    if (quad == 0) {
      kb0 = *(const short8*)(kls + (l15) * 8);
      kb1 = *(const short8*)(kls + (16 + l15) * 8);
    }
    for (int ci = 0; ci < 15; ++ci) {
      const int sc = ci * 32;
      short8 nk0 = short8{0, 0, 0, 0, 0, 0, 0, 0};
      short8 nk1 = short8{0, 0, 0, 0, 0, 0, 0, 0};
      if (ci < 14 && quad == 0) {
        nk0 = *(const short8*)(kls + (sc + 32 + l15) * 8);
        nk1 = *(const short8*)(kls + (sc + 48 + l15) * 8);
      }
      short8 vb[4];
#pragma unroll
      for (int ct = 0; ct < 4; ++ct)
        vb[ct] = *(const short8*)(vbs + (ct * 16 + l15) * VSW + sc + quad * 8);
      const f32x4 z4 = f32x4{0.f, 0.f, 0.f, 0.f};
      const f32x4 E00 = __builtin_amdgcn_mfma_f32_16x16x32_bf16(kb0, qa0, z4, 0, 0, 0);
      const f32x4 E01 = __builtin_amdgcn_mfma_f32_16x16x32_bf16(kb1, qa0, z4, 0, 0, 0);
      const f32x4 E10 = __builtin_amdgcn_mfma_f32_16x16x32_bf16(kb0, qa1, z4, 0, 0, 0);
      const f32x4 E11 = __builtin_amdgcn_mfma_f32_16x16x32_bf16(kb1, qa1, z4, 0, 0, 0);
#pragma unroll
      for (int mt = 0; mt < 2; ++mt) {
        const int m = m0 + mt * 16 + l15;
        const f32x4 Ea = mt ? E10 : E00;
        const f32x4 Eb = mt ? E11 : E01;
        float p0[4], p1[4];
#pragma unroll
        for (int rr = 0; rr < 4; ++rr) {
          const float d0 = (float)(m - (sc + quad * 4 + rr));
          const float d1 = d0 - 16.0f;
          p0[rr] = __expf(Ea[rr] * __expf(-(d0 * d0) * INVW2));
          p1[rr] = __expf(Eb[rr] * __expf(-(d1 * d1) * INVW2));
          Sacc[mt] += p0[rr] + p1[rr];
        }
        const short8 pa = pack_p(p0, p1);
#pragma unroll
        for (int ct = 0; ct < 4; ++ct)
          acc[mt][ct] = __builtin_amdgcn_mfma_f32_16x16x32_bf16(pa, vb[ct], acc[mt][ct], 0, 0, 0);
      }
      kb0 = nk0;
      kb1 = nk1;
    }

#pragma unroll
    for (int mt = 0; mt < 2; ++mt) {
      float s = Sacc[mt];
      s += __shfl_xor(s, 16);
      s += __shfl_xor(s, 32);
      if (lane < 16) Sw[rowbase + m0 + mt * 16 + l15] = s;
    }
  }

  __syncthreads();  // vbs reads done; reuse as [c][480] transpose buffer
  unsigned short* ob = vbs;
  if (active) {
#pragma unroll
    for (int mt = 0; mt < 2; ++mt)
#pragma unroll
      for (int ct = 0; ct < 4; ++ct)
#pragma unroll
        for (int rr = 0; rr < 4; ++rr)
          ob[(ct * 16 + l15) * VSW + m0 + mt * 16 + quad * 4 + rr] = f2bf(acc[mt][ct][rr]);
  }
  __syncthreads();
  unsigned short* og = ow + ((size_t)b * H + h) * C * W;
  const int mlo = z ? 256 : 0;
  const int nu = z ? 112 : 128;  // u32 per c-row in this block's m-range
  for (int idx = tid; idx < 64 * nu; idx += 512) {
    const int c = idx / nu, i = idx - c * nu;
    *(unsigned int*)(og + (size_t)c * W + mlo + 2 * i) =
        *(const unsigned int*)(ob + c * VSW + mlo + 2 * i);
  }
}

// ---------------------------------------------------------------------------
// K3: out_h unnormalized + S_h. ONE block per (b,w): 576 thr = 9 waves, wave
// wv owns chunk wv of 32 m-rows (M=288; rows >= 270 pad). Parallel-E (R4's
// measured-best). Async staging: 8 vt ushort4 loads -> regs, then scatter
// ds_writes (one HBM latency instead of 8). kb prefetch in the ci loop.
// Outputs oht [b][w][c][h], Sht [b][w][h].
// ---------------------------------------------------------------------------
constexpr int VSH = 302;

__global__ __launch_bounds__(576, 1)
void k_outh(const unsigned short* __restrict__ qhp,
            const unsigned short* __restrict__ khp,
            const unsigned short* __restrict__ vt,
            unsigned short* __restrict__ oht, float* __restrict__ Sht) {
  __shared__ __align__(16) unsigned short vbs[64 * VSH];   // 38656 B
  __shared__ __align__(16) unsigned short kls[288 * 8];    // 4608 B
  const int w = blockIdx.x;
  const int b = blockIdx.y;
  const int tid = threadIdx.x;
  const size_t colbase = ((size_t)b * W + w) * H;

  const unsigned short* vtb = vt + colbase * C;
  // ---- async staging: 288*16 = 4608 = 8*576 exactly ----
  ushort4 vreg[8];
#pragma unroll
  for (int it = 0; it < 8; ++it) {
    const int idx = tid + it * 576;
    const int g = idx >> 4, c4 = (idx & 15) * 4;
    vreg[it] = (g < H) ? *(const ushort4*)(vtb + (size_t)g * C + c4)
                       : make_ushort4(0, 0, 0, 0);
  }
  uint4 kreg;
  if (tid < 288) kreg = *(const uint4*)(khp + (colbase + min(tid, H - 1)) * 8);
#pragma unroll
  for (int it = 0; it < 8; ++it) {
    const int idx = tid + it * 576;
    const int g = idx >> 4, c4 = (idx & 15) * 4;
    const int u = g & 31;
    const int t = (u < 16) ? ((u >> 2) * 8 + (u & 3))
                           : (((u - 16) >> 2) * 8 + 4 + (u & 3));
    const int slot = (g & ~31) + t;
    vbs[(c4 + 0) * VSH + slot] = vreg[it].x;
    vbs[(c4 + 1) * VSH + slot] = vreg[it].y;
    vbs[(c4 + 2) * VSH + slot] = vreg[it].z;
    vbs[(c4 + 3) * VSH + slot] = vreg[it].w;
  }
  if (tid < 288) *(uint4*)(kls + tid * 8) = kreg;

  const int lane = tid & 63, wv = tid >> 6;
  const int l15 = lane & 15, quad = lane >> 4;
  const int m0 = wv * 32;

  short8 qa0 = short8{0, 0, 0, 0, 0, 0, 0, 0};
  short8 qa1 = short8{0, 0, 0, 0, 0, 0, 0, 0};
  if (quad == 0) {
    qa0 = *(const short8*)(qhp + (colbase + min(m0 + l15, H - 1)) * 8);
    qa1 = *(const short8*)(qhp + (colbase + min(m0 + 16 + l15, H - 1)) * 8);
  }

  f32x4 acc[2][4];
  float Sacc[2] = {0.0f, 0.0f};
#pragma unroll
  for (int mt = 0; mt < 2; ++mt)
#pragma unroll
    for (int ct = 0; ct < 4; ++ct)
#pragma unroll
      for (int rr = 0; rr < 4; ++rr) acc[mt][ct][rr] = 0.0f;

  __syncthreads();

  {
    short8 kb0 = short8{0, 0, 0, 0, 0, 0, 0, 0};
    short8 kb1 = short8{0, 0, 0, 0, 0, 0, 0, 0};
    if (quad == 0) {
      kb0 = *(const short8*)(kls + (l15) * 8);
      kb1 = *(const short8*)(kls + (16 + l15) * 8);
    }
    for (int ci = 0; ci < 9; ++ci) {
      const int gc = ci * 32;
      short8 nk0 = short8{0, 0, 0, 0, 0, 0, 0, 0};
      short8 nk1 = short8{0, 0, 0, 0, 0, 0, 0, 0};
      if (ci < 8 && quad == 0) {
        nk0 = *(const short8*)(kls + (gc + 32 + l15) * 8);
        nk1 = *(const short8*)(kls + (gc + 48 + l15) * 8);
      }
      short8 vb[4];
#pragma unroll
      for (int ct = 0; ct < 4; ++ct)
        vb[ct] = *(const short8*)(vbs + (ct * 16 + l15) * VSH + gc + quad * 8);
      const f32x4 z4 = f32x4{0.f, 0.f, 0.f, 0.f};
      const f32x4 E00 = __builtin_amdgcn_mfma_f32_16x16x32_bf16(kb0, qa0, z4, 0, 0, 0);
      const f32x4 E01 = __builtin_amdgcn_mfma_f32_16x16x32_bf16(kb1, qa0, z4, 0, 0, 0);
      const f32x4 E10 = __builtin_amdgcn_mfma_f32_16x16x32_bf16(kb0, qa1, z4, 0, 0, 0);
      const f32x4 E11 = __builtin_amdgcn_mfma_f32_16x16x32_bf16(kb1, qa1, z4, 0, 0, 0);
#pragma unroll
      for (int mt = 0; mt < 2; ++mt) {
        const int m = m0 + mt * 16 + l15;
        const f32x4 Ea = mt ? E10 : E00;
        const f32x4 Eb = mt ? E11 : E01;
        float p0[4], p1[4];
#pragma unroll
        for (int rr = 0; rr < 4; ++rr) {
          const int g0 = gc + quad * 4 + rr;
          const int g1 = g0 + 16;
          const float d0 = (float)(m - g0);
          const float d1 = d0 - 16.0f;
          p0[rr] = (g0 < H && g0 != m)
                       ? __expf(Ea[rr] * __expf(-(d0 * d0) * INVH2)) : 0.0f;
          p1[rr] = (g1 < H && g1 != m)
                       ? __expf(Eb[rr] * __expf(-(d1 * d1) * INVH2)) : 0.0f;
          Sacc[mt] += p0[rr] + p1[rr];
        }
        const short8 pa = pack_p(p0, p1);
#pragma unroll
        for (int ct = 0; ct < 4; ++ct)
          acc[mt][ct] = __builtin_amdgcn_mfma_f32_16x16x32_bf16(pa, vb[ct], acc[mt][ct], 0, 0, 0);
      }
      kb0 = nk0;
      kb1 = nk1;
    }
  }

#pragma unroll
  for (int mt = 0; mt < 2; ++mt) {
    float s = Sacc[mt];
    s += __shfl_xor(s, 16);
    s += __shfl_xor(s, 32);
    const int m = m0 + mt * 16 + l15;
    if (lane < 16 && m < H) Sht[colbase + m] = s;
  }

  __syncthreads();
  unsigned short* ob = vbs;  // [c][288] stride VSH
#pragma unroll
  for (int mt = 0; mt < 2; ++mt)
#pragma unroll
    for (int ct = 0; ct < 4; ++ct)
#pragma unroll
      for (int rr = 0; rr < 4; ++rr)
        ob[(ct * 16 + l15) * VSH + m0 + mt * 16 + quad * 4 + rr] = f2bf(acc[mt][ct][rr]);
  __syncthreads();
  unsigned short* og = oht + ((size_t)b * W + w) * C * H;
  for (int idx = tid; idx < 64 * 135; idx += 576) {
    const int c = idx / 135, hp = idx - c * 135;
    *(unsigned int*)(og + (size_t)c * H + 2 * hp) =
        *(const unsigned int*)(ob + c * VSH + 2 * hp);
  }
}

// ---------------------------------------------------------------------------
// K4: out = gamma*(U_h + U_w)/(S_h+S_w) + x, LDS tile transpose for oht.
// Sht is [b][w][h] (1 MB, L2-resident, 64x c-reuse -> strided read is cheap).
// ---------------------------------------------------------------------------
__global__ __launch_bounds__(256)
void k_combine(const unsigned short* __restrict__ oht,
               const unsigned short* __restrict__ ow,
               const float* __restrict__ Sht, const float* __restrict__ Sw,
               const float* __restrict__ x,
               const float* __restrict__ gp,
               float* __restrict__ out) {
  __shared__ float tile[32][33];
  const int b = blockIdx.z >> 6, c = blockIdx.z & 63;
  const int w0 = blockIdx.x * 32, h0 = blockIdx.y * 32;
  const int tx = threadIdx.x, ty = threadIdx.y;  // (32, 8)
#pragma unroll
  for (int i = 0; i < 4; ++i) {
    const int wl = ty + i * 8;
    const int hh = h0 + tx;
    float val = 0.0f;
    if (hh < H) val = bits2f(oht[(((size_t)b * W + (w0 + wl)) * C + c) * H + hh]);
    tile[wl][tx] = val;
  }
  __syncthreads();
  const float gamma = *gp;
#pragma unroll
  for (int i = 0; i < 4; ++i) {
    const int hl = ty + i * 8;
    const int hh = h0 + hl;
    if (hh < H) {
      const int ww = w0 + tx;
      const float uh = tile[tx][hl];
      const float uw = bits2f(ow[(((size_t)b * H + hh) * C + c) * W + ww]);
      const size_t si = ((size_t)b * H + hh) * W + ww;
      const float Z = Sht[((size_t)b * W + ww) * H + hh] + Sw[si];
      const float invZ = __builtin_amdgcn_rcpf(Z);
      const size_t xi = ((size_t)b * C + c) * HW + (size_t)hh * W + ww;
      out[xi] = fmaf(gamma * invZ, uh + uw, x[xi]);
    }
  }
}

}  // namespace

extern "C" void kernel_launch(void* const* d_in, const int* in_sizes, int n_in,
                              void* d_out, int out_size, void* d_ws, size_t ws_size,
                              hipStream_t stream) {
  (void)in_sizes; (void)n_in; (void)out_size; (void)ws_size;
  const float* x  = (const float*)d_in[0];
  const float* Wq = (const float*)d_in[1];
  const float* bq = (const float*)d_in[2];
  const float* Wk = (const float*)d_in[3];
  const float* bk = (const float*)d_in[4];
  const float* Wv = (const float*)d_in[5];
  const float* bv = (const float*)d_in[6];
  const float* gp = (const float*)d_in[7];
  float* out = (float*)d_out;

  char* p = (char*)d_ws;
  auto take = [&](size_t bytes) -> void* {
    char* r = p;
    p += (bytes + 255) & ~(size_t)255;
    return (void*)r;
  };
  unsigned short* qwp = (unsigned short*)take(sizeof(unsigned short) * (size_t)B * HW * 8);
  unsigned short* kwp = (unsigned short*)take(sizeof(unsigned short) * (size_t)B * HW * 8);
  unsigned short* qhp = (unsigned short*)take(sizeof(unsigned short) * (size_t)B * HW * 8);
  unsigned short* khp = (unsigned short*)take(sizeof(unsigned short) * (size_t)B * HW * 8);
  unsigned short* v   = (unsigned short*)take(sizeof(unsigned short) * (size_t)B * C * HW);
  unsigned short* vt  = (unsigned short*)take(sizeof(unsigned short) * (size_t)B * C * HW);
  unsigned short* oht = (unsigned short*)take(sizeof(unsigned short) * (size_t)B * C * HW);
  unsigned short* owb = (unsigned short*)take(sizeof(unsigned short) * (size_t)B * C * HW);
  float* Sht = (float*)take(sizeof(float) * (size_t)B * HW);
  float* Sw  = (float*)take(sizeof(float) * (size_t)B * HW);

  hipLaunchKernelGGL(k_qkv, dim3((B * HW + 255) / 256), dim3(256), 0, stream,
                     x, Wq, bq, Wk, bk, Wv, bv, qwp, kwp, qhp, khp, v, vt);
  hipLaunchKernelGGL(k_outh, dim3(W, B), dim3(576), 0, stream,
                     qhp, khp, vt, oht, Sht);
  hipLaunchKernelGGL(k_outw, dim3(2 * H, B), dim3(512), 0, stream,
                     qwp, kwp, v, owb, Sw);
  hipLaunchKernelGGL(k_combine, dim3(W / 32, (H + 31) / 32, B * C), dim3(32, 8), 0, stream,
                     oht, owb, Sht, Sw, x, gp, out);
}

// Round 9
// 405.025 us; speedup vs baseline: 1.7417x; 1.0714x over previous
//
#include <hip/hip_runtime.h>
#include <hip/hip_bf16.h>

namespace {

constexpr int B  = 2;
constexpr int C  = 64;
constexpr int CQ = 8;
constexpr int H  = 270;
constexpr int W  = 480;
constexpr int HW = H * W;
constexpr float INVH2 = 2.0f / (270.0f * 270.0f);  // dw_h = exp(-d^2 * INVH2)
constexpr float INVW2 = 2.0f / (480.0f * 480.0f);

typedef __attribute__((ext_vector_type(4))) float f32x4;
typedef __attribute__((ext_vector_type(8))) short short8;
typedef __attribute__((ext_vector_type(4))) unsigned int uint4v;

__device__ __forceinline__ float bits2f(unsigned short u) {
  union { unsigned int i; float f; } cv;
  cv.i = ((unsigned int)u) << 16;
  return cv.f;
}

__device__ __forceinline__ unsigned short f2bf(float f) {
  union { __hip_bfloat16 b; unsigned short u; } cv;
  cv.b = __float2bfloat16(f);
  return cv.u;
}

__device__ __forceinline__ unsigned int pack2(float a, float b) {
  return ((unsigned int)f2bf(b) << 16) | (unsigned int)f2bf(a);
}

__device__ __forceinline__ short8 pack_p(const float p0[4], const float p1[4]) {
  uint4v pw;
  pw[0] = pack2(p0[0], p0[1]);
  pw[1] = pack2(p0[2], p0[3]);
  pw[2] = pack2(p1[0], p1[1]);
  pw[3] = pack2(p1[2], p1[3]);
  return __builtin_bit_cast(short8, pw);
}

// V-row permutation inside each 32-row K-step so that the swapped-QK P layout
// (lane quad q holds g = 4q+rr from E0 and 16+4q+rr from E1) feeds the PV
// A-fragment (k-slot q*8+j) with NO cross-lane data movement:
//   u < 16: slot = 8*(u>>2) + (u&3);  u >= 16: slot = 8*((u-16)>>2) + 4 + (u&3)

// ---------------------------------------------------------------------------
// K1: q/k/v 1x1 projections. One thread per pixel. Writes bf16 packs:
// qwp/kwp [b][h][w][8], qhp/khp [b][w][h][8], v [b][c][h][w], vt [b][w][h][c].
// ---------------------------------------------------------------------------
__global__ __launch_bounds__(256)
void k_qkv(const float* __restrict__ x,
           const float* __restrict__ Wq, const float* __restrict__ bq,
           const float* __restrict__ Wk, const float* __restrict__ bk,
           const float* __restrict__ Wv, const float* __restrict__ bv,
           unsigned short* __restrict__ qwp, unsigned short* __restrict__ kwp,
           unsigned short* __restrict__ qhp, unsigned short* __restrict__ khp,
           unsigned short* __restrict__ v, unsigned short* __restrict__ vt) {
  __shared__ __align__(16) float wql[CQ * C];
  __shared__ __align__(16) float wkl[CQ * C];
  __shared__ __align__(16) float wvl[C * C];
  __shared__ float bql[CQ], bkl[CQ], bvl[C];
  const int tid = threadIdx.x;
  for (int i = tid; i < CQ * C; i += 256) { wql[i] = Wq[i]; wkl[i] = Wk[i]; }
  for (int i = tid; i < C * C; i += 256) wvl[i] = Wv[i];
  if (tid < CQ) { bql[tid] = bq[tid]; bkl[tid] = bk[tid]; }
  if (tid < C) bvl[tid] = bv[tid];
  __syncthreads();
  const int pix = blockIdx.x * 256 + tid;
  if (pix >= B * HW) return;
  const int b = pix / HW;
  const int r = pix - b * HW;
  const int h = r / W;
  const int w = r - h * W;

  float qa[CQ], ka[CQ], va[C];
#pragma unroll
  for (int o = 0; o < CQ; ++o) { qa[o] = bql[o]; ka[o] = bkl[o]; }
#pragma unroll
  for (int o = 0; o < C; ++o) va[o] = bvl[o];

  const float* xp = x + (size_t)b * C * HW + r;
  for (int c = 0; c < C; c += 4) {
    const float x0 = xp[(size_t)(c + 0) * HW];
    const float x1 = xp[(size_t)(c + 1) * HW];
    const float x2 = xp[(size_t)(c + 2) * HW];
    const float x3 = xp[(size_t)(c + 3) * HW];
#pragma unroll
    for (int o = 0; o < CQ; ++o) {
      const float4 a = *(const float4*)(wql + o * C + c);
      qa[o] = fmaf(a.w, x3, fmaf(a.z, x2, fmaf(a.y, x1, fmaf(a.x, x0, qa[o]))));
      const float4 bb = *(const float4*)(wkl + o * C + c);
      ka[o] = fmaf(bb.w, x3, fmaf(bb.z, x2, fmaf(bb.y, x1, fmaf(bb.x, x0, ka[o]))));
    }
#pragma unroll
    for (int o = 0; o < C; ++o) {
      const float4 cc = *(const float4*)(wvl + o * C + c);
      va[o] = fmaf(cc.w, x3, fmaf(cc.z, x2, fmaf(cc.y, x1, fmaf(cc.x, x0, va[o]))));
    }
  }

  uint4 qp4, kp4;
  qp4.x = pack2(qa[0], qa[1]); qp4.y = pack2(qa[2], qa[3]);
  qp4.z = pack2(qa[4], qa[5]); qp4.w = pack2(qa[6], qa[7]);
  kp4.x = pack2(ka[0], ka[1]); kp4.y = pack2(ka[2], ka[3]);
  kp4.z = pack2(ka[4], ka[5]); kp4.w = pack2(ka[6], ka[7]);
  *(uint4*)(qwp + (size_t)pix * 8) = qp4;
  *(uint4*)(kwp + (size_t)pix * 8) = kp4;
  const size_t tbase = ((size_t)b * W + w) * H + h;
  *(uint4*)(qhp + tbase * 8) = qp4;
  *(uint4*)(khp + tbase * 8) = kp4;

  unsigned short* vp = v + (size_t)b * C * HW + r;
#pragma unroll
  for (int o = 0; o < C; ++o) vp[(size_t)o * HW] = f2bf(va[o]);
  unsigned short* vtp = vt + tbase * C;
#pragma unroll
  for (int j = 0; j < 16; ++j) {
    ushort4 u;
    u.x = f2bf(va[4 * j + 0]);
    u.y = f2bf(va[4 * j + 1]);
    u.z = f2bf(va[4 * j + 2]);
    u.w = f2bf(va[4 * j + 3]);
    *(ushort4*)(vtp + 4 * j) = u;
  }
}

// ---------------------------------------------------------------------------
// K2: out_w unnormalized + S_w. Byte-identical to R8 (measured < 108 us,
// likely 2-block resident at 8 waves x 116 regs = 464 <= 512).
// ---------------------------------------------------------------------------
constexpr int VSW = 494;

__global__ __launch_bounds__(512, 1)
void k_outw(const unsigned short* __restrict__ qwp,
            const unsigned short* __restrict__ kwp,
            const unsigned short* __restrict__ v,
            unsigned short* __restrict__ ow, float* __restrict__ Sw) {
  __shared__ __align__(16) unsigned short vbs[64 * VSW];   // 63232 B
  __shared__ __align__(16) unsigned short kls[480 * 8];    // 7680 B
  const int h = blockIdx.x >> 1, z = blockIdx.x & 1;
  const int b = blockIdx.y;
  const int tid = threadIdx.x;
  const size_t rowbase = ((size_t)b * H + h) * W;

  const unsigned short* vrow = v + (size_t)b * C * HW + (size_t)h * W;
  // ---- async staging: load batch 1 (8), write, load batch 2 (7), write ----
  ushort4 vr0[8];
#pragma unroll
  for (int it = 0; it < 8; ++it) {
    const int idx = tid + it * 512;
    const int c = idx / 120, s4 = (idx - c * 120) * 4;
    vr0[it] = *(const ushort4*)(vrow + (size_t)c * HW + s4);
  }
  uint4 kreg;
  if (tid < 480) kreg = *(const uint4*)(kwp + (rowbase + tid) * 8);
#pragma unroll
  for (int it = 0; it < 8; ++it) {
    const int idx = tid + it * 512;
    const int c = idx / 120, s4 = (idx - c * 120) * 4;
    const int u = s4 & 31;
    const int t = (u < 16) ? ((u >> 2) * 8) : (((u - 16) >> 2) * 8 + 4);
    *(ushort4*)(vbs + c * VSW + (s4 & ~31) + t) = vr0[it];
  }
  ushort4 vr1[7];
#pragma unroll
  for (int it = 0; it < 7; ++it) {
    const int idx = tid + (8 + it) * 512;
    const int c = idx / 120, s4 = (idx - c * 120) * 4;
    vr1[it] = *(const ushort4*)(vrow + (size_t)c * HW + s4);
  }
#pragma unroll
  for (int it = 0; it < 7; ++it) {
    const int idx = tid + (8 + it) * 512;
    const int c = idx / 120, s4 = (idx - c * 120) * 4;
    const int u = s4 & 31;
    const int t = (u < 16) ? ((u >> 2) * 8) : (((u - 16) >> 2) * 8 + 4);
    *(ushort4*)(vbs + c * VSW + (s4 & ~31) + t) = vr1[it];
  }
  if (tid < 480) *(uint4*)(kls + tid * 8) = kreg;

  const int lane = tid & 63, wv = tid >> 6;
  const int l15 = lane & 15, quad = lane >> 4;
  const int chunk = z * 8 + wv;
  const bool active = chunk < 15;
  const int m0 = chunk * 32;

  short8 qa0 = short8{0, 0, 0, 0, 0, 0, 0, 0};
  short8 qa1 = short8{0, 0, 0, 0, 0, 0, 0, 0};
  if (quad == 0 && active) {
    qa0 = *(const short8*)(qwp + (rowbase + m0 + l15) * 8);
    qa1 = *(const short8*)(qwp + (rowbase + m0 + 16 + l15) * 8);
  }

  f32x4 acc[2][4];
  float Sacc[2] = {0.0f, 0.0f};
#pragma unroll
  for (int mt = 0; mt < 2; ++mt)
#pragma unroll
    for (int ct = 0; ct < 4; ++ct)
#pragma unroll
      for (int rr = 0; rr < 4; ++rr) acc[mt][ct][rr] = 0.0f;

  __syncthreads();

  if (active) {
    short8 kb0 = short8{0, 0, 0, 0, 0, 0, 0, 0};
    short8 kb1 = short8{0, 0, 0, 0, 0, 0, 0, 0};
    if (quad == 0) {
      kb0 = *(const short8*)(kls + (l15) * 8);
      kb1 = *(const short8*)(kls + (16 + l15) * 8);
    }
    for (int ci = 0; ci < 15; ++ci) {
      const int sc = ci * 32;
      short8 nk0 = short8{0, 0, 0, 0, 0, 0, 0, 0};
      short8 nk1 = short8{0, 0, 0, 0, 0, 0, 0, 0};
      if (ci < 14 && quad == 0) {
        nk0 = *(const short8*)(kls + (sc + 32 + l15) * 8);
        nk1 = *(const short8*)(kls + (sc + 48 + l15) * 8);
      }
      short8 vb[4];
#pragma unroll
      for (int ct = 0; ct < 4; ++ct)
        vb[ct] = *(const short8*)(vbs + (ct * 16 + l15) * VSW + sc + quad * 8);
      const f32x4 z4 = f32x4{0.f, 0.f, 0.f, 0.f};
      const f32x4 E00 = __builtin_amdgcn_mfma_f32_16x16x32_bf16(kb0, qa0, z4, 0, 0, 0);
      const f32x4 E01 = __builtin_amdgcn_mfma_f32_16x16x32_bf16(kb1, qa0, z4, 0, 0, 0);
      const f32x4 E10 = __builtin_amdgcn_mfma_f32_16x16x32_bf16(kb0, qa1, z4, 0, 0, 0);
      const f32x4 E11 = __builtin_amdgcn_mfma_f32_16x16x32_bf16(kb1, qa1, z4, 0, 0, 0);
#pragma unroll
      for (int mt = 0; mt < 2; ++mt) {
        const int m = m0 + mt * 16 + l15;
        const f32x4 Ea = mt ? E10 : E00;
        const f32x4 Eb = mt ? E11 : E01;
        float p0[4], p1[4];
#pragma unroll
        for (int rr = 0; rr < 4; ++rr) {
          const float d0 = (float)(m - (sc + quad * 4 + rr));
          const float d1 = d0 - 16.0f;
          p0[rr] = __expf(Ea[rr] * __expf(-(d0 * d0) * INVW2));
          p1[rr] = __expf(Eb[rr] * __expf(-(d1 * d1) * INVW2));
          Sacc[mt] += p0[rr] + p1[rr];
        }
        const short8 pa = pack_p(p0, p1);
#pragma unroll
        for (int ct = 0; ct < 4; ++ct)
          acc[mt][ct] = __builtin_amdgcn_mfma_f32_16x16x32_bf16(pa, vb[ct], acc[mt][ct], 0, 0, 0);
      }
      kb0 = nk0;
      kb1 = nk1;
    }

#pragma unroll
    for (int mt = 0; mt < 2; ++mt) {
      float s = Sacc[mt];
      s += __shfl_xor(s, 16);
      s += __shfl_xor(s, 32);
      if (lane < 16) Sw[rowbase + m0 + mt * 16 + l15] = s;
    }
  }

  __syncthreads();  // vbs reads done; reuse as [c][480] transpose buffer
  unsigned short* ob = vbs;
  if (active) {
#pragma unroll
    for (int mt = 0; mt < 2; ++mt)
#pragma unroll
      for (int ct = 0; ct < 4; ++ct)
#pragma unroll
        for (int rr = 0; rr < 4; ++rr)
          ob[(ct * 16 + l15) * VSW + m0 + mt * 16 + quad * 4 + rr] = f2bf(acc[mt][ct][rr]);
  }
  __syncthreads();
  unsigned short* og = ow + ((size_t)b * H + h) * C * W;
  const int mlo = z ? 256 : 0;
  const int nu = z ? 112 : 128;  // u32 per c-row in this block's m-range
  for (int idx = tid; idx < 64 * nu; idx += 512) {
    const int c = idx / nu, i = idx - c * nu;
    *(unsigned int*)(og + (size_t)c * W + mlo + 2 * i) =
        *(const unsigned int*)(ob + c * VSW + mlo + 2 * i);
  }
}

// ---------------------------------------------------------------------------
// K3: out_h unnormalized + S_h. 16-ROW WAVES: TWO blocks per (b,w)
// (z = blockIdx.x&1), 576 thr = 9 waves, wave wv owns chunk z*9+wv of 16
// m-rows (18 chunks x 16 = M=288; rows >= 270 pad). Halving the per-wave tile
// halves acc(32->16)/qa(8->4)/E(16->8) => ~88-96 regs, so TWO 9-wave blocks
// co-reside (busiest SIMD 5 waves x 96 = 480 <= 512): 4.5 waves/SIMD vs the
// 32-row structure's hard 1-block wall (5 x 116 = 580). kb prefetch dropped
// (8 regs; TLP now covers the ds_read latency). Staging duplicated per z-pair
// but hidden under the co-resident block's compute.
// Outputs oht [b][w][c][h], Sht [b][w][h].
// ---------------------------------------------------------------------------
constexpr int VSH = 302;

__global__ __launch_bounds__(576, 1)
void k_outh(const unsigned short* __restrict__ qhp,
            const unsigned short* __restrict__ khp,
            const unsigned short* __restrict__ vt,
            unsigned short* __restrict__ oht, float* __restrict__ Sht) {
  __shared__ __align__(16) unsigned short vbs[64 * VSH];   // 38656 B
  __shared__ __align__(16) unsigned short kls[288 * 8];    // 4608 B
  const int w = blockIdx.x >> 1, z = blockIdx.x & 1;
  const int b = blockIdx.y;
  const int tid = threadIdx.x;
  const size_t colbase = ((size_t)b * W + w) * H;

  const unsigned short* vtb = vt + colbase * C;
  // ---- async staging: 288*16 = 4608 = 8*576 exactly ----
  ushort4 vreg[8];
#pragma unroll
  for (int it = 0; it < 8; ++it) {
    const int idx = tid + it * 576;
    const int g = idx >> 4, c4 = (idx & 15) * 4;
    vreg[it] = (g < H) ? *(const ushort4*)(vtb + (size_t)g * C + c4)
                       : make_ushort4(0, 0, 0, 0);
  }
  uint4 kreg;
  if (tid < 288) kreg = *(const uint4*)(khp + (colbase + min(tid, H - 1)) * 8);
#pragma unroll
  for (int it = 0; it < 8; ++it) {
    const int idx = tid + it * 576;
    const int g = idx >> 4, c4 = (idx & 15) * 4;
    const int u = g & 31;
    const int t = (u < 16) ? ((u >> 2) * 8 + (u & 3))
                           : (((u - 16) >> 2) * 8 + 4 + (u & 3));
    const int slot = (g & ~31) + t;
    vbs[(c4 + 0) * VSH + slot] = vreg[it].x;
    vbs[(c4 + 1) * VSH + slot] = vreg[it].y;
    vbs[(c4 + 2) * VSH + slot] = vreg[it].z;
    vbs[(c4 + 3) * VSH + slot] = vreg[it].w;
  }
  if (tid < 288) *(uint4*)(kls + tid * 8) = kreg;

  const int lane = tid & 63, wv = tid >> 6;
  const int l15 = lane & 15, quad = lane >> 4;
  const int m0 = (z * 9 + wv) * 16;
  const int m = m0 + l15;  // this lane's m-row

  short8 qa = short8{0, 0, 0, 0, 0, 0, 0, 0};
  if (quad == 0)
    qa = *(const short8*)(qhp + (colbase + min(m, H - 1)) * 8);

  f32x4 acc[4];
  float Sacc = 0.0f;
#pragma unroll
  for (int ct = 0; ct < 4; ++ct)
#pragma unroll
    for (int rr = 0; rr < 4; ++rr) acc[ct][rr] = 0.0f;

  __syncthreads();

  for (int ci = 0; ci < 9; ++ci) {
    const int gc = ci * 32;
    short8 kb0 = short8{0, 0, 0, 0, 0, 0, 0, 0};
    short8 kb1 = short8{0, 0, 0, 0, 0, 0, 0, 0};
    if (quad == 0) {
      kb0 = *(const short8*)(kls + (gc + l15) * 8);
      kb1 = *(const short8*)(kls + (gc + 16 + l15) * 8);
    }
    short8 vb[4];
#pragma unroll
    for (int ct = 0; ct < 4; ++ct)
      vb[ct] = *(const short8*)(vbs + (ct * 16 + l15) * VSH + gc + quad * 8);
    const f32x4 z4 = f32x4{0.f, 0.f, 0.f, 0.f};
    const f32x4 E0 = __builtin_amdgcn_mfma_f32_16x16x32_bf16(kb0, qa, z4, 0, 0, 0);
    const f32x4 E1 = __builtin_amdgcn_mfma_f32_16x16x32_bf16(kb1, qa, z4, 0, 0, 0);
    float p0[4], p1[4];
#pragma unroll
    for (int rr = 0; rr < 4; ++rr) {
      const int g0 = gc + quad * 4 + rr;
      const int g1 = g0 + 16;
      const float d0 = (float)(m - g0);
      const float d1 = d0 - 16.0f;
      p0[rr] = (g0 < H && g0 != m)
                   ? __expf(E0[rr] * __expf(-(d0 * d0) * INVH2)) : 0.0f;
      p1[rr] = (g1 < H && g1 != m)
                   ? __expf(E1[rr] * __expf(-(d1 * d1) * INVH2)) : 0.0f;
      Sacc += p0[rr] + p1[rr];
    }
    const short8 pa = pack_p(p0, p1);
#pragma unroll
    for (int ct = 0; ct < 4; ++ct)
      acc[ct] = __builtin_amdgcn_mfma_f32_16x16x32_bf16(pa, vb[ct], acc[ct], 0, 0, 0);
  }

  {
    float s = Sacc;
    s += __shfl_xor(s, 16);
    s += __shfl_xor(s, 32);
    if (lane < 16 && m < H) Sht[colbase + m] = s;
  }

  __syncthreads();
  unsigned short* ob = vbs;  // [c][288] stride VSH
#pragma unroll
  for (int ct = 0; ct < 4; ++ct)
#pragma unroll
    for (int rr = 0; rr < 4; ++rr)
      ob[(ct * 16 + l15) * VSH + m0 + quad * 4 + rr] = f2bf(acc[ct][rr]);
  __syncthreads();
  unsigned short* og = oht + ((size_t)b * W + w) * C * H;
  const int mlo = z ? 144 : 0;
  const int nu = z ? 63 : 72;  // u32 per c-row: z=0 rows 0-143, z=1 rows 144-269
  for (int idx = tid; idx < 64 * nu; idx += 576) {
    const int c = idx / nu, i = idx - c * nu;
    *(unsigned int*)(og + (size_t)c * H + mlo + 2 * i) =
        *(const unsigned int*)(ob + c * VSH + mlo + 2 * i);
  }
}

// ---------------------------------------------------------------------------
// K4: out = gamma*(U_h + U_w)/(S_h+S_w) + x, LDS tile transpose for oht.
// Sht is [b][w][h] (1 MB, L2-resident, 64x c-reuse -> strided read is cheap).
// ---------------------------------------------------------------------------
__global__ __launch_bounds__(256)
void k_combine(const unsigned short* __restrict__ oht,
               const unsigned short* __restrict__ ow,
               const float* __restrict__ Sht, const float* __restrict__ Sw,
               const float* __restrict__ x,
               const float* __restrict__ gp,
               float* __restrict__ out) {
  __shared__ float tile[32][33];
  const int b = blockIdx.z >> 6, c = blockIdx.z & 63;
  const int w0 = blockIdx.x * 32, h0 = blockIdx.y * 32;
  const int tx = threadIdx.x, ty = threadIdx.y;  // (32, 8)
#pragma unroll
  for (int i = 0; i < 4; ++i) {
    const int wl = ty + i * 8;
    const int hh = h0 + tx;
    float val = 0.0f;
    if (hh < H) val = bits2f(oht[(((size_t)b * W + (w0 + wl)) * C + c) * H + hh]);
    tile[wl][tx] = val;
  }
  __syncthreads();
  const float gamma = *gp;
#pragma unroll
  for (int i = 0; i < 4; ++i) {
    const int hl = ty + i * 8;
    const int hh = h0 + hl;
    if (hh < H) {
      const int ww = w0 + tx;
      const float uh = tile[tx][hl];
      const float uw = bits2f(ow[(((size_t)b * H + hh) * C + c) * W + ww]);
      const size_t si = ((size_t)b * H + hh) * W + ww;
      const float Z = Sht[((size_t)b * W + ww) * H + hh] + Sw[si];
      const float invZ = __builtin_amdgcn_rcpf(Z);
      const size_t xi = ((size_t)b * C + c) * HW + (size_t)hh * W + ww;
      out[xi] = fmaf(gamma * invZ, uh + uw, x[xi]);
    }
  }
}

}  // namespace

extern "C" void kernel_launch(void* const* d_in, const int* in_sizes, int n_in,
                              void* d_out, int out_size, void* d_ws, size_t ws_size,
                              hipStream_t stream) {
  (void)in_sizes; (void)n_in; (void)out_size; (void)ws_size;
  const float* x  = (const float*)d_in[0];
  const float* Wq = (const float*)d_in[1];
  const float* bq = (const float*)d_in[2];
  const float* Wk = (const float*)d_in[3];
  const float* bk = (const float*)d_in[4];
  const float* Wv = (const float*)d_in[5];
  const float* bv = (const float*)d_in[6];
  const float* gp = (const float*)d_in[7];
  float* out = (float*)d_out;

  char* p = (char*)d_ws;
  auto take = [&](size_t bytes) -> void* {
    char* r = p;
    p += (bytes + 255) & ~(size_t)255;
    return (void*)r;
  };
  unsigned short* qwp = (unsigned short*)take(sizeof(unsigned short) * (size_t)B * HW * 8);
  unsigned short* kwp = (unsigned short*)take(sizeof(unsigned short) * (size_t)B * HW * 8);
  unsigned short* qhp = (unsigned short*)take(sizeof(unsigned short) * (size_t)B * HW * 8);
  unsigned short* khp = (unsigned short*)take(sizeof(unsigned short) * (size_t)B * HW * 8);
  unsigned short* v   = (unsigned short*)take(sizeof(unsigned short) * (size_t)B * C * HW);
  unsigned short* vt  = (unsigned short*)take(sizeof(unsigned short) * (size_t)B * C * HW);
  unsigned short* oht = (unsigned short*)take(sizeof(unsigned short) * (size_t)B * C * HW);
  unsigned short* owb = (unsigned short*)take(sizeof(unsigned short) * (size_t)B * C * HW);
  float* Sht = (float*)take(sizeof(float) * (size_t)B * HW);
  float* Sw  = (float*)take(sizeof(float) * (size_t)B * HW);

  hipLaunchKernelGGL(k_qkv, dim3((B * HW + 255) / 256), dim3(256), 0, stream,
                     x, Wq, bq, Wk, bk, Wv, bv, qwp, kwp, qhp, khp, v, vt);
  hipLaunchKernelGGL(k_outh, dim3(2 * W, B), dim3(576), 0, stream,
                     qhp, khp, vt, oht, Sht);
  hipLaunchKernelGGL(k_outw, dim3(2 * H, B), dim3(512), 0, stream,
                     qwp, kwp, v, owb, Sw);
  hipLaunchKernelGGL(k_combine, dim3(W / 32, (H + 31) / 32, B * C), dim3(32, 8), 0, stream,
                     oht, owb, Sht, Sw, x, gp, out);
}

// Round 10
// 398.822 us; speedup vs baseline: 1.7688x; 1.0156x over previous
//
#include <hip/hip_runtime.h>
#include <hip/hip_bf16.h>

namespace {

constexpr int B  = 2;
constexpr int C  = 64;
constexpr int CQ = 8;
constexpr int H  = 270;
constexpr int W  = 480;
constexpr int HW = H * W;
constexpr float INVH2 = 2.0f / (270.0f * 270.0f);  // dw_h = exp(-d^2 * INVH2)
constexpr float INVW2 = 2.0f / (480.0f * 480.0f);

typedef __attribute__((ext_vector_type(4))) float f32x4;
typedef __attribute__((ext_vector_type(8))) short short8;
typedef __attribute__((ext_vector_type(4))) unsigned int uint4v;

__device__ __forceinline__ float bits2f(unsigned short u) {
  union { unsigned int i; float f; } cv;
  cv.i = ((unsigned int)u) << 16;
  return cv.f;
}

__device__ __forceinline__ unsigned short f2bf(float f) {
  union { __hip_bfloat16 b; unsigned short u; } cv;
  cv.b = __float2bfloat16(f);
  return cv.u;
}

__device__ __forceinline__ unsigned int pack2(float a, float b) {
  return ((unsigned int)f2bf(b) << 16) | (unsigned int)f2bf(a);
}

__device__ __forceinline__ short8 pack_p(const float p0[4], const float p1[4]) {
  uint4v pw;
  pw[0] = pack2(p0[0], p0[1]);
  pw[1] = pack2(p0[2], p0[3]);
  pw[2] = pack2(p1[0], p1[1]);
  pw[3] = pack2(p1[2], p1[3]);
  return __builtin_bit_cast(short8, pw);
}

// V-row permutation inside each 32-row K-step so that the swapped-QK P layout
// (lane quad q holds g = 4q+rr from E0 and 16+4q+rr from E1) feeds the PV
// A-fragment (k-slot q*8+j) with NO cross-lane data movement:
//   u < 16: slot = 8*(u>>2) + (u&3);  u >= 16: slot = 8*((u-16)>>2) + 4 + (u&3)

// ---------------------------------------------------------------------------
// K1: q/k/v 1x1 projections. TWO adjacent pixels per thread: each weight
// float4 broadcast from LDS feeds 8 FMAs (was 4) -> ds:fma issue mix 1:8
// (was 1:4, VALUBusy 50% ceiling). Pairs never straddle a row (pix0 even, W
// even), so x loads are float2 and the v store packs 2 bf16 into one u32.
// ~180 VGPR -> (256,1) so the allocator has headroom (min-waves SHRINKS the
// cap; R1-R3 lesson). Writes qwp/kwp [b][h][w][8], qhp/khp [b][w][h][8],
// v [b][c][h][w], vt [b][w][h][c].
// ---------------------------------------------------------------------------
__global__ __launch_bounds__(256, 1)
void k_qkv(const float* __restrict__ x,
           const float* __restrict__ Wq, const float* __restrict__ bq,
           const float* __restrict__ Wk, const float* __restrict__ bk,
           const float* __restrict__ Wv, const float* __restrict__ bv,
           unsigned short* __restrict__ qwp, unsigned short* __restrict__ kwp,
           unsigned short* __restrict__ qhp, unsigned short* __restrict__ khp,
           unsigned short* __restrict__ v, unsigned short* __restrict__ vt) {
  __shared__ __align__(16) float wql[CQ * C];
  __shared__ __align__(16) float wkl[CQ * C];
  __shared__ __align__(16) float wvl[C * C];
  __shared__ float bql[CQ], bkl[CQ], bvl[C];
  const int tid = threadIdx.x;
  for (int i = tid; i < CQ * C; i += 256) { wql[i] = Wq[i]; wkl[i] = Wk[i]; }
  for (int i = tid; i < C * C; i += 256) wvl[i] = Wv[i];
  if (tid < CQ) { bql[tid] = bq[tid]; bkl[tid] = bk[tid]; }
  if (tid < C) bvl[tid] = bv[tid];
  __syncthreads();
  const int pix0 = (blockIdx.x * 256 + tid) * 2;
  if (pix0 >= B * HW) return;
  const int b = pix0 / HW;
  const int r = pix0 - b * HW;   // even; pixels r and r+1 share b and h
  const int h = r / W;
  const int w = r - h * W;       // even; w+1 < W

  float qa0[CQ], qa1[CQ], ka0[CQ], ka1[CQ], va0[C], va1[C];
#pragma unroll
  for (int o = 0; o < CQ; ++o) {
    qa0[o] = bql[o]; qa1[o] = bql[o];
    ka0[o] = bkl[o]; ka1[o] = bkl[o];
  }
#pragma unroll
  for (int o = 0; o < C; ++o) { va0[o] = bvl[o]; va1[o] = bvl[o]; }

  const float* xp = x + (size_t)b * C * HW + r;
  for (int c = 0; c < C; c += 4) {
    const float2 x0 = *(const float2*)(xp + (size_t)(c + 0) * HW);
    const float2 x1 = *(const float2*)(xp + (size_t)(c + 1) * HW);
    const float2 x2 = *(const float2*)(xp + (size_t)(c + 2) * HW);
    const float2 x3 = *(const float2*)(xp + (size_t)(c + 3) * HW);
#pragma unroll
    for (int o = 0; o < CQ; ++o) {
      const float4 a = *(const float4*)(wql + o * C + c);
      qa0[o] = fmaf(a.w, x3.x, fmaf(a.z, x2.x, fmaf(a.y, x1.x, fmaf(a.x, x0.x, qa0[o]))));
      qa1[o] = fmaf(a.w, x3.y, fmaf(a.z, x2.y, fmaf(a.y, x1.y, fmaf(a.x, x0.y, qa1[o]))));
      const float4 bb = *(const float4*)(wkl + o * C + c);
      ka0[o] = fmaf(bb.w, x3.x, fmaf(bb.z, x2.x, fmaf(bb.y, x1.x, fmaf(bb.x, x0.x, ka0[o]))));
      ka1[o] = fmaf(bb.w, x3.y, fmaf(bb.z, x2.y, fmaf(bb.y, x1.y, fmaf(bb.x, x0.y, ka1[o]))));
    }
#pragma unroll
    for (int o = 0; o < C; ++o) {
      const float4 cc = *(const float4*)(wvl + o * C + c);
      va0[o] = fmaf(cc.w, x3.x, fmaf(cc.z, x2.x, fmaf(cc.y, x1.x, fmaf(cc.x, x0.x, va0[o]))));
      va1[o] = fmaf(cc.w, x3.y, fmaf(cc.z, x2.y, fmaf(cc.y, x1.y, fmaf(cc.x, x0.y, va1[o]))));
    }
  }

  uint4 qp0, kp0, qp1, kp1;
  qp0.x = pack2(qa0[0], qa0[1]); qp0.y = pack2(qa0[2], qa0[3]);
  qp0.z = pack2(qa0[4], qa0[5]); qp0.w = pack2(qa0[6], qa0[7]);
  kp0.x = pack2(ka0[0], ka0[1]); kp0.y = pack2(ka0[2], ka0[3]);
  kp0.z = pack2(ka0[4], ka0[5]); kp0.w = pack2(ka0[6], ka0[7]);
  qp1.x = pack2(qa1[0], qa1[1]); qp1.y = pack2(qa1[2], qa1[3]);
  qp1.z = pack2(qa1[4], qa1[5]); qp1.w = pack2(qa1[6], qa1[7]);
  kp1.x = pack2(ka1[0], ka1[1]); kp1.y = pack2(ka1[2], ka1[3]);
  kp1.z = pack2(ka1[4], ka1[5]); kp1.w = pack2(ka1[6], ka1[7]);
  *(uint4*)(qwp + (size_t)pix0 * 8) = qp0;
  *(uint4*)(qwp + (size_t)(pix0 + 1) * 8) = qp1;
  *(uint4*)(kwp + (size_t)pix0 * 8) = kp0;
  *(uint4*)(kwp + (size_t)(pix0 + 1) * 8) = kp1;
  const size_t tb0 = ((size_t)b * W + w) * H + h;
  const size_t tb1 = tb0 + H;  // w+1
  *(uint4*)(qhp + tb0 * 8) = qp0;
  *(uint4*)(qhp + tb1 * 8) = qp1;
  *(uint4*)(khp + tb0 * 8) = kp0;
  *(uint4*)(khp + tb1 * 8) = kp1;

  unsigned short* vp = v + (size_t)b * C * HW + r;
#pragma unroll
  for (int o = 0; o < C; ++o)
    *(unsigned int*)(vp + (size_t)o * HW) = pack2(va0[o], va1[o]);
  unsigned short* vt0 = vt + tb0 * C;
  unsigned short* vt1 = vt + tb1 * C;
#pragma unroll
  for (int j = 0; j < 16; ++j) {
    ushort4 u0, u1;
    u0.x = f2bf(va0[4 * j + 0]); u0.y = f2bf(va0[4 * j + 1]);
    u0.z = f2bf(va0[4 * j + 2]); u0.w = f2bf(va0[4 * j + 3]);
    u1.x = f2bf(va1[4 * j + 0]); u1.y = f2bf(va1[4 * j + 1]);
    u1.z = f2bf(va1[4 * j + 2]); u1.w = f2bf(va1[4 * j + 3]);
    *(ushort4*)(vt0 + 4 * j) = u0;
    *(ushort4*)(vt1 + 4 * j) = u1;
  }
}

// ---------------------------------------------------------------------------
// K2: out_w unnormalized + S_w. Byte-identical to R8/R9 (measured < 108 us,
// likely 2-block resident at 8 waves x 116 regs = 464 <= 512).
// ---------------------------------------------------------------------------
constexpr int VSW = 494;

__global__ __launch_bounds__(512, 1)
void k_outw(const unsigned short* __restrict__ qwp,
            const unsigned short* __restrict__ kwp,
            const unsigned short* __restrict__ v,
            unsigned short* __restrict__ ow, float* __restrict__ Sw) {
  __shared__ __align__(16) unsigned short vbs[64 * VSW];   // 63232 B
  __shared__ __align__(16) unsigned short kls[480 * 8];    // 7680 B
  const int h = blockIdx.x >> 1, z = blockIdx.x & 1;
  const int b = blockIdx.y;
  const int tid = threadIdx.x;
  const size_t rowbase = ((size_t)b * H + h) * W;

  const unsigned short* vrow = v + (size_t)b * C * HW + (size_t)h * W;
  // ---- async staging: load batch 1 (8), write, load batch 2 (7), write ----
  ushort4 vr0[8];
#pragma unroll
  for (int it = 0; it < 8; ++it) {
    const int idx = tid + it * 512;
    const int c = idx / 120, s4 = (idx - c * 120) * 4;
    vr0[it] = *(const ushort4*)(vrow + (size_t)c * HW + s4);
  }
  uint4 kreg;
  if (tid < 480) kreg = *(const uint4*)(kwp + (rowbase + tid) * 8);
#pragma unroll
  for (int it = 0; it < 8; ++it) {
    const int idx = tid + it * 512;
    const int c = idx / 120, s4 = (idx - c * 120) * 4;
    const int u = s4 & 31;
    const int t = (u < 16) ? ((u >> 2) * 8) : (((u - 16) >> 2) * 8 + 4);
    *(ushort4*)(vbs + c * VSW + (s4 & ~31) + t) = vr0[it];
  }
  ushort4 vr1[7];
#pragma unroll
  for (int it = 0; it < 7; ++it) {
    const int idx = tid + (8 + it) * 512;
    const int c = idx / 120, s4 = (idx - c * 120) * 4;
    vr1[it] = *(const ushort4*)(vrow + (size_t)c * HW + s4);
  }
#pragma unroll
  for (int it = 0; it < 7; ++it) {
    const int idx = tid + (8 + it) * 512;
    const int c = idx / 120, s4 = (idx - c * 120) * 4;
    const int u = s4 & 31;
    const int t = (u < 16) ? ((u >> 2) * 8) : (((u - 16) >> 2) * 8 + 4);
    *(ushort4*)(vbs + c * VSW + (s4 & ~31) + t) = vr1[it];
  }
  if (tid < 480) *(uint4*)(kls + tid * 8) = kreg;

  const int lane = tid & 63, wv = tid >> 6;
  const int l15 = lane & 15, quad = lane >> 4;
  const int chunk = z * 8 + wv;
  const bool active = chunk < 15;
  const int m0 = chunk * 32;

  short8 qa0 = short8{0, 0, 0, 0, 0, 0, 0, 0};
  short8 qa1 = short8{0, 0, 0, 0, 0, 0, 0, 0};
  if (quad == 0 && active) {
    qa0 = *(const short8*)(qwp + (rowbase + m0 + l15) * 8);
    qa1 = *(const short8*)(qwp + (rowbase + m0 + 16 + l15) * 8);
  }

  f32x4 acc[2][4];
  float Sacc[2] = {0.0f, 0.0f};
#pragma unroll
  for (int mt = 0; mt < 2; ++mt)
#pragma unroll
    for (int ct = 0; ct < 4; ++ct)
#pragma unroll
      for (int rr = 0; rr < 4; ++rr) acc[mt][ct][rr] = 0.0f;

  __syncthreads();

  if (active) {
    short8 kb0 = short8{0, 0, 0, 0, 0, 0, 0, 0};
    short8 kb1 = short8{0, 0, 0, 0, 0, 0, 0, 0};
    if (quad == 0) {
      kb0 = *(const short8*)(kls + (l15) * 8);
      kb1 = *(const short8*)(kls + (16 + l15) * 8);
    }
    for (int ci = 0; ci < 15; ++ci) {
      const int sc = ci * 32;
      short8 nk0 = short8{0, 0, 0, 0, 0, 0, 0, 0};
      short8 nk1 = short8{0, 0, 0, 0, 0, 0, 0, 0};
      if (ci < 14 && quad == 0) {
        nk0 = *(const short8*)(kls + (sc + 32 + l15) * 8);
        nk1 = *(const short8*)(kls + (sc + 48 + l15) * 8);
      }
      short8 vb[4];
#pragma unroll
      for (int ct = 0; ct < 4; ++ct)
        vb[ct] = *(const short8*)(vbs + (ct * 16 + l15) * VSW + sc + quad * 8);
      const f32x4 z4 = f32x4{0.f, 0.f, 0.f, 0.f};
      const f32x4 E00 = __builtin_amdgcn_mfma_f32_16x16x32_bf16(kb0, qa0, z4, 0, 0, 0);
      const f32x4 E01 = __builtin_amdgcn_mfma_f32_16x16x32_bf16(kb1, qa0, z4, 0, 0, 0);
      const f32x4 E10 = __builtin_amdgcn_mfma_f32_16x16x32_bf16(kb0, qa1, z4, 0, 0, 0);
      const f32x4 E11 = __builtin_amdgcn_mfma_f32_16x16x32_bf16(kb1, qa1, z4, 0, 0, 0);
#pragma unroll
      for (int mt = 0; mt < 2; ++mt) {
        const int m = m0 + mt * 16 + l15;
        const f32x4 Ea = mt ? E10 : E00;
        const f32x4 Eb = mt ? E11 : E01;
        float p0[4], p1[4];
#pragma unroll
        for (int rr = 0; rr < 4; ++rr) {
          const float d0 = (float)(m - (sc + quad * 4 + rr));
          const float d1 = d0 - 16.0f;
          p0[rr] = __expf(Ea[rr] * __expf(-(d0 * d0) * INVW2));
          p1[rr] = __expf(Eb[rr] * __expf(-(d1 * d1) * INVW2));
          Sacc[mt] += p0[rr] + p1[rr];
        }
        const short8 pa = pack_p(p0, p1);
#pragma unroll
        for (int ct = 0; ct < 4; ++ct)
          acc[mt][ct] = __builtin_amdgcn_mfma_f32_16x16x32_bf16(pa, vb[ct], acc[mt][ct], 0, 0, 0);
      }
      kb0 = nk0;
      kb1 = nk1;
    }

#pragma unroll
    for (int mt = 0; mt < 2; ++mt) {
      float s = Sacc[mt];
      s += __shfl_xor(s, 16);
      s += __shfl_xor(s, 32);
      if (lane < 16) Sw[rowbase + m0 + mt * 16 + l15] = s;
    }
  }

  __syncthreads();  // vbs reads done; reuse as [c][480] transpose buffer
  unsigned short* ob = vbs;
  if (active) {
#pragma unroll
    for (int mt = 0; mt < 2; ++mt)
#pragma unroll
      for (int ct = 0; ct < 4; ++ct)
#pragma unroll
        for (int rr = 0; rr < 4; ++rr)
          ob[(ct * 16 + l15) * VSW + m0 + mt * 16 + quad * 4 + rr] = f2bf(acc[mt][ct][rr]);
  }
  __syncthreads();
  unsigned short* og = ow + ((size_t)b * H + h) * C * W;
  const int mlo = z ? 256 : 0;
  const int nu = z ? 112 : 128;  // u32 per c-row in this block's m-range
  for (int idx = tid; idx < 64 * nu; idx += 512) {
    const int c = idx / nu, i = idx - c * nu;
    *(unsigned int*)(og + (size_t)c * W + mlo + 2 * i) =
        *(const unsigned int*)(ob + c * VSW + mlo + 2 * i);
  }
}

// ---------------------------------------------------------------------------
// K3: out_h unnormalized + S_h. 16-ROW WAVES (R9's measured win): TWO blocks
// per (b,w), 576 thr = 9 waves, wave wv owns chunk z*9+wv of 16 m-rows.
// Byte-identical to R9.
// ---------------------------------------------------------------------------
constexpr int VSH = 302;

__global__ __launch_bounds__(576, 1)
void k_outh(const unsigned short* __restrict__ qhp,
            const unsigned short* __restrict__ khp,
            const unsigned short* __restrict__ vt,
            unsigned short* __restrict__ oht, float* __restrict__ Sht) {
  __shared__ __align__(16) unsigned short vbs[64 * VSH];   // 38656 B
  __shared__ __align__(16) unsigned short kls[288 * 8];    // 4608 B
  const int w = blockIdx.x >> 1, z = blockIdx.x & 1;
  const int b = blockIdx.y;
  const int tid = threadIdx.x;
  const size_t colbase = ((size_t)b * W + w) * H;

  const unsigned short* vtb = vt + colbase * C;
  // ---- async staging: 288*16 = 4608 = 8*576 exactly ----
  ushort4 vreg[8];
#pragma unroll
  for (int it = 0; it < 8; ++it) {
    const int idx = tid + it * 576;
    const int g = idx >> 4, c4 = (idx & 15) * 4;
    vreg[it] = (g < H) ? *(const ushort4*)(vtb + (size_t)g * C + c4)
                       : make_ushort4(0, 0, 0, 0);
  }
  uint4 kreg;
  if (tid < 288) kreg = *(const uint4*)(khp + (colbase + min(tid, H - 1)) * 8);
#pragma unroll
  for (int it = 0; it < 8; ++it) {
    const int idx = tid + it * 576;
    const int g = idx >> 4, c4 = (idx & 15) * 4;
    const int u = g & 31;
    const int t = (u < 16) ? ((u >> 2) * 8 + (u & 3))
                           : (((u - 16) >> 2) * 8 + 4 + (u & 3));
    const int slot = (g & ~31) + t;
    vbs[(c4 + 0) * VSH + slot] = vreg[it].x;
    vbs[(c4 + 1) * VSH + slot] = vreg[it].y;
    vbs[(c4 + 2) * VSH + slot] = vreg[it].z;
    vbs[(c4 + 3) * VSH + slot] = vreg[it].w;
  }
  if (tid < 288) *(uint4*)(kls + tid * 8) = kreg;

  const int lane = tid & 63, wv = tid >> 6;
  const int l15 = lane & 15, quad = lane >> 4;
  const int m0 = (z * 9 + wv) * 16;
  const int m = m0 + l15;  // this lane's m-row

  short8 qa = short8{0, 0, 0, 0, 0, 0, 0, 0};
  if (quad == 0)
    qa = *(const short8*)(qhp + (colbase + min(m, H - 1)) * 8);

  f32x4 acc[4];
  float Sacc = 0.0f;
#pragma unroll
  for (int ct = 0; ct < 4; ++ct)
#pragma unroll
    for (int rr = 0; rr < 4; ++rr) acc[ct][rr] = 0.0f;

  __syncthreads();

  for (int ci = 0; ci < 9; ++ci) {
    const int gc = ci * 32;
    short8 kb0 = short8{0, 0, 0, 0, 0, 0, 0, 0};
    short8 kb1 = short8{0, 0, 0, 0, 0, 0, 0, 0};
    if (quad == 0) {
      kb0 = *(const short8*)(kls + (gc + l15) * 8);
      kb1 = *(const short8*)(kls + (gc + 16 + l15) * 8);
    }
    short8 vb[4];
#pragma unroll
    for (int ct = 0; ct < 4; ++ct)
      vb[ct] = *(const short8*)(vbs + (ct * 16 + l15) * VSH + gc + quad * 8);
    const f32x4 z4 = f32x4{0.f, 0.f, 0.f, 0.f};
    const f32x4 E0 = __builtin_amdgcn_mfma_f32_16x16x32_bf16(kb0, qa, z4, 0, 0, 0);
    const f32x4 E1 = __builtin_amdgcn_mfma_f32_16x16x32_bf16(kb1, qa, z4, 0, 0, 0);
    float p0[4], p1[4];
#pragma unroll
    for (int rr = 0; rr < 4; ++rr) {
      const int g0 = gc + quad * 4 + rr;
      const int g1 = g0 + 16;
      const float d0 = (float)(m - g0);
      const float d1 = d0 - 16.0f;
      p0[rr] = (g0 < H && g0 != m)
                   ? __expf(E0[rr] * __expf(-(d0 * d0) * INVH2)) : 0.0f;
      p1[rr] = (g1 < H && g1 != m)
                   ? __expf(E1[rr] * __expf(-(d1 * d1) * INVH2)) : 0.0f;
      Sacc += p0[rr] + p1[rr];
    }
    const short8 pa = pack_p(p0, p1);
#pragma unroll
    for (int ct = 0; ct < 4; ++ct)
      acc[ct] = __builtin_amdgcn_mfma_f32_16x16x32_bf16(pa, vb[ct], acc[ct], 0, 0, 0);
  }

  {
    float s = Sacc;
    s += __shfl_xor(s, 16);
    s += __shfl_xor(s, 32);
    if (lane < 16 && m < H) Sht[colbase + m] = s;
  }

  __syncthreads();
  unsigned short* ob = vbs;  // [c][288] stride VSH
#pragma unroll
  for (int ct = 0; ct < 4; ++ct)
#pragma unroll
    for (int rr = 0; rr < 4; ++rr)
      ob[(ct * 16 + l15) * VSH + m0 + quad * 4 + rr] = f2bf(acc[ct][rr]);
  __syncthreads();
  unsigned short* og = oht + ((size_t)b * W + w) * C * H;
  const int mlo = z ? 144 : 0;
  const int nu = z ? 63 : 72;  // u32 per c-row: z=0 rows 0-143, z=1 rows 144-269
  for (int idx = tid; idx < 64 * nu; idx += 576) {
    const int c = idx / nu, i = idx - c * nu;
    *(unsigned int*)(og + (size_t)c * H + mlo + 2 * i) =
        *(const unsigned int*)(ob + c * VSH + mlo + 2 * i);
  }
}

// ---------------------------------------------------------------------------
// K4: out = gamma*(U_h + U_w)/(S_h+S_w) + x, LDS tile transpose for oht.
// Sht is [b][w][h] (1 MB, L2-resident, 64x c-reuse -> strided read is cheap).
// ---------------------------------------------------------------------------
__global__ __launch_bounds__(256)
void k_combine(const unsigned short* __restrict__ oht,
               const unsigned short* __restrict__ ow,
               const float* __restrict__ Sht, const float* __restrict__ Sw,
               const float* __restrict__ x,
               const float* __restrict__ gp,
               float* __restrict__ out) {
  __shared__ float tile[32][33];
  const int b = blockIdx.z >> 6, c = blockIdx.z & 63;
  const int w0 = blockIdx.x * 32, h0 = blockIdx.y * 32;
  const int tx = threadIdx.x, ty = threadIdx.y;  // (32, 8)
#pragma unroll
  for (int i = 0; i < 4; ++i) {
    const int wl = ty + i * 8;
    const int hh = h0 + tx;
    float val = 0.0f;
    if (hh < H) val = bits2f(oht[(((size_t)b * W + (w0 + wl)) * C + c) * H + hh]);
    tile[wl][tx] = val;
  }
  __syncthreads();
  const float gamma = *gp;
#pragma unroll
  for (int i = 0; i < 4; ++i) {
    const int hl = ty + i * 8;
    const int hh = h0 + hl;
    if (hh < H) {
      const int ww = w0 + tx;
      const float uh = tile[tx][hl];
      const float uw = bits2f(ow[(((size_t)b * H + hh) * C + c) * W + ww]);
      const size_t si = ((size_t)b * H + hh) * W + ww;
      const float Z = Sht[((size_t)b * W + ww) * H + hh] + Sw[si];
      const float invZ = __builtin_amdgcn_rcpf(Z);
      const size_t xi = ((size_t)b * C + c) * HW + (size_t)hh * W + ww;
      out[xi] = fmaf(gamma * invZ, uh + uw, x[xi]);
    }
  }
}

}  // namespace

extern "C" void kernel_launch(void* const* d_in, const int* in_sizes, int n_in,
                              void* d_out, int out_size, void* d_ws, size_t ws_size,
                              hipStream_t stream) {
  (void)in_sizes; (void)n_in; (void)out_size; (void)ws_size;
  const float* x  = (const float*)d_in[0];
  const float* Wq = (const float*)d_in[1];
  const float* bq = (const float*)d_in[2];
  const float* Wk = (const float*)d_in[3];
  const float* bk = (const float*)d_in[4];
  const float* Wv = (const float*)d_in[5];
  const float* bv = (const float*)d_in[6];
  const float* gp = (const float*)d_in[7];
  float* out = (float*)d_out;

  char* p = (char*)d_ws;
  auto take = [&](size_t bytes) -> void* {
    char* r = p;
    p += (bytes + 255) & ~(size_t)255;
    return (void*)r;
  };
  unsigned short* qwp = (unsigned short*)take(sizeof(unsigned short) * (size_t)B * HW * 8);
  unsigned short* kwp = (unsigned short*)take(sizeof(unsigned short) * (size_t)B * HW * 8);
  unsigned short* qhp = (unsigned short*)take(sizeof(unsigned short) * (size_t)B * HW * 8);
  unsigned short* khp = (unsigned short*)take(sizeof(unsigned short) * (size_t)B * HW * 8);
  unsigned short* v   = (unsigned short*)take(sizeof(unsigned short) * (size_t)B * C * HW);
  unsigned short* vt  = (unsigned short*)take(sizeof(unsigned short) * (size_t)B * C * HW);
  unsigned short* oht = (unsigned short*)take(sizeof(unsigned short) * (size_t)B * C * HW);
  unsigned short* owb = (unsigned short*)take(sizeof(unsigned short) * (size_t)B * C * HW);
  float* Sht = (float*)take(sizeof(float) * (size_t)B * HW);
  float* Sw  = (float*)take(sizeof(float) * (size_t)B * HW);

  hipLaunchKernelGGL(k_qkv, dim3((B * HW / 2 + 255) / 256), dim3(256), 0, stream,
                     x, Wq, bq, Wk, bk, Wv, bv, qwp, kwp, qhp, khp, v, vt);
  hipLaunchKernelGGL(k_outh, dim3(2 * W, B), dim3(576), 0, stream,
                     qhp, khp, vt, oht, Sht);
  hipLaunchKernelGGL(k_outw, dim3(2 * H, B), dim3(512), 0, stream,
                     qwp, kwp, v, owb, Sw);
  hipLaunchKernelGGL(k_combine, dim3(W / 32, (H + 31) / 32, B * C), dim3(32, 8), 0, stream,
                     oht, owb, Sht, Sw, x, gp, out);
}